// Round 2
// baseline (12116.128 us; speedup 1.0000x reference)
//
#include <hip/hip_runtime.h>

#define ALPHA 0.5f

static inline int ceil_div(int a, int b) { return (a + b - 1) / b; }

// ---------------- degree / norm ----------------
__global__ void deg_kernel(const int* __restrict__ src, const int* __restrict__ dst,
                           float* __restrict__ deg_in, float* __restrict__ deg_out, int E)
{
    int e = blockIdx.x * blockDim.x + threadIdx.x;
    if (e < E) {
        atomicAdd(&deg_in[dst[e]], 1.0f);   // GCN(in): deg over dst
        atomicAdd(&deg_out[src[e]], 1.0f);  // GCN(reversed): deg over src
    }
}

__global__ void dinv_cnt_kernel(float* __restrict__ dinv_in, float* __restrict__ dinv_out,
                                const int* __restrict__ seg, float* __restrict__ cnt, int N)
{
    int v = blockIdx.x * blockDim.x + threadIdx.x;
    if (v < N) {
        float di = dinv_in[v];
        dinv_in[v] = (di > 0.f) ? rsqrtf(di) : 0.f;
        float dq = dinv_out[v];
        dinv_out[v] = (dq > 0.f) ? rsqrtf(dq) : 0.f;
        atomicAdd(&cnt[seg[v]], 1.0f);
    }
}

// ---------------- width-4 aggregation (layer 1, pre-projection) ----------------
__global__ void agg4_kernel(const int* __restrict__ src, const int* __restrict__ dst,
                            const float4* __restrict__ x,
                            const float* __restrict__ dinv_in, const float* __restrict__ dinv_out,
                            float* __restrict__ accI, float* __restrict__ accO, int E)
{
    int e = blockIdx.x * blockDim.x + threadIdx.x;
    if (e >= E) return;
    int s = src[e], d = dst[e];
    float ci = dinv_in[s] * dinv_in[d];
    float co = dinv_out[s] * dinv_out[d];
    float4 xs = x[s];
    float4 xd = x[d];
    atomicAdd(&accI[d * 4 + 0], ci * xs.x);
    atomicAdd(&accI[d * 4 + 1], ci * xs.y);
    atomicAdd(&accI[d * 4 + 2], ci * xs.z);
    atomicAdd(&accI[d * 4 + 3], ci * xs.w);
    atomicAdd(&accO[s * 4 + 0], co * xd.x);
    atomicAdd(&accO[s * 4 + 1], co * xd.y);
    atomicAdd(&accO[s * 4 + 2], co * xd.z);
    atomicAdd(&accO[s * 4 + 3], co * xd.w);
}

// ---------------- layer 1 dense: (N,4)x2 -> (N,128), relu ----------------
#define L1_NODES 32
__global__ void layer1_kernel(const float* __restrict__ accI, const float* __restrict__ accO,
                              const float* __restrict__ Wi, const float* __restrict__ bi,
                              const float* __restrict__ Wr, const float* __restrict__ br,
                              float* __restrict__ h1, int N)
{
    __shared__ float wI[4][128], wO[4][128], bb[128];
    int j = threadIdx.x;  // 128 threads
    for (int c = 0; c < 4; ++c) {
        wI[c][j] = (1.f - ALPHA) * Wi[c * 128 + j];
        wO[c][j] = ALPHA * Wr[c * 128 + j];
    }
    bb[j] = (1.f - ALPHA) * bi[j] + ALPHA * br[j];
    __syncthreads();
    int v0 = blockIdx.x * L1_NODES;
    int v1 = min(N, v0 + L1_NODES);
    for (int v = v0; v < v1; ++v) {
        float s = bb[j];
#pragma unroll
        for (int c = 0; c < 4; ++c)
            s += accI[v * 4 + c] * wI[c][j] + accO[v * 4 + c] * wO[c][j];
        h1[(size_t)v * 128 + j] = fmaxf(s, 0.f);
    }
}

// ---------------- width-128 aggregation (layers 2 & 3) ----------------
// 32 lanes per edge, float4 per lane; atomics into both direction accumulators.
__global__ void agg128_kernel(const int* __restrict__ src, const int* __restrict__ dst,
                              const float* __restrict__ h,
                              const float* __restrict__ dinv_in, const float* __restrict__ dinv_out,
                              float* __restrict__ accI, float* __restrict__ accO, int E)
{
    int lane = threadIdx.x & 31;
    int esub = threadIdx.x >> 5;
    int e = blockIdx.x * 8 + esub;
    if (e >= E) return;
    int s = src[e], d = dst[e];
    float ci = dinv_in[s] * dinv_in[d];
    float co = dinv_out[s] * dinv_out[d];
    const float4* h4 = (const float4*)h;
    float4 hs = h4[(size_t)s * 32 + lane];
    float4 hd = h4[(size_t)d * 32 + lane];
    float* pi = &accI[(size_t)d * 128 + lane * 4];
    atomicAdd(pi + 0, ci * hs.x);
    atomicAdd(pi + 1, ci * hs.y);
    atomicAdd(pi + 2, ci * hs.z);
    atomicAdd(pi + 3, ci * hs.w);
    float* po = &accO[(size_t)s * 128 + lane * 4];
    atomicAdd(po + 0, co * hd.x);
    atomicAdd(po + 1, co * hd.y);
    atomicAdd(po + 2, co * hd.z);
    atomicAdd(po + 3, co * hd.w);
}

// ---------------- layer 2 dense: (N,128)x2 -> (N,128), relu ----------------
#define L2_NODES 16
__global__ void layer2_kernel(const float* __restrict__ aggI, const float* __restrict__ aggO,
                              const float* __restrict__ Wi, const float* __restrict__ bi,
                              const float* __restrict__ Wr, const float* __restrict__ br,
                              float* __restrict__ h2, int N)
{
    __shared__ float rI[L2_NODES][128];
    __shared__ float rO[L2_NODES][128];
    int j = threadIdx.x;  // 128 threads
    int v0 = blockIdx.x * L2_NODES;
    if (v0 >= N) return;
    int nv = min(L2_NODES, N - v0);
    for (int n = 0; n < nv; ++n) {
        rI[n][j] = aggI[(size_t)(v0 + n) * 128 + j];
        rO[n][j] = aggO[(size_t)(v0 + n) * 128 + j];
    }
    __syncthreads();
    float bcomb = (1.f - ALPHA) * bi[j] + ALPHA * br[j];
    float acc[L2_NODES];
#pragma unroll
    for (int n = 0; n < L2_NODES; ++n) acc[n] = bcomb;
    for (int k = 0; k < 128; ++k) {
        float wi = (1.f - ALPHA) * Wi[k * 128 + j];
        float wo = ALPHA * Wr[k * 128 + j];
#pragma unroll
        for (int n = 0; n < L2_NODES; ++n)
            acc[n] += rI[n][k] * wi + rO[n][k] * wo;
    }
    for (int n = 0; n < nv; ++n)
        h2[(size_t)(v0 + n) * 128 + j] = fmaxf(acc[n], 0.f);
}

// ---------------- pooling of 128-wide aggregated features (batch_seg sorted) ----------------
#define POOL_NODES 256
__global__ void pool_kernel(const float* __restrict__ aggI, const float* __restrict__ aggO,
                            const int* __restrict__ seg,
                            float* __restrict__ poolI, float* __restrict__ poolO, int N)
{
    int j = threadIdx.x;  // 128 threads
    int v0 = blockIdx.x * POOL_NODES;
    if (v0 >= N) return;
    int v1 = min(N, v0 + POOL_NODES);
    float aI = 0.f, aO = 0.f;
    int cur = seg[v0];
    for (int v = v0; v < v1; ++v) {
        int g = seg[v];
        if (g != cur) {
            atomicAdd(&poolI[cur * 128 + j], aI);
            atomicAdd(&poolO[cur * 128 + j], aO);
            aI = 0.f; aO = 0.f; cur = g;
        }
        aI += aggI[(size_t)v * 128 + j];
        aO += aggO[(size_t)v * 128 + j];
    }
    atomicAdd(&poolI[cur * 128 + j], aI);
    atomicAdd(&poolO[cur * 128 + j], aO);
}

// ---------------- final: (G,128)x2 -> (G,120) with mean ----------------
__global__ void final_kernel(const float* __restrict__ poolI, const float* __restrict__ poolO,
                             const float* __restrict__ cnt,
                             const float* __restrict__ Wo, const float* __restrict__ bo,
                             const float* __restrict__ Wor, const float* __restrict__ bor,
                             float* __restrict__ out, int G)
{
    int g = blockIdx.x;
    int j = threadIdx.x;  // 120 threads
    if (g >= G || j >= 120) return;
    float acc = 0.f;
    for (int k = 0; k < 128; ++k) {
        acc += poolI[g * 128 + k] * ((1.f - ALPHA) * Wo[k * 120 + j])
             + poolO[g * 128 + k] * (ALPHA * Wor[k * 120 + j]);
    }
    float c = cnt[g];
    float bcomb = (1.f - ALPHA) * bo[j] + ALPHA * bor[j];
    out[g * 120 + j] = (c > 0.f) ? (acc / c + bcomb) : 0.f;
}

extern "C" void kernel_launch(void* const* d_in, const int* in_sizes, int n_in,
                              void* d_out, int out_size, void* d_ws, size_t ws_size,
                              hipStream_t stream)
{
    const float* x      = (const float*)d_in[0];
    const int*   ei     = (const int*)d_in[1];
    const int*   seg    = (const int*)d_in[2];
    const float* W_in   = (const float*)d_in[3];
    const float* b_in   = (const float*)d_in[4];
    const float* W_in_r = (const float*)d_in[5];
    const float* b_in_r = (const float*)d_in[6];
    const float* W_mid  = (const float*)d_in[7];
    const float* b_mid  = (const float*)d_in[8];
    const float* W_mid_r= (const float*)d_in[9];
    const float* b_mid_r= (const float*)d_in[10];
    const float* W_out  = (const float*)d_in[11];
    const float* b_out  = (const float*)d_in[12];
    const float* W_out_r= (const float*)d_in[13];
    const float* b_out_r= (const float*)d_in[14];

    const int N = in_sizes[0] / 4;
    const int E = in_sizes[1] / 2;
    const int G = out_size / 120;
    const int* src = ei;
    const int* dst = ei + E;

    float* ws = (float*)d_ws;
    size_t off = 0;
    float* dinv_in  = ws + off; off += N;
    float* dinv_out = ws + off; off += N;
    float* cnt      = ws + off; off += G;
    float* acc4_in  = ws + off; off += (size_t)N * 4;
    float* acc4_out = ws + off; off += (size_t)N * 4;
    float* bufB     = ws + off; off += (size_t)N * 128;   // agg in-direction
    float* bufC     = ws + off; off += (size_t)N * 128;   // agg out-direction
    float* poolI    = ws + off; off += (size_t)G * 128;
    float* poolO    = ws + off; off += (size_t)G * 128;
    size_t zero_floats = off;                              // everything above needs zeroing
    float* bufA     = ws + off; off += (size_t)N * 128;   // h1 then h2 (no zeroing needed)

    // Zero accumulators (poisoned 0xAA by harness; must re-zero every call).
    hipMemsetAsync(d_ws, 0, zero_floats * sizeof(float), stream);

    const int T = 256;
    deg_kernel<<<ceil_div(E, T), T, 0, stream>>>(src, dst, dinv_in, dinv_out, E);
    dinv_cnt_kernel<<<ceil_div(N, T), T, 0, stream>>>(dinv_in, dinv_out, seg, cnt, N);
    agg4_kernel<<<ceil_div(E, T), T, 0, stream>>>(src, dst, (const float4*)x,
                                                  dinv_in, dinv_out, acc4_in, acc4_out, E);
    layer1_kernel<<<ceil_div(N, L1_NODES), 128, 0, stream>>>(acc4_in, acc4_out,
                                                             W_in, b_in, W_in_r, b_in_r, bufA, N);
    agg128_kernel<<<ceil_div(E, 8), 256, 0, stream>>>(src, dst, bufA, dinv_in, dinv_out,
                                                      bufB, bufC, E);
    layer2_kernel<<<ceil_div(N, L2_NODES), 128, 0, stream>>>(bufB, bufC,
                                                             W_mid, b_mid, W_mid_r, b_mid_r, bufA, N);
    hipMemsetAsync(bufB, 0, (size_t)N * 128 * 2 * sizeof(float), stream);
    agg128_kernel<<<ceil_div(E, 8), 256, 0, stream>>>(src, dst, bufA, dinv_in, dinv_out,
                                                      bufB, bufC, E);
    pool_kernel<<<ceil_div(N, POOL_NODES), 128, 0, stream>>>(bufB, bufC, seg, poolI, poolO, N);
    final_kernel<<<G, 128, 0, stream>>>(poolI, poolO, cnt,
                                        W_out, b_out, W_out_r, b_out_r, (float*)d_out, G);
}

// Round 3
// 2097.179 us; speedup vs baseline: 5.7773x; 5.7773x over previous
//
#include <hip/hip_runtime.h>

#define ALPHA 0.5f
#define SCAN_B 256

static inline int ceil_div(int a, int b) { return (a + b - 1) / b; }

// ---------------- degree histogram (int) ----------------
__global__ void deg_kernel(const int* __restrict__ src, const int* __restrict__ dst,
                           unsigned int* __restrict__ degI, unsigned int* __restrict__ degO, int E)
{
    int e = blockIdx.x * blockDim.x + threadIdx.x;
    if (e < E) {
        atomicAdd(&degI[dst[e]], 1u);   // GCN(in): deg over dst
        atomicAdd(&degO[src[e]], 1u);   // GCN(reversed): deg over src
    }
}

// ---------------- exclusive scan: per-block pass ----------------
__global__ void scan_blk_kernel(const unsigned int* __restrict__ deg,
                                unsigned int* __restrict__ excl,
                                unsigned int* __restrict__ bsum, int N)
{
    __shared__ unsigned int tmp[SCAN_B];
    int t = threadIdx.x;
    int i = blockIdx.x * SCAN_B + t;
    unsigned int v = (i < N) ? deg[i] : 0u;
    tmp[t] = v;
    __syncthreads();
    for (int o = 1; o < SCAN_B; o <<= 1) {
        unsigned int x = (t >= o) ? tmp[t - o] : 0u;
        __syncthreads();
        tmp[t] += x;
        __syncthreads();
    }
    if (i < N) excl[i] = tmp[t] - v;               // local exclusive
    if (t == SCAN_B - 1) bsum[blockIdx.x] = tmp[t]; // block total
}

// ---------------- exclusive scan: top-level (single block, nb <= 1024) ----------------
__global__ void scan_top_kernel(unsigned int* __restrict__ bsum, int nb)
{
    __shared__ unsigned int tmp[1024];
    int t = threadIdx.x;
    unsigned int v = (t < nb) ? bsum[t] : 0u;
    tmp[t] = v;
    __syncthreads();
    for (int o = 1; o < 1024; o <<= 1) {
        unsigned int x = (t >= o) ? tmp[t - o] : 0u;
        __syncthreads();
        tmp[t] += x;
        __syncthreads();
    }
    if (t < nb) bsum[t] = tmp[t] - v;              // exclusive block offsets
}

// ---------------- scan finalize: add block offset, compute dinv ----------------
__global__ void scan_add_kernel(unsigned int* __restrict__ excl,
                                const unsigned int* __restrict__ bsum,
                                const unsigned int* __restrict__ deg,
                                float* __restrict__ dinv, int N)
{
    int i = blockIdx.x * SCAN_B + threadIdx.x;
    if (i < N) {
        excl[i] += bsum[blockIdx.x];
        unsigned int d = deg[i];
        dinv[i] = d ? rsqrtf((float)d) : 0.f;
    }
}

// ---------------- per-graph node counts ----------------
__global__ void cnt_kernel(const int* __restrict__ seg, float* __restrict__ cnt, int N)
{
    int v = blockIdx.x * blockDim.x + threadIdx.x;
    if (v < N) atomicAdd(&cnt[seg[v]], 1.0f);
}

// ---------------- CSR scatter (rowptr used as cursor; becomes row END after) ----------------
__global__ void scatter_kernel(const int* __restrict__ src, const int* __restrict__ dst,
                               unsigned int* __restrict__ curI, unsigned int* __restrict__ curO,
                               int* __restrict__ adjI, int* __restrict__ adjO, int E)
{
    int e = blockIdx.x * blockDim.x + threadIdx.x;
    if (e < E) {
        int s = src[e], d = dst[e];
        unsigned int p = atomicAdd(&curI[d], 1u);
        adjI[p] = s;
        unsigned int q = atomicAdd(&curO[s], 1u);
        adjO[q] = d;
    }
}

// ---------------- width-4 aggregation (layer 1, pre-projection; cheap, atomics OK) -------
__global__ void agg4_kernel(const int* __restrict__ src, const int* __restrict__ dst,
                            const float4* __restrict__ x,
                            const float* __restrict__ dinvI, const float* __restrict__ dinvO,
                            float* __restrict__ accI, float* __restrict__ accO, int E)
{
    int e = blockIdx.x * blockDim.x + threadIdx.x;
    if (e >= E) return;
    int s = src[e], d = dst[e];
    float ci = dinvI[s] * dinvI[d];
    float co = dinvO[s] * dinvO[d];
    float4 xs = x[s];
    float4 xd = x[d];
    atomicAdd(&accI[d * 4 + 0], ci * xs.x);
    atomicAdd(&accI[d * 4 + 1], ci * xs.y);
    atomicAdd(&accI[d * 4 + 2], ci * xs.z);
    atomicAdd(&accI[d * 4 + 3], ci * xs.w);
    atomicAdd(&accO[s * 4 + 0], co * xd.x);
    atomicAdd(&accO[s * 4 + 1], co * xd.y);
    atomicAdd(&accO[s * 4 + 2], co * xd.z);
    atomicAdd(&accO[s * 4 + 3], co * xd.w);
}

// ---------------- layer 1 dense: (N,4)x2 -> (N,128), relu ----------------
#define L1_NODES 32
__global__ void layer1_kernel(const float* __restrict__ accI, const float* __restrict__ accO,
                              const float* __restrict__ Wi, const float* __restrict__ bi,
                              const float* __restrict__ Wr, const float* __restrict__ br,
                              float* __restrict__ h1, int N)
{
    __shared__ float wI[4][128], wO[4][128], bb[128];
    int j = threadIdx.x;  // 128 threads
    for (int c = 0; c < 4; ++c) {
        wI[c][j] = (1.f - ALPHA) * Wi[c * 128 + j];
        wO[c][j] = ALPHA * Wr[c * 128 + j];
    }
    bb[j] = (1.f - ALPHA) * bi[j] + ALPHA * br[j];
    __syncthreads();
    int v0 = blockIdx.x * L1_NODES;
    int v1 = min(N, v0 + L1_NODES);
    for (int v = v0; v < v1; ++v) {
        float s = bb[j];
#pragma unroll
        for (int c = 0; c < 4; ++c)
            s += accI[v * 4 + c] * wI[c][j] + accO[v * 4 + c] * wO[c][j];
        h1[(size_t)v * 128 + j] = fmaxf(s, 0.f);
    }
}

// ---------------- CSR gather aggregation, width 128 (atomic-free) ----------------
// 32 lanes per node (float4 each); 256-thread block = 8 nodes.
// rowend[v] = end of v's adjacency (rowptr after cursor-scatter); start = end - deg[v].
__global__ void gather128_kernel(const unsigned int* __restrict__ rowend,
                                 const unsigned int* __restrict__ deg,
                                 const int* __restrict__ adj,
                                 const float* __restrict__ dinv,
                                 const float4* __restrict__ h4,
                                 float4* __restrict__ out4, int N)
{
    int v = blockIdx.x * 8 + (threadIdx.x >> 5);
    if (v >= N) return;
    int lane = threadIdx.x & 31;
    unsigned int end = rowend[v];
    unsigned int d = deg[v];
    unsigned int k = end - d;
    float4 acc = {0.f, 0.f, 0.f, 0.f};
    for (; k < end; ++k) {
        int s = adj[k];               // wave-broadcast load
        float w = dinv[s];            // wave-broadcast load
        float4 hv = h4[(size_t)s * 32 + lane];  // coalesced 512B per edge
        acc.x += w * hv.x;
        acc.y += w * hv.y;
        acc.z += w * hv.z;
        acc.w += w * hv.w;
    }
    float dv = dinv[v];
    float4 o = {dv * acc.x, dv * acc.y, dv * acc.z, dv * acc.w};
    out4[(size_t)v * 32 + lane] = o;
}

// ---------------- layer 2 dense: (N,128)x2 -> (N,128), relu ----------------
#define L2_NODES 16
__global__ void layer2_kernel(const float* __restrict__ aggI, const float* __restrict__ aggO,
                              const float* __restrict__ Wi, const float* __restrict__ bi,
                              const float* __restrict__ Wr, const float* __restrict__ br,
                              float* __restrict__ h2, int N)
{
    __shared__ float rI[L2_NODES][128];
    __shared__ float rO[L2_NODES][128];
    int j = threadIdx.x;  // 128 threads
    int v0 = blockIdx.x * L2_NODES;
    if (v0 >= N) return;
    int nv = min(L2_NODES, N - v0);
    for (int n = 0; n < nv; ++n) {
        rI[n][j] = aggI[(size_t)(v0 + n) * 128 + j];
        rO[n][j] = aggO[(size_t)(v0 + n) * 128 + j];
    }
    __syncthreads();
    float bcomb = (1.f - ALPHA) * bi[j] + ALPHA * br[j];
    float acc[L2_NODES];
#pragma unroll
    for (int n = 0; n < L2_NODES; ++n) acc[n] = bcomb;
    for (int k = 0; k < 128; ++k) {
        float wi = (1.f - ALPHA) * Wi[k * 128 + j];
        float wo = ALPHA * Wr[k * 128 + j];
#pragma unroll
        for (int n = 0; n < L2_NODES; ++n)
            acc[n] += rI[n][k] * wi + rO[n][k] * wo;
    }
    for (int n = 0; n < nv; ++n)
        h2[(size_t)(v0 + n) * 128 + j] = fmaxf(acc[n], 0.f);
}

// ---------------- pooling of 128-wide aggregated features (batch_seg sorted) -------------
#define POOL_NODES 256
__global__ void pool_kernel(const float* __restrict__ aggI, const float* __restrict__ aggO,
                            const int* __restrict__ seg,
                            float* __restrict__ poolI, float* __restrict__ poolO, int N)
{
    int j = threadIdx.x;  // 128 threads
    int v0 = blockIdx.x * POOL_NODES;
    if (v0 >= N) return;
    int v1 = min(N, v0 + POOL_NODES);
    float aI = 0.f, aO = 0.f;
    int cur = seg[v0];
    for (int v = v0; v < v1; ++v) {
        int g = seg[v];
        if (g != cur) {
            atomicAdd(&poolI[cur * 128 + j], aI);
            atomicAdd(&poolO[cur * 128 + j], aO);
            aI = 0.f; aO = 0.f; cur = g;
        }
        aI += aggI[(size_t)v * 128 + j];
        aO += aggO[(size_t)v * 128 + j];
    }
    atomicAdd(&poolI[cur * 128 + j], aI);
    atomicAdd(&poolO[cur * 128 + j], aO);
}

// ---------------- final: (G,128)x2 -> (G,120) with mean ----------------
__global__ void final_kernel(const float* __restrict__ poolI, const float* __restrict__ poolO,
                             const float* __restrict__ cnt,
                             const float* __restrict__ Wo, const float* __restrict__ bo,
                             const float* __restrict__ Wor, const float* __restrict__ bor,
                             float* __restrict__ out, int G)
{
    int g = blockIdx.x;
    int j = threadIdx.x;  // 120 threads
    if (g >= G || j >= 120) return;
    float acc = 0.f;
    for (int k = 0; k < 128; ++k) {
        acc += poolI[g * 128 + k] * ((1.f - ALPHA) * Wo[k * 120 + j])
             + poolO[g * 128 + k] * (ALPHA * Wor[k * 120 + j]);
    }
    float c = cnt[g];
    float bcomb = (1.f - ALPHA) * bo[j] + ALPHA * bor[j];
    out[g * 120 + j] = (c > 0.f) ? (acc / c + bcomb) : 0.f;
}

extern "C" void kernel_launch(void* const* d_in, const int* in_sizes, int n_in,
                              void* d_out, int out_size, void* d_ws, size_t ws_size,
                              hipStream_t stream)
{
    const float* x      = (const float*)d_in[0];
    const int*   ei     = (const int*)d_in[1];
    const int*   seg    = (const int*)d_in[2];
    const float* W_in   = (const float*)d_in[3];
    const float* b_in   = (const float*)d_in[4];
    const float* W_in_r = (const float*)d_in[5];
    const float* b_in_r = (const float*)d_in[6];
    const float* W_mid  = (const float*)d_in[7];
    const float* b_mid  = (const float*)d_in[8];
    const float* W_mid_r= (const float*)d_in[9];
    const float* b_mid_r= (const float*)d_in[10];
    const float* W_out  = (const float*)d_in[11];
    const float* b_out  = (const float*)d_in[12];
    const float* W_out_r= (const float*)d_in[13];
    const float* b_out_r= (const float*)d_in[14];

    const int N = in_sizes[0] / 4;
    const int E = in_sizes[1] / 2;
    const int G = out_size / 120;
    const int* src = ei;
    const int* dst = ei + E;
    const int NBLK = ceil_div(N, SCAN_B);   // must be <= 1024 (N <= 262144)

    // -------- workspace layout (4-byte units) --------
    char* wsb = (char*)d_ws;
    size_t off = 0;
    auto alloc = [&](size_t elems) { void* p = wsb + off * 4; off += elems; return p; };

    unsigned int* degI  = (unsigned int*)alloc(N);      // zeroed
    unsigned int* degO  = (unsigned int*)alloc(N);      // zeroed
    float*        cnt   = (float*)alloc(G);             // zeroed
    float*        acc4I = (float*)alloc((size_t)N * 4); // zeroed
    float*        acc4O = (float*)alloc((size_t)N * 4); // zeroed
    float*        poolI = (float*)alloc((size_t)G * 128);// zeroed
    float*        poolO = (float*)alloc((size_t)G * 128);// zeroed
    size_t zero_elems = off;
    float*        dinvI = (float*)alloc(N);
    float*        dinvO = (float*)alloc(N);
    unsigned int* rowI  = (unsigned int*)alloc(N);      // exclusive starts -> row ends
    unsigned int* rowO  = (unsigned int*)alloc(N);
    int*          adjI  = (int*)alloc(E);
    int*          adjO  = (int*)alloc(E);
    unsigned int* bsum  = (unsigned int*)alloc(1024);
    off = (off + 3) & ~(size_t)3;                       // 16B align for float4 bufs
    float* bufA = (float*)alloc((size_t)N * 128);       // h1 / h2
    float* bufB = (float*)alloc((size_t)N * 128);       // agg in-direction
    float* bufC = (float*)alloc((size_t)N * 128);       // agg out-direction
    (void)ws_size;

    hipMemsetAsync(d_ws, 0, zero_elems * 4, stream);

    const int T = 256;
    // degrees + per-graph counts
    deg_kernel<<<ceil_div(E, T), T, 0, stream>>>(src, dst, degI, degO, E);
    cnt_kernel<<<ceil_div(N, T), T, 0, stream>>>(seg, cnt, N);
    // exclusive scans -> rowI/rowO, dinv
    scan_blk_kernel<<<NBLK, SCAN_B, 0, stream>>>(degI, rowI, bsum, N);
    scan_top_kernel<<<1, 1024, 0, stream>>>(bsum, NBLK);
    scan_add_kernel<<<NBLK, SCAN_B, 0, stream>>>(rowI, bsum, degI, dinvI, N);
    scan_blk_kernel<<<NBLK, SCAN_B, 0, stream>>>(degO, rowO, bsum, N);
    scan_top_kernel<<<1, 1024, 0, stream>>>(bsum, NBLK);
    scan_add_kernel<<<NBLK, SCAN_B, 0, stream>>>(rowO, bsum, degO, dinvO, N);
    // CSR adjacency (rowI/rowO become row ends)
    scatter_kernel<<<ceil_div(E, T), T, 0, stream>>>(src, dst, rowI, rowO, adjI, adjO, E);

    // layer 1: width-4 agg (atomics, cheap) then dense 4->128
    agg4_kernel<<<ceil_div(E, T), T, 0, stream>>>(src, dst, (const float4*)x,
                                                  dinvI, dinvO, acc4I, acc4O, E);
    layer1_kernel<<<ceil_div(N, L1_NODES), 128, 0, stream>>>(acc4I, acc4O,
                                                             W_in, b_in, W_in_r, b_in_r, bufA, N);
    // layer 2: CSR gathers (atomic-free) then dense 128->128
    gather128_kernel<<<ceil_div(N, 8), 256, 0, stream>>>(rowI, degI, adjI, dinvI,
                                                         (const float4*)bufA, (float4*)bufB, N);
    gather128_kernel<<<ceil_div(N, 8), 256, 0, stream>>>(rowO, degO, adjO, dinvO,
                                                         (const float4*)bufA, (float4*)bufC, N);
    layer2_kernel<<<ceil_div(N, L2_NODES), 128, 0, stream>>>(bufB, bufC,
                                                             W_mid, b_mid, W_mid_r, b_mid_r, bufA, N);
    // layer 3: CSR gathers, then pool + final projection on G graphs only
    gather128_kernel<<<ceil_div(N, 8), 256, 0, stream>>>(rowI, degI, adjI, dinvI,
                                                         (const float4*)bufA, (float4*)bufB, N);
    gather128_kernel<<<ceil_div(N, 8), 256, 0, stream>>>(rowO, degO, adjO, dinvO,
                                                         (const float4*)bufA, (float4*)bufC, N);
    pool_kernel<<<ceil_div(N, POOL_NODES), 128, 0, stream>>>(bufB, bufC, seg, poolI, poolO, N);
    final_kernel<<<G, 128, 0, stream>>>(poolI, poolO, cnt,
                                        W_out, b_out, W_out_r, b_out_r, (float*)d_out, G);
}

// Round 4
// 1448.070 us; speedup vs baseline: 8.3671x; 1.4483x over previous
//
#include <hip/hip_runtime.h>

#define ALPHA 0.5f
#define SCAN_B 256

static inline int ceil_div(int a, int b) { return (a + b - 1) / b; }

// ---------------- degree histogram (int) ----------------
__global__ void deg_kernel(const int* __restrict__ src, const int* __restrict__ dst,
                           unsigned int* __restrict__ degI, unsigned int* __restrict__ degO, int E)
{
    int e = blockIdx.x * blockDim.x + threadIdx.x;
    if (e < E) {
        atomicAdd(&degI[dst[e]], 1u);   // GCN(in): deg over dst
        atomicAdd(&degO[src[e]], 1u);   // GCN(reversed): deg over src
    }
}

// ---------------- exclusive scan: per-block pass ----------------
__global__ void scan_blk_kernel(const unsigned int* __restrict__ deg,
                                unsigned int* __restrict__ excl,
                                unsigned int* __restrict__ bsum, int N)
{
    __shared__ unsigned int tmp[SCAN_B];
    int t = threadIdx.x;
    int i = blockIdx.x * SCAN_B + t;
    unsigned int v = (i < N) ? deg[i] : 0u;
    tmp[t] = v;
    __syncthreads();
    for (int o = 1; o < SCAN_B; o <<= 1) {
        unsigned int x = (t >= o) ? tmp[t - o] : 0u;
        __syncthreads();
        tmp[t] += x;
        __syncthreads();
    }
    if (i < N) excl[i] = tmp[t] - v;               // local exclusive
    if (t == SCAN_B - 1) bsum[blockIdx.x] = tmp[t]; // block total
}

// ---------------- exclusive scan: top-level (single block, nb <= 1024) ----------------
__global__ void scan_top_kernel(unsigned int* __restrict__ bsum, int nb)
{
    __shared__ unsigned int tmp[1024];
    int t = threadIdx.x;
    unsigned int v = (t < nb) ? bsum[t] : 0u;
    tmp[t] = v;
    __syncthreads();
    for (int o = 1; o < 1024; o <<= 1) {
        unsigned int x = (t >= o) ? tmp[t - o] : 0u;
        __syncthreads();
        tmp[t] += x;
        __syncthreads();
    }
    if (t < nb) bsum[t] = tmp[t] - v;              // exclusive block offsets
}

// ---------------- scan finalize: add block offset, compute dinv ----------------
__global__ void scan_add_kernel(unsigned int* __restrict__ excl,
                                const unsigned int* __restrict__ bsum,
                                const unsigned int* __restrict__ deg,
                                float* __restrict__ dinv, int N)
{
    int i = blockIdx.x * SCAN_B + threadIdx.x;
    if (i < N) {
        excl[i] += bsum[blockIdx.x];
        unsigned int d = deg[i];
        dinv[i] = d ? rsqrtf((float)d) : 0.f;
    }
}

// ---------------- per-graph node counts ----------------
__global__ void cnt_kernel(const int* __restrict__ seg, float* __restrict__ cnt, int N)
{
    int v = blockIdx.x * blockDim.x + threadIdx.x;
    if (v < N) atomicAdd(&cnt[seg[v]], 1.0f);
}

// ---------------- CSR scatter (rowptr used as cursor; becomes row END after) ----------------
__global__ void scatter_kernel(const int* __restrict__ src, const int* __restrict__ dst,
                               unsigned int* __restrict__ curI, unsigned int* __restrict__ curO,
                               int* __restrict__ adjI, int* __restrict__ adjO, int E)
{
    int e = blockIdx.x * blockDim.x + threadIdx.x;
    if (e < E) {
        int s = src[e], d = dst[e];
        unsigned int p = atomicAdd(&curI[d], 1u);
        adjI[p] = s;
        unsigned int q = atomicAdd(&curO[s], 1u);
        adjO[q] = d;
    }
}

// ---------------- CSR gather, width 4 (layer 1 pre-projection; atomic-free) ----------------
// One thread per node, both directions in one kernel. x is 1.6 MB -> L2-resident.
__global__ void gather4_kernel(const unsigned int* __restrict__ rowendI,
                               const unsigned int* __restrict__ degI,
                               const int* __restrict__ adjI,
                               const float* __restrict__ dinvI,
                               const unsigned int* __restrict__ rowendO,
                               const unsigned int* __restrict__ degO,
                               const int* __restrict__ adjO,
                               const float* __restrict__ dinvO,
                               const float4* __restrict__ x4,
                               float4* __restrict__ accI, float4* __restrict__ accO, int N)
{
    int v = blockIdx.x * blockDim.x + threadIdx.x;
    if (v >= N) return;
    {
        unsigned int end = rowendI[v], d = degI[v], k = end - d;
        float4 acc = {0.f, 0.f, 0.f, 0.f};
        for (; k < end; ++k) {
            int s = adjI[k];
            float w = dinvI[s];
            float4 xv = x4[s];
            acc.x += w * xv.x; acc.y += w * xv.y; acc.z += w * xv.z; acc.w += w * xv.w;
        }
        float dv = dinvI[v];
        accI[v] = make_float4(dv * acc.x, dv * acc.y, dv * acc.z, dv * acc.w);
    }
    {
        unsigned int end = rowendO[v], d = degO[v], k = end - d;
        float4 acc = {0.f, 0.f, 0.f, 0.f};
        for (; k < end; ++k) {
            int s = adjO[k];
            float w = dinvO[s];
            float4 xv = x4[s];
            acc.x += w * xv.x; acc.y += w * xv.y; acc.z += w * xv.z; acc.w += w * xv.w;
        }
        float dv = dinvO[v];
        accO[v] = make_float4(dv * acc.x, dv * acc.y, dv * acc.z, dv * acc.w);
    }
}

// ---------------- layer 1 dense: (N,4)x2 -> (N,128), relu ----------------
#define L1_NODES 32
__global__ void layer1_kernel(const float* __restrict__ accI, const float* __restrict__ accO,
                              const float* __restrict__ Wi, const float* __restrict__ bi,
                              const float* __restrict__ Wr, const float* __restrict__ br,
                              float* __restrict__ h1, int N)
{
    __shared__ float wI[4][128], wO[4][128], bb[128];
    int j = threadIdx.x;  // 128 threads
    for (int c = 0; c < 4; ++c) {
        wI[c][j] = (1.f - ALPHA) * Wi[c * 128 + j];
        wO[c][j] = ALPHA * Wr[c * 128 + j];
    }
    bb[j] = (1.f - ALPHA) * bi[j] + ALPHA * br[j];
    __syncthreads();
    int v0 = blockIdx.x * L1_NODES;
    int v1 = min(N, v0 + L1_NODES);
    for (int v = v0; v < v1; ++v) {
        float s = bb[j];
#pragma unroll
        for (int c = 0; c < 4; ++c)
            s += accI[v * 4 + c] * wI[c][j] + accO[v * 4 + c] * wO[c][j];
        h1[(size_t)v * 128 + j] = fmaxf(s, 0.f);
    }
}

// ---------------- CSR gather aggregation, width 128 (atomic-free) ----------------
// 32 lanes per node (float4 each); 256-thread block = 8 nodes.
__global__ void gather128_kernel(const unsigned int* __restrict__ rowend,
                                 const unsigned int* __restrict__ deg,
                                 const int* __restrict__ adj,
                                 const float* __restrict__ dinv,
                                 const float4* __restrict__ h4,
                                 float4* __restrict__ out4, int N)
{
    int v = blockIdx.x * 8 + (threadIdx.x >> 5);
    if (v >= N) return;
    int lane = threadIdx.x & 31;
    unsigned int end = rowend[v];
    unsigned int d = deg[v];
    unsigned int k = end - d;
    float4 acc = {0.f, 0.f, 0.f, 0.f};
    for (; k < end; ++k) {
        int s = adj[k];               // wave-broadcast load
        float w = dinv[s];            // wave-broadcast load
        float4 hv = h4[(size_t)s * 32 + lane];  // coalesced 512B per edge
        acc.x += w * hv.x;
        acc.y += w * hv.y;
        acc.z += w * hv.z;
        acc.w += w * hv.w;
    }
    float dv = dinv[v];
    float4 o = {dv * acc.x, dv * acc.y, dv * acc.z, dv * acc.w};
    out4[(size_t)v * 32 + lane] = o;
}

// ---------------- layer 2 dense: (N,128)x2 -> (N,128), relu ----------------
#define L2_NODES 16
__global__ void layer2_kernel(const float* __restrict__ aggI, const float* __restrict__ aggO,
                              const float* __restrict__ Wi, const float* __restrict__ bi,
                              const float* __restrict__ Wr, const float* __restrict__ br,
                              float* __restrict__ h2, int N)
{
    __shared__ float rI[L2_NODES][128];
    __shared__ float rO[L2_NODES][128];
    int j = threadIdx.x;  // 128 threads
    int v0 = blockIdx.x * L2_NODES;
    if (v0 >= N) return;
    int nv = min(L2_NODES, N - v0);
    for (int n = 0; n < nv; ++n) {
        rI[n][j] = aggI[(size_t)(v0 + n) * 128 + j];
        rO[n][j] = aggO[(size_t)(v0 + n) * 128 + j];
    }
    __syncthreads();
    float bcomb = (1.f - ALPHA) * bi[j] + ALPHA * br[j];
    float acc[L2_NODES];
#pragma unroll
    for (int n = 0; n < L2_NODES; ++n) acc[n] = bcomb;
    for (int k = 0; k < 128; ++k) {
        float wi = (1.f - ALPHA) * Wi[k * 128 + j];
        float wo = ALPHA * Wr[k * 128 + j];
#pragma unroll
        for (int n = 0; n < L2_NODES; ++n)
            acc[n] += rI[n][k] * wi + rO[n][k] * wo;
    }
    for (int n = 0; n < nv; ++n)
        h2[(size_t)(v0 + n) * 128 + j] = fmaxf(acc[n], 0.f);
}

// ---------------- pooling of 128-wide aggregated features (batch_seg sorted) -------------
#define POOL_NODES 32
__global__ void pool_kernel(const float* __restrict__ aggI, const float* __restrict__ aggO,
                            const int* __restrict__ seg,
                            float* __restrict__ poolI, float* __restrict__ poolO, int N)
{
    int j = threadIdx.x;  // 128 threads
    int v0 = blockIdx.x * POOL_NODES;
    if (v0 >= N) return;
    int v1 = min(N, v0 + POOL_NODES);
    float aI = 0.f, aO = 0.f;
    int cur = seg[v0];
    for (int v = v0; v < v1; ++v) {
        int g = seg[v];
        if (g != cur) {
            atomicAdd(&poolI[cur * 128 + j], aI);
            atomicAdd(&poolO[cur * 128 + j], aO);
            aI = 0.f; aO = 0.f; cur = g;
        }
        aI += aggI[(size_t)v * 128 + j];
        aO += aggO[(size_t)v * 128 + j];
    }
    atomicAdd(&poolI[cur * 128 + j], aI);
    atomicAdd(&poolO[cur * 128 + j], aO);
}

// ---------------- final: (G,128)x2 -> (G,120) with mean ----------------
__global__ void final_kernel(const float* __restrict__ poolI, const float* __restrict__ poolO,
                             const float* __restrict__ cnt,
                             const float* __restrict__ Wo, const float* __restrict__ bo,
                             const float* __restrict__ Wor, const float* __restrict__ bor,
                             float* __restrict__ out, int G)
{
    int g = blockIdx.x;
    int j = threadIdx.x;  // 120 threads
    if (g >= G || j >= 120) return;
    float acc = 0.f;
    for (int k = 0; k < 128; ++k) {
        acc += poolI[g * 128 + k] * ((1.f - ALPHA) * Wo[k * 120 + j])
             + poolO[g * 128 + k] * (ALPHA * Wor[k * 120 + j]);
    }
    float c = cnt[g];
    float bcomb = (1.f - ALPHA) * bo[j] + ALPHA * bor[j];
    out[g * 120 + j] = (c > 0.f) ? (acc / c + bcomb) : 0.f;
}

extern "C" void kernel_launch(void* const* d_in, const int* in_sizes, int n_in,
                              void* d_out, int out_size, void* d_ws, size_t ws_size,
                              hipStream_t stream)
{
    const float* x      = (const float*)d_in[0];
    const int*   ei     = (const int*)d_in[1];
    const int*   seg    = (const int*)d_in[2];
    const float* W_in   = (const float*)d_in[3];
    const float* b_in   = (const float*)d_in[4];
    const float* W_in_r = (const float*)d_in[5];
    const float* b_in_r = (const float*)d_in[6];
    const float* W_mid  = (const float*)d_in[7];
    const float* b_mid  = (const float*)d_in[8];
    const float* W_mid_r= (const float*)d_in[9];
    const float* b_mid_r= (const float*)d_in[10];
    const float* W_out  = (const float*)d_in[11];
    const float* b_out  = (const float*)d_in[12];
    const float* W_out_r= (const float*)d_in[13];
    const float* b_out_r= (const float*)d_in[14];

    const int N = in_sizes[0] / 4;
    const int E = in_sizes[1] / 2;
    const int G = out_size / 120;
    const int* src = ei;
    const int* dst = ei + E;
    const int NBLK = ceil_div(N, SCAN_B);   // must be <= 1024 (N <= 262144)

    // -------- workspace layout (4-byte units) --------
    char* wsb = (char*)d_ws;
    size_t off = 0;
    auto alloc = [&](size_t elems) { void* p = wsb + off * 4; off += elems; return p; };

    unsigned int* degI  = (unsigned int*)alloc(N);        // zeroed
    unsigned int* degO  = (unsigned int*)alloc(N);        // zeroed
    float*        cnt   = (float*)alloc(G);               // zeroed
    float*        poolI = (float*)alloc((size_t)G * 128); // zeroed
    float*        poolO = (float*)alloc((size_t)G * 128); // zeroed
    size_t zero_elems = off;
    float*        dinvI = (float*)alloc(N);
    float*        dinvO = (float*)alloc(N);
    unsigned int* rowI  = (unsigned int*)alloc(N);        // exclusive starts -> row ends
    unsigned int* rowO  = (unsigned int*)alloc(N);
    int*          adjI  = (int*)alloc(E);
    int*          adjO  = (int*)alloc(E);
    unsigned int* bsum  = (unsigned int*)alloc(1024);
    off = (off + 3) & ~(size_t)3;                         // 16B align for float4 bufs
    float* acc4I = (float*)alloc((size_t)N * 4);          // written fully by gather4
    float* acc4O = (float*)alloc((size_t)N * 4);
    float* bufA  = (float*)alloc((size_t)N * 128);        // h1 / h2
    float* bufB  = (float*)alloc((size_t)N * 128);        // agg in-direction
    float* bufC  = (float*)alloc((size_t)N * 128);        // agg out-direction
    (void)ws_size;

    hipMemsetAsync(d_ws, 0, zero_elems * 4, stream);

    const int T = 256;
    // degrees + per-graph counts
    deg_kernel<<<ceil_div(E, T), T, 0, stream>>>(src, dst, degI, degO, E);
    cnt_kernel<<<ceil_div(N, T), T, 0, stream>>>(seg, cnt, N);
    // exclusive scans -> rowI/rowO, dinv
    scan_blk_kernel<<<NBLK, SCAN_B, 0, stream>>>(degI, rowI, bsum, N);
    scan_top_kernel<<<1, 1024, 0, stream>>>(bsum, NBLK);
    scan_add_kernel<<<NBLK, SCAN_B, 0, stream>>>(rowI, bsum, degI, dinvI, N);
    scan_blk_kernel<<<NBLK, SCAN_B, 0, stream>>>(degO, rowO, bsum, N);
    scan_top_kernel<<<1, 1024, 0, stream>>>(bsum, NBLK);
    scan_add_kernel<<<NBLK, SCAN_B, 0, stream>>>(rowO, bsum, degO, dinvO, N);
    // CSR adjacency (rowI/rowO become row ends)
    scatter_kernel<<<ceil_div(E, T), T, 0, stream>>>(src, dst, rowI, rowO, adjI, adjO, E);

    // layer 1: CSR width-4 gathers (atomic-free) then dense 4->128
    gather4_kernel<<<ceil_div(N, T), T, 0, stream>>>(rowI, degI, adjI, dinvI,
                                                     rowO, degO, adjO, dinvO,
                                                     (const float4*)x,
                                                     (float4*)acc4I, (float4*)acc4O, N);
    layer1_kernel<<<ceil_div(N, L1_NODES), 128, 0, stream>>>(acc4I, acc4O,
                                                             W_in, b_in, W_in_r, b_in_r, bufA, N);
    // layer 2: CSR gathers (atomic-free) then dense 128->128
    gather128_kernel<<<ceil_div(N, 8), 256, 0, stream>>>(rowI, degI, adjI, dinvI,
                                                         (const float4*)bufA, (float4*)bufB, N);
    gather128_kernel<<<ceil_div(N, 8), 256, 0, stream>>>(rowO, degO, adjO, dinvO,
                                                         (const float4*)bufA, (float4*)bufC, N);
    layer2_kernel<<<ceil_div(N, L2_NODES), 128, 0, stream>>>(bufB, bufC,
                                                             W_mid, b_mid, W_mid_r, b_mid_r, bufA, N);
    // layer 3: CSR gathers, then pool + final projection on G graphs only
    gather128_kernel<<<ceil_div(N, 8), 256, 0, stream>>>(rowI, degI, adjI, dinvI,
                                                         (const float4*)bufA, (float4*)bufB, N);
    gather128_kernel<<<ceil_div(N, 8), 256, 0, stream>>>(rowO, degO, adjO, dinvO,
                                                         (const float4*)bufA, (float4*)bufC, N);
    pool_kernel<<<ceil_div(N, POOL_NODES), 128, 0, stream>>>(bufB, bufC, seg, poolI, poolO, N);
    final_kernel<<<G, 128, 0, stream>>>(poolI, poolO, cnt,
                                        W_out, b_out, W_out_r, b_out_r, (float*)d_out, G);
}

// Round 5
// 1137.060 us; speedup vs baseline: 10.6557x; 1.2735x over previous
//
#include <hip/hip_runtime.h>

#define ALPHA 0.5f
#define SCAN_B 256
#define BSH 9            // bucket shift: 512 nodes/bucket
#define BSZ 512          // nodes per bucket
#define MAXB 512         // max buckets -> supports N <= 262144
#define CHUNK 4096       // edges per block in bucket_scatter

static inline int ceil_div(int a, int b) { return (a + b - 1) / b; }

// ---------------- bucket histogram (both directions) ----------------
__global__ void hist_kernel(const int* __restrict__ src, const int* __restrict__ dst,
                            unsigned int* __restrict__ bhI, unsigned int* __restrict__ bhO,
                            int E, int nbuck)
{
    __shared__ unsigned int hI[MAXB], hO[MAXB];
    for (int b = threadIdx.x; b < MAXB; b += blockDim.x) { hI[b] = 0; hO[b] = 0; }
    __syncthreads();
    for (int e = blockIdx.x * blockDim.x + threadIdx.x; e < E; e += gridDim.x * blockDim.x) {
        atomicAdd(&hI[dst[e] >> BSH], 1u);
        atomicAdd(&hO[src[e] >> BSH], 1u);
    }
    __syncthreads();
    for (int b = threadIdx.x; b < nbuck; b += blockDim.x) {
        if (hI[b]) atomicAdd(&bhI[b], hI[b]);
        if (hO[b]) atomicAdd(&bhO[b], hO[b]);
    }
}

// ---------------- bucket bases: exclusive scan of both hists (1 block, MAXB threads) ------
__global__ void bucket_base_kernel(const unsigned int* __restrict__ bhI,
                                   const unsigned int* __restrict__ bhO,
                                   unsigned int* __restrict__ baseI, unsigned int* __restrict__ baseO,
                                   unsigned int* __restrict__ curI, unsigned int* __restrict__ curO,
                                   int nbuck)
{
    __shared__ unsigned int tI[MAXB], tO[MAXB];
    int t = threadIdx.x;
    unsigned int vI = (t < nbuck) ? bhI[t] : 0u;
    unsigned int vO = (t < nbuck) ? bhO[t] : 0u;
    tI[t] = vI; tO[t] = vO;
    __syncthreads();
    for (int o = 1; o < MAXB; o <<= 1) {
        unsigned int xI = (t >= o) ? tI[t - o] : 0u;
        unsigned int xO = (t >= o) ? tO[t - o] : 0u;
        __syncthreads();
        tI[t] += xI; tO[t] += xO;
        __syncthreads();
    }
    if (t < nbuck) {
        baseI[t] = tI[t] - vI; baseO[t] = tO[t] - vO;
        curI[t]  = tI[t] - vI; curO[t]  = tO[t] - vO;
    }
}

// ---------------- bucket scatter with block-local reservation ----------------
// Writes int2(key, payload): direction I keyed by dst (payload src), O keyed by src.
__global__ void bucket_scatter_kernel(const int* __restrict__ src, const int* __restrict__ dst,
                                      unsigned int* __restrict__ curI, unsigned int* __restrict__ curO,
                                      int2* __restrict__ ebI, int2* __restrict__ ebO, int E)
{
    __shared__ unsigned int cI[MAXB], cO[MAXB], bI[MAXB], bO[MAXB];
    int t = threadIdx.x;
    for (int b = t; b < MAXB; b += blockDim.x) { cI[b] = 0; cO[b] = 0; }
    __syncthreads();
    int e0 = blockIdx.x * CHUNK;
    int e1 = min(E, e0 + CHUNK);
    for (int e = e0 + t; e < e1; e += blockDim.x) {
        atomicAdd(&cI[dst[e] >> BSH], 1u);
        atomicAdd(&cO[src[e] >> BSH], 1u);
    }
    __syncthreads();
    for (int b = t; b < MAXB; b += blockDim.x) {
        unsigned int n = cI[b];
        if (n) bI[b] = atomicAdd(&curI[b], n);
        cI[b] = 0;
        n = cO[b];
        if (n) bO[b] = atomicAdd(&curO[b], n);
        cO[b] = 0;
    }
    __syncthreads();
    for (int e = e0 + t; e < e1; e += blockDim.x) {
        int s = src[e], d = dst[e];
        int lb = d >> BSH;
        unsigned int p = bI[lb] + atomicAdd(&cI[lb], 1u);
        ebI[p] = make_int2(d, s);
        lb = s >> BSH;
        p = bO[lb] + atomicAdd(&cO[lb], 1u);
        ebO[p] = make_int2(s, d);
    }
}

// ---------------- per-bucket degree (LDS counters, coalesced write) ----------------
__global__ void bucket_deg_kernel(const int2* __restrict__ eb,
                                  const unsigned int* __restrict__ base,
                                  const unsigned int* __restrict__ bend,
                                  unsigned int* __restrict__ deg, int N)
{
    __shared__ unsigned int d[BSZ];
    int b = blockIdx.x, t = threadIdx.x;
    for (int i = t; i < BSZ; i += blockDim.x) d[i] = 0;
    __syncthreads();
    unsigned int lo = base[b], hi = bend[b];
    int nbase = b << BSH;
    for (unsigned int i = lo + t; i < hi; i += blockDim.x)
        atomicAdd(&d[eb[i].x - nbase], 1u);
    __syncthreads();
    for (int i = t; i < BSZ; i += blockDim.x) {
        int v = nbase + i;
        if (v < N) deg[v] = d[i];
    }
}

// ---------------- per-bucket adjacency scatter (LDS cursors, window-local) ----------------
__global__ void bucket_adj_kernel(const int2* __restrict__ eb,
                                  const unsigned int* __restrict__ base,
                                  const unsigned int* __restrict__ bend,
                                  const unsigned int* __restrict__ rowstart,
                                  int* __restrict__ adj, int N)
{
    __shared__ unsigned int cur[BSZ];
    int b = blockIdx.x, t = threadIdx.x;
    int nbase = b << BSH;
    for (int i = t; i < BSZ; i += blockDim.x) {
        int v = nbase + i;
        cur[i] = (v < N) ? rowstart[v] : 0u;
    }
    __syncthreads();
    unsigned int lo = base[b], hi = bend[b];
    for (unsigned int i = lo + t; i < hi; i += blockDim.x) {
        int2 e = eb[i];
        unsigned int p = atomicAdd(&cur[e.x - nbase], 1u);
        adj[p] = e.y;
    }
}

// ---------------- exclusive scan: per-block pass ----------------
__global__ void scan_blk_kernel(const unsigned int* __restrict__ deg,
                                unsigned int* __restrict__ excl,
                                unsigned int* __restrict__ bsum, int N)
{
    __shared__ unsigned int tmp[SCAN_B];
    int t = threadIdx.x;
    int i = blockIdx.x * SCAN_B + t;
    unsigned int v = (i < N) ? deg[i] : 0u;
    tmp[t] = v;
    __syncthreads();
    for (int o = 1; o < SCAN_B; o <<= 1) {
        unsigned int x = (t >= o) ? tmp[t - o] : 0u;
        __syncthreads();
        tmp[t] += x;
        __syncthreads();
    }
    if (i < N) excl[i] = tmp[t] - v;
    if (t == SCAN_B - 1) bsum[blockIdx.x] = tmp[t];
}

// ---------------- exclusive scan: top-level (single block, nb <= 1024) ----------------
__global__ void scan_top_kernel(unsigned int* __restrict__ bsum, int nb)
{
    __shared__ unsigned int tmp[1024];
    int t = threadIdx.x;
    unsigned int v = (t < nb) ? bsum[t] : 0u;
    tmp[t] = v;
    __syncthreads();
    for (int o = 1; o < 1024; o <<= 1) {
        unsigned int x = (t >= o) ? tmp[t - o] : 0u;
        __syncthreads();
        tmp[t] += x;
        __syncthreads();
    }
    if (t < nb) bsum[t] = tmp[t] - v;
}

// ---------------- scan finalize: add block offset, compute dinv ----------------
__global__ void scan_add_kernel(unsigned int* __restrict__ excl,
                                const unsigned int* __restrict__ bsum,
                                const unsigned int* __restrict__ deg,
                                float* __restrict__ dinv, int N)
{
    int i = blockIdx.x * SCAN_B + threadIdx.x;
    if (i < N) {
        excl[i] += bsum[blockIdx.x];
        unsigned int d = deg[i];
        dinv[i] = d ? rsqrtf((float)d) : 0.f;
    }
}

// ---------------- per-graph node counts ----------------
__global__ void cnt_kernel(const int* __restrict__ seg, float* __restrict__ cnt, int N)
{
    int v = blockIdx.x * blockDim.x + threadIdx.x;
    if (v < N) atomicAdd(&cnt[seg[v]], 1.0f);
}

// ---------------- CSR gather, width 4 (layer 1 pre-projection) ----------------
__global__ void gather4_kernel(const unsigned int* __restrict__ rowI,
                               const unsigned int* __restrict__ degI,
                               const int* __restrict__ adjI,
                               const float* __restrict__ dinvI,
                               const unsigned int* __restrict__ rowO,
                               const unsigned int* __restrict__ degO,
                               const int* __restrict__ adjO,
                               const float* __restrict__ dinvO,
                               const float4* __restrict__ x4,
                               float4* __restrict__ accI, float4* __restrict__ accO, int N)
{
    int v = blockIdx.x * blockDim.x + threadIdx.x;
    if (v >= N) return;
    {
        unsigned int k = rowI[v], end = k + degI[v];
        float4 acc = {0.f, 0.f, 0.f, 0.f};
        for (; k < end; ++k) {
            int s = adjI[k];
            float w = dinvI[s];
            float4 xv = x4[s];
            acc.x += w * xv.x; acc.y += w * xv.y; acc.z += w * xv.z; acc.w += w * xv.w;
        }
        float dv = dinvI[v];
        accI[v] = make_float4(dv * acc.x, dv * acc.y, dv * acc.z, dv * acc.w);
    }
    {
        unsigned int k = rowO[v], end = k + degO[v];
        float4 acc = {0.f, 0.f, 0.f, 0.f};
        for (; k < end; ++k) {
            int s = adjO[k];
            float w = dinvO[s];
            float4 xv = x4[s];
            acc.x += w * xv.x; acc.y += w * xv.y; acc.z += w * xv.z; acc.w += w * xv.w;
        }
        float dv = dinvO[v];
        accO[v] = make_float4(dv * acc.x, dv * acc.y, dv * acc.z, dv * acc.w);
    }
}

// ---------------- layer 1 dense: (N,4)x2 -> (N,128), relu ----------------
#define L1_NODES 32
__global__ void layer1_kernel(const float* __restrict__ accI, const float* __restrict__ accO,
                              const float* __restrict__ Wi, const float* __restrict__ bi,
                              const float* __restrict__ Wr, const float* __restrict__ br,
                              float* __restrict__ h1, int N)
{
    __shared__ float wI[4][128], wO[4][128], bb[128];
    int j = threadIdx.x;  // 128 threads
    for (int c = 0; c < 4; ++c) {
        wI[c][j] = (1.f - ALPHA) * Wi[c * 128 + j];
        wO[c][j] = ALPHA * Wr[c * 128 + j];
    }
    bb[j] = (1.f - ALPHA) * bi[j] + ALPHA * br[j];
    __syncthreads();
    int v0 = blockIdx.x * L1_NODES;
    int v1 = min(N, v0 + L1_NODES);
    for (int v = v0; v < v1; ++v) {
        float s = bb[j];
#pragma unroll
        for (int c = 0; c < 4; ++c)
            s += accI[v * 4 + c] * wI[c][j] + accO[v * 4 + c] * wO[c][j];
        h1[(size_t)v * 128 + j] = fmaxf(s, 0.f);
    }
}

// ---------------- CSR gather aggregation, width 128 (atomic-free) ----------------
__global__ void gather128_kernel(const unsigned int* __restrict__ rowstart,
                                 const unsigned int* __restrict__ deg,
                                 const int* __restrict__ adj,
                                 const float* __restrict__ dinv,
                                 const float4* __restrict__ h4,
                                 float4* __restrict__ out4, int N)
{
    int v = blockIdx.x * 8 + (threadIdx.x >> 5);
    if (v >= N) return;
    int lane = threadIdx.x & 31;
    unsigned int k = rowstart[v];
    unsigned int end = k + deg[v];
    float4 acc = {0.f, 0.f, 0.f, 0.f};
    for (; k < end; ++k) {
        int s = adj[k];               // wave-broadcast load
        float w = dinv[s];            // wave-broadcast load
        float4 hv = h4[(size_t)s * 32 + lane];  // coalesced 512B per edge
        acc.x += w * hv.x;
        acc.y += w * hv.y;
        acc.z += w * hv.z;
        acc.w += w * hv.w;
    }
    float dv = dinv[v];
    float4 o = {dv * acc.x, dv * acc.y, dv * acc.z, dv * acc.w};
    out4[(size_t)v * 32 + lane] = o;
}

// ---------------- layer 2 dense: (N,128)x2 -> (N,128), relu ----------------
#define L2_NODES 16
__global__ void layer2_kernel(const float* __restrict__ aggI, const float* __restrict__ aggO,
                              const float* __restrict__ Wi, const float* __restrict__ bi,
                              const float* __restrict__ Wr, const float* __restrict__ br,
                              float* __restrict__ h2, int N)
{
    __shared__ float rI[L2_NODES][128];
    __shared__ float rO[L2_NODES][128];
    int j = threadIdx.x;  // 128 threads
    int v0 = blockIdx.x * L2_NODES;
    if (v0 >= N) return;
    int nv = min(L2_NODES, N - v0);
    for (int n = 0; n < nv; ++n) {
        rI[n][j] = aggI[(size_t)(v0 + n) * 128 + j];
        rO[n][j] = aggO[(size_t)(v0 + n) * 128 + j];
    }
    __syncthreads();
    float bcomb = (1.f - ALPHA) * bi[j] + ALPHA * br[j];
    float acc[L2_NODES];
#pragma unroll
    for (int n = 0; n < L2_NODES; ++n) acc[n] = bcomb;
    for (int k = 0; k < 128; ++k) {
        float wi = (1.f - ALPHA) * Wi[k * 128 + j];
        float wo = ALPHA * Wr[k * 128 + j];
#pragma unroll
        for (int n = 0; n < L2_NODES; ++n)
            acc[n] += rI[n][k] * wi + rO[n][k] * wo;
    }
    for (int n = 0; n < nv; ++n)
        h2[(size_t)(v0 + n) * 128 + j] = fmaxf(acc[n], 0.f);
}

// ---------------- pooling of 128-wide aggregated features (batch_seg sorted) -------------
#define POOL_NODES 32
__global__ void pool_kernel(const float* __restrict__ aggI, const float* __restrict__ aggO,
                            const int* __restrict__ seg,
                            float* __restrict__ poolI, float* __restrict__ poolO, int N)
{
    int j = threadIdx.x;  // 128 threads
    int v0 = blockIdx.x * POOL_NODES;
    if (v0 >= N) return;
    int v1 = min(N, v0 + POOL_NODES);
    float aI = 0.f, aO = 0.f;
    int cur = seg[v0];
    for (int v = v0; v < v1; ++v) {
        int g = seg[v];
        if (g != cur) {
            atomicAdd(&poolI[cur * 128 + j], aI);
            atomicAdd(&poolO[cur * 128 + j], aO);
            aI = 0.f; aO = 0.f; cur = g;
        }
        aI += aggI[(size_t)v * 128 + j];
        aO += aggO[(size_t)v * 128 + j];
    }
    atomicAdd(&poolI[cur * 128 + j], aI);
    atomicAdd(&poolO[cur * 128 + j], aO);
}

// ---------------- final: (G,128)x2 -> (G,120) with mean ----------------
__global__ void final_kernel(const float* __restrict__ poolI, const float* __restrict__ poolO,
                             const float* __restrict__ cnt,
                             const float* __restrict__ Wo, const float* __restrict__ bo,
                             const float* __restrict__ Wor, const float* __restrict__ bor,
                             float* __restrict__ out, int G)
{
    int g = blockIdx.x;
    int j = threadIdx.x;  // 120 threads
    if (g >= G || j >= 120) return;
    float acc = 0.f;
    for (int k = 0; k < 128; ++k) {
        acc += poolI[g * 128 + k] * ((1.f - ALPHA) * Wo[k * 120 + j])
             + poolO[g * 128 + k] * (ALPHA * Wor[k * 120 + j]);
    }
    float c = cnt[g];
    float bcomb = (1.f - ALPHA) * bo[j] + ALPHA * bor[j];
    out[g * 120 + j] = (c > 0.f) ? (acc / c + bcomb) : 0.f;
}

extern "C" void kernel_launch(void* const* d_in, const int* in_sizes, int n_in,
                              void* d_out, int out_size, void* d_ws, size_t ws_size,
                              hipStream_t stream)
{
    const float* x      = (const float*)d_in[0];
    const int*   ei     = (const int*)d_in[1];
    const int*   seg    = (const int*)d_in[2];
    const float* W_in   = (const float*)d_in[3];
    const float* b_in   = (const float*)d_in[4];
    const float* W_in_r = (const float*)d_in[5];
    const float* b_in_r = (const float*)d_in[6];
    const float* W_mid  = (const float*)d_in[7];
    const float* b_mid  = (const float*)d_in[8];
    const float* W_mid_r= (const float*)d_in[9];
    const float* b_mid_r= (const float*)d_in[10];
    const float* W_out  = (const float*)d_in[11];
    const float* b_out  = (const float*)d_in[12];
    const float* W_out_r= (const float*)d_in[13];
    const float* b_out_r= (const float*)d_in[14];

    const int N = in_sizes[0] / 4;
    const int E = in_sizes[1] / 2;
    const int G = out_size / 120;
    const int* src = ei;
    const int* dst = ei + E;
    const int NBLK  = ceil_div(N, SCAN_B);   // <= 1024 (N <= 262144)
    const int NBUCK = ceil_div(N, BSZ);      // <= 512

    // -------- workspace layout (4-byte units) --------
    char* wsb = (char*)d_ws;
    size_t off = 0;
    auto alloc = [&](size_t elems) { void* p = wsb + off * 4; off += elems; return p; };

    unsigned int* bhI   = (unsigned int*)alloc(MAXB);     // zeroed
    unsigned int* bhO   = (unsigned int*)alloc(MAXB);     // zeroed
    float*        cnt   = (float*)alloc(G);               // zeroed
    float*        poolI = (float*)alloc((size_t)G * 128); // zeroed
    float*        poolO = (float*)alloc((size_t)G * 128); // zeroed
    size_t zero_elems = off;
    unsigned int* baseI = (unsigned int*)alloc(MAXB);
    unsigned int* baseO = (unsigned int*)alloc(MAXB);
    unsigned int* curI  = (unsigned int*)alloc(MAXB);
    unsigned int* curO  = (unsigned int*)alloc(MAXB);
    unsigned int* degI  = (unsigned int*)alloc(N);
    unsigned int* degO  = (unsigned int*)alloc(N);
    float*        dinvI = (float*)alloc(N);
    float*        dinvO = (float*)alloc(N);
    unsigned int* rowI  = (unsigned int*)alloc(N);        // exclusive row starts
    unsigned int* rowO  = (unsigned int*)alloc(N);
    int*          adjI  = (int*)alloc(E);
    int*          adjO  = (int*)alloc(E);
    unsigned int* bsum  = (unsigned int*)alloc(1024);
    off = (off + 3) & ~(size_t)3;                         // 16B align
    float* acc4I = (float*)alloc((size_t)N * 4);
    float* acc4O = (float*)alloc((size_t)N * 4);
    float* bufA  = (float*)alloc((size_t)N * 128);        // h1 / h2
    float* bufB  = (float*)alloc((size_t)N * 128);        // agg in-direction
    float* bufC  = (float*)alloc((size_t)N * 128);        // agg out-direction
    (void)ws_size;

    // Bucketed edge buffers alias bufB/bufC (dead until gather128 writes them).
    int2* ebI = (int2*)bufB;
    int2* ebO = (int2*)bufC;

    hipMemsetAsync(d_ws, 0, zero_elems * 4, stream);

    const int T = 256;
    // ---- binned CSR build ----
    hist_kernel<<<ceil_div(E, T * 16), T, 0, stream>>>(src, dst, bhI, bhO, E, NBUCK);
    bucket_base_kernel<<<1, MAXB, 0, stream>>>(bhI, bhO, baseI, baseO, curI, curO, NBUCK);
    bucket_scatter_kernel<<<ceil_div(E, CHUNK), T, 0, stream>>>(src, dst, curI, curO, ebI, ebO, E);
    // after bucket_scatter, curI[b]/curO[b] == bucket end
    bucket_deg_kernel<<<NBUCK, T, 0, stream>>>(ebI, baseI, curI, degI, N);
    bucket_deg_kernel<<<NBUCK, T, 0, stream>>>(ebO, baseO, curO, degO, N);
    scan_blk_kernel<<<NBLK, SCAN_B, 0, stream>>>(degI, rowI, bsum, N);
    scan_top_kernel<<<1, 1024, 0, stream>>>(bsum, NBLK);
    scan_add_kernel<<<NBLK, SCAN_B, 0, stream>>>(rowI, bsum, degI, dinvI, N);
    scan_blk_kernel<<<NBLK, SCAN_B, 0, stream>>>(degO, rowO, bsum, N);
    scan_top_kernel<<<1, 1024, 0, stream>>>(bsum, NBLK);
    scan_add_kernel<<<NBLK, SCAN_B, 0, stream>>>(rowO, bsum, degO, dinvO, N);
    bucket_adj_kernel<<<NBUCK, T, 0, stream>>>(ebI, baseI, curI, rowI, adjI, N);
    bucket_adj_kernel<<<NBUCK, T, 0, stream>>>(ebO, baseO, curO, rowO, adjO, N);
    cnt_kernel<<<ceil_div(N, T), T, 0, stream>>>(seg, cnt, N);

    // ---- layer 1: width-4 gathers then dense 4->128 ----
    gather4_kernel<<<ceil_div(N, T), T, 0, stream>>>(rowI, degI, adjI, dinvI,
                                                     rowO, degO, adjO, dinvO,
                                                     (const float4*)x,
                                                     (float4*)acc4I, (float4*)acc4O, N);
    layer1_kernel<<<ceil_div(N, L1_NODES), 128, 0, stream>>>(acc4I, acc4O,
                                                             W_in, b_in, W_in_r, b_in_r, bufA, N);
    // ---- layer 2: gathers then dense 128->128 ----
    gather128_kernel<<<ceil_div(N, 8), 256, 0, stream>>>(rowI, degI, adjI, dinvI,
                                                         (const float4*)bufA, (float4*)bufB, N);
    gather128_kernel<<<ceil_div(N, 8), 256, 0, stream>>>(rowO, degO, adjO, dinvO,
                                                         (const float4*)bufA, (float4*)bufC, N);
    layer2_kernel<<<ceil_div(N, L2_NODES), 128, 0, stream>>>(bufB, bufC,
                                                             W_mid, b_mid, W_mid_r, b_mid_r, bufA, N);
    // ---- layer 3: gathers, pool, final projection ----
    gather128_kernel<<<ceil_div(N, 8), 256, 0, stream>>>(rowI, degI, adjI, dinvI,
                                                         (const float4*)bufA, (float4*)bufB, N);
    gather128_kernel<<<ceil_div(N, 8), 256, 0, stream>>>(rowO, degO, adjO, dinvO,
                                                         (const float4*)bufA, (float4*)bufC, N);
    pool_kernel<<<ceil_div(N, POOL_NODES), 128, 0, stream>>>(bufB, bufC, seg, poolI, poolO, N);
    final_kernel<<<G, 128, 0, stream>>>(poolI, poolO, cnt,
                                        W_out, b_out, W_out_r, b_out_r, (float*)d_out, G);
}

// Round 6
// 1068.810 us; speedup vs baseline: 11.3361x; 1.0639x over previous
//
#include <hip/hip_runtime.h>

#define ALPHA 0.5f
#define SCAN_B 256
#define BSH 9            // bucket shift: 512 nodes/bucket
#define BSZ 512          // nodes per bucket
#define MAXB 512         // max buckets -> supports N <= 262144
#define CHUNK 4096       // edges per block in bucket_scatter

static inline int ceil_div(int a, int b) { return (a + b - 1) / b; }

// ---------------- bucket histogram (both directions) ----------------
__global__ void hist_kernel(const int* __restrict__ src, const int* __restrict__ dst,
                            unsigned int* __restrict__ bhI, unsigned int* __restrict__ bhO,
                            int E, int nbuck)
{
    __shared__ unsigned int hI[MAXB], hO[MAXB];
    for (int b = threadIdx.x; b < MAXB; b += blockDim.x) { hI[b] = 0; hO[b] = 0; }
    __syncthreads();
    for (int e = blockIdx.x * blockDim.x + threadIdx.x; e < E; e += gridDim.x * blockDim.x) {
        atomicAdd(&hI[dst[e] >> BSH], 1u);
        atomicAdd(&hO[src[e] >> BSH], 1u);
    }
    __syncthreads();
    for (int b = threadIdx.x; b < nbuck; b += blockDim.x) {
        if (hI[b]) atomicAdd(&bhI[b], hI[b]);
        if (hO[b]) atomicAdd(&bhO[b], hO[b]);
    }
}

// ---------------- bucket bases: exclusive scan of both hists (1 block, MAXB threads) ------
__global__ void bucket_base_kernel(const unsigned int* __restrict__ bhI,
                                   const unsigned int* __restrict__ bhO,
                                   unsigned int* __restrict__ baseI, unsigned int* __restrict__ baseO,
                                   unsigned int* __restrict__ curI, unsigned int* __restrict__ curO,
                                   int nbuck)
{
    __shared__ unsigned int tI[MAXB], tO[MAXB];
    int t = threadIdx.x;
    unsigned int vI = (t < nbuck) ? bhI[t] : 0u;
    unsigned int vO = (t < nbuck) ? bhO[t] : 0u;
    tI[t] = vI; tO[t] = vO;
    __syncthreads();
    for (int o = 1; o < MAXB; o <<= 1) {
        unsigned int xI = (t >= o) ? tI[t - o] : 0u;
        unsigned int xO = (t >= o) ? tO[t - o] : 0u;
        __syncthreads();
        tI[t] += xI; tO[t] += xO;
        __syncthreads();
    }
    if (t < nbuck) {
        baseI[t] = tI[t] - vI; baseO[t] = tO[t] - vO;
        curI[t]  = tI[t] - vI; curO[t]  = tO[t] - vO;
    }
}

// ---------------- bucket scatter with block-local reservation ----------------
__global__ void bucket_scatter_kernel(const int* __restrict__ src, const int* __restrict__ dst,
                                      unsigned int* __restrict__ curI, unsigned int* __restrict__ curO,
                                      int2* __restrict__ ebI, int2* __restrict__ ebO, int E)
{
    __shared__ unsigned int cI[MAXB], cO[MAXB], bI[MAXB], bO[MAXB];
    int t = threadIdx.x;
    for (int b = t; b < MAXB; b += blockDim.x) { cI[b] = 0; cO[b] = 0; }
    __syncthreads();
    int e0 = blockIdx.x * CHUNK;
    int e1 = min(E, e0 + CHUNK);
    for (int e = e0 + t; e < e1; e += blockDim.x) {
        atomicAdd(&cI[dst[e] >> BSH], 1u);
        atomicAdd(&cO[src[e] >> BSH], 1u);
    }
    __syncthreads();
    for (int b = t; b < MAXB; b += blockDim.x) {
        unsigned int n = cI[b];
        if (n) bI[b] = atomicAdd(&curI[b], n);
        cI[b] = 0;
        n = cO[b];
        if (n) bO[b] = atomicAdd(&curO[b], n);
        cO[b] = 0;
    }
    __syncthreads();
    for (int e = e0 + t; e < e1; e += blockDim.x) {
        int s = src[e], d = dst[e];
        int lb = d >> BSH;
        unsigned int p = bI[lb] + atomicAdd(&cI[lb], 1u);
        ebI[p] = make_int2(d, s);
        lb = s >> BSH;
        p = bO[lb] + atomicAdd(&cO[lb], 1u);
        ebO[p] = make_int2(s, d);
    }
}

// ---------------- per-bucket degree (LDS counters, coalesced write) ----------------
__global__ void bucket_deg_kernel(const int2* __restrict__ eb,
                                  const unsigned int* __restrict__ base,
                                  const unsigned int* __restrict__ bend,
                                  unsigned int* __restrict__ deg, int N)
{
    __shared__ unsigned int d[BSZ];
    int b = blockIdx.x, t = threadIdx.x;
    for (int i = t; i < BSZ; i += blockDim.x) d[i] = 0;
    __syncthreads();
    unsigned int lo = base[b], hi = bend[b];
    int nbase = b << BSH;
    for (unsigned int i = lo + t; i < hi; i += blockDim.x)
        atomicAdd(&d[eb[i].x - nbase], 1u);
    __syncthreads();
    for (int i = t; i < BSZ; i += blockDim.x) {
        int v = nbase + i;
        if (v < N) deg[v] = d[i];
    }
}

// ---------------- per-bucket adjacency scatter (LDS cursors, window-local) ----------------
__global__ void bucket_adj_kernel(const int2* __restrict__ eb,
                                  const unsigned int* __restrict__ base,
                                  const unsigned int* __restrict__ bend,
                                  const unsigned int* __restrict__ rowstart,
                                  int* __restrict__ adj, int N)
{
    __shared__ unsigned int cur[BSZ];
    int b = blockIdx.x, t = threadIdx.x;
    int nbase = b << BSH;
    for (int i = t; i < BSZ; i += blockDim.x) {
        int v = nbase + i;
        cur[i] = (v < N) ? rowstart[v] : 0u;
    }
    __syncthreads();
    unsigned int lo = base[b], hi = bend[b];
    for (unsigned int i = lo + t; i < hi; i += blockDim.x) {
        int2 e = eb[i];
        unsigned int p = atomicAdd(&cur[e.x - nbase], 1u);
        adj[p] = e.y;
    }
}

// ---------------- exclusive scan: per-block pass ----------------
__global__ void scan_blk_kernel(const unsigned int* __restrict__ deg,
                                unsigned int* __restrict__ excl,
                                unsigned int* __restrict__ bsum, int N)
{
    __shared__ unsigned int tmp[SCAN_B];
    int t = threadIdx.x;
    int i = blockIdx.x * SCAN_B + t;
    unsigned int v = (i < N) ? deg[i] : 0u;
    tmp[t] = v;
    __syncthreads();
    for (int o = 1; o < SCAN_B; o <<= 1) {
        unsigned int x = (t >= o) ? tmp[t - o] : 0u;
        __syncthreads();
        tmp[t] += x;
        __syncthreads();
    }
    if (i < N) excl[i] = tmp[t] - v;
    if (t == SCAN_B - 1) bsum[blockIdx.x] = tmp[t];
}

// ---------------- exclusive scan: top-level (single block, nb <= 1024) ----------------
__global__ void scan_top_kernel(unsigned int* __restrict__ bsum, int nb)
{
    __shared__ unsigned int tmp[1024];
    int t = threadIdx.x;
    unsigned int v = (t < nb) ? bsum[t] : 0u;
    tmp[t] = v;
    __syncthreads();
    for (int o = 1; o < 1024; o <<= 1) {
        unsigned int x = (t >= o) ? tmp[t - o] : 0u;
        __syncthreads();
        tmp[t] += x;
        __syncthreads();
    }
    if (t < nb) bsum[t] = tmp[t] - v;
}

// ---------------- scan finalize: add block offset, compute dinv ----------------
__global__ void scan_add_kernel(unsigned int* __restrict__ excl,
                                const unsigned int* __restrict__ bsum,
                                const unsigned int* __restrict__ deg,
                                float* __restrict__ dinv, int N)
{
    int i = blockIdx.x * SCAN_B + threadIdx.x;
    if (i < N) {
        excl[i] += bsum[blockIdx.x];
        unsigned int d = deg[i];
        dinv[i] = d ? rsqrtf((float)d) : 0.f;
    }
}

// ---------------- per-graph node counts ----------------
__global__ void cnt_kernel(const int* __restrict__ seg, float* __restrict__ cnt, int N)
{
    int v = blockIdx.x * blockDim.x + threadIdx.x;
    if (v < N) atomicAdd(&cnt[seg[v]], 1.0f);
}

// ---------------- CSR gather, width 4 (layer 1 pre-projection) ----------------
__global__ void gather4_kernel(const unsigned int* __restrict__ rowI,
                               const unsigned int* __restrict__ degI,
                               const int* __restrict__ adjI,
                               const float* __restrict__ dinvI,
                               const unsigned int* __restrict__ rowO,
                               const unsigned int* __restrict__ degO,
                               const int* __restrict__ adjO,
                               const float* __restrict__ dinvO,
                               const float4* __restrict__ x4,
                               float4* __restrict__ accI, float4* __restrict__ accO, int N)
{
    int v = blockIdx.x * blockDim.x + threadIdx.x;
    if (v >= N) return;
    {
        unsigned int k = rowI[v], end = k + degI[v];
        float4 acc = {0.f, 0.f, 0.f, 0.f};
        for (; k < end; ++k) {
            int s = adjI[k];
            float w = dinvI[s];
            float4 xv = x4[s];
            acc.x += w * xv.x; acc.y += w * xv.y; acc.z += w * xv.z; acc.w += w * xv.w;
        }
        float dv = dinvI[v];
        accI[v] = make_float4(dv * acc.x, dv * acc.y, dv * acc.z, dv * acc.w);
    }
    {
        unsigned int k = rowO[v], end = k + degO[v];
        float4 acc = {0.f, 0.f, 0.f, 0.f};
        for (; k < end; ++k) {
            int s = adjO[k];
            float w = dinvO[s];
            float4 xv = x4[s];
            acc.x += w * xv.x; acc.y += w * xv.y; acc.z += w * xv.z; acc.w += w * xv.w;
        }
        float dv = dinvO[v];
        accO[v] = make_float4(dv * acc.x, dv * acc.y, dv * acc.z, dv * acc.w);
    }
}

// ---------------- layer 1 dense: (N,4)x2 -> (N,128), relu ----------------
#define L1_NODES 32
__global__ void layer1_kernel(const float* __restrict__ accI, const float* __restrict__ accO,
                              const float* __restrict__ Wi, const float* __restrict__ bi,
                              const float* __restrict__ Wr, const float* __restrict__ br,
                              float* __restrict__ h1, int N)
{
    __shared__ float wI[4][128], wO[4][128], bb[128];
    int j = threadIdx.x;  // 128 threads
    for (int c = 0; c < 4; ++c) {
        wI[c][j] = (1.f - ALPHA) * Wi[c * 128 + j];
        wO[c][j] = ALPHA * Wr[c * 128 + j];
    }
    bb[j] = (1.f - ALPHA) * bi[j] + ALPHA * br[j];
    __syncthreads();
    int v0 = blockIdx.x * L1_NODES;
    int v1 = min(N, v0 + L1_NODES);
    for (int v = v0; v < v1; ++v) {
        float s = bb[j];
#pragma unroll
        for (int c = 0; c < 4; ++c)
            s += accI[v * 4 + c] * wI[c][j] + accO[v * 4 + c] * wO[c][j];
        h1[(size_t)v * 128 + j] = fmaxf(s, 0.f);
    }
}

// ---------------- CSR gather aggregation, width 128, both dirs (blockIdx.y) --------------
// 32 lanes per node (float4 each); 256-thread block = 8 nodes. Edge loop unrolled x2.
__global__ void gather128_kernel(const unsigned int* __restrict__ rowstartI,
                                 const unsigned int* __restrict__ degI,
                                 const int* __restrict__ adjI,
                                 const float* __restrict__ dinvI,
                                 const unsigned int* __restrict__ rowstartO,
                                 const unsigned int* __restrict__ degO,
                                 const int* __restrict__ adjO,
                                 const float* __restrict__ dinvO,
                                 const float4* __restrict__ h4,
                                 float4* __restrict__ outI4, float4* __restrict__ outO4, int N)
{
    int v = blockIdx.x * 8 + (threadIdx.x >> 5);
    if (v >= N) return;
    int lane = threadIdx.x & 31;
    const unsigned int* __restrict__ rowstart = blockIdx.y ? rowstartO : rowstartI;
    const unsigned int* __restrict__ deg      = blockIdx.y ? degO : degI;
    const int* __restrict__ adj               = blockIdx.y ? adjO : adjI;
    const float* __restrict__ dinv            = blockIdx.y ? dinvO : dinvI;
    float4* __restrict__ out4                 = blockIdx.y ? outO4 : outI4;

    unsigned int k = rowstart[v];
    unsigned int end = k + deg[v];
    float4 acc = {0.f, 0.f, 0.f, 0.f};
    for (; k + 2 <= end; k += 2) {
        int s0 = adj[k], s1 = adj[k + 1];
        float w0 = dinv[s0], w1 = dinv[s1];
        float4 h0 = h4[(size_t)s0 * 32 + lane];
        float4 h1 = h4[(size_t)s1 * 32 + lane];
        acc.x += w0 * h0.x + w1 * h1.x;
        acc.y += w0 * h0.y + w1 * h1.y;
        acc.z += w0 * h0.z + w1 * h1.z;
        acc.w += w0 * h0.w + w1 * h1.w;
    }
    if (k < end) {
        int s = adj[k];
        float w = dinv[s];
        float4 hv = h4[(size_t)s * 32 + lane];
        acc.x += w * hv.x; acc.y += w * hv.y; acc.z += w * hv.z; acc.w += w * hv.w;
    }
    float dv = dinv[v];
    float4 o = {dv * acc.x, dv * acc.y, dv * acc.z, dv * acc.w};
    out4[(size_t)v * 32 + lane] = o;
}

// ---------------- layer 2 dense, register-blocked: (N,128)x2 -> (N,128), relu -----------
// 256 threads, 32 nodes x 128 outputs per block. Thread tile: 4 nodes x 4 outputs, k unroll 4.
__global__ __launch_bounds__(256) void layer2_kernel(
    const float4* __restrict__ aggI4, const float4* __restrict__ aggO4,
    const float* __restrict__ Wi, const float* __restrict__ bi,
    const float* __restrict__ Wr, const float* __restrict__ br,
    float* __restrict__ h2, int N)
{
    __shared__ float sI[32][128];
    __shared__ float sO[32][128];
    int tid = threadIdx.x;
    int v0 = blockIdx.x * 32;
    // stage 32 nodes x 128 f32 per buffer (1024 float4); 4 per thread, coalesced
#pragma unroll
    for (int i = 0; i < 4; ++i) {
        int f = tid + i * 256;
        int n = f >> 5, kq = f & 31;
        int v = v0 + n;
        float4 a = (v < N) ? aggI4[(size_t)v * 32 + kq] : make_float4(0.f, 0.f, 0.f, 0.f);
        float4 b = (v < N) ? aggO4[(size_t)v * 32 + kq] : make_float4(0.f, 0.f, 0.f, 0.f);
        *(float4*)&sI[n][kq * 4] = a;
        *(float4*)&sO[n][kq * 4] = b;
    }
    __syncthreads();

    int jg = tid & 31;  int j0 = jg * 4;   // 4 outputs
    int ng = tid >> 5;  int n0 = ng * 4;   // 4 nodes
    float accI[4][4], accO[4][4];
#pragma unroll
    for (int n = 0; n < 4; ++n)
#pragma unroll
        for (int j = 0; j < 4; ++j) { accI[n][j] = 0.f; accO[n][j] = 0.f; }

    for (int kq = 0; kq < 32; ++kq) {
        int k = kq * 4;
        float4 wi0 = *(const float4*)&Wi[(k + 0) * 128 + j0];
        float4 wi1 = *(const float4*)&Wi[(k + 1) * 128 + j0];
        float4 wi2 = *(const float4*)&Wi[(k + 2) * 128 + j0];
        float4 wi3 = *(const float4*)&Wi[(k + 3) * 128 + j0];
        float4 wo0 = *(const float4*)&Wr[(k + 0) * 128 + j0];
        float4 wo1 = *(const float4*)&Wr[(k + 1) * 128 + j0];
        float4 wo2 = *(const float4*)&Wr[(k + 2) * 128 + j0];
        float4 wo3 = *(const float4*)&Wr[(k + 3) * 128 + j0];
#pragma unroll
        for (int n = 0; n < 4; ++n) {
            float4 aI = *(const float4*)&sI[n0 + n][k];   // same addr across 32-lane group -> broadcast
            float4 aO = *(const float4*)&sO[n0 + n][k];
            accI[n][0] += aI.x * wi0.x + aI.y * wi1.x + aI.z * wi2.x + aI.w * wi3.x;
            accI[n][1] += aI.x * wi0.y + aI.y * wi1.y + aI.z * wi2.y + aI.w * wi3.y;
            accI[n][2] += aI.x * wi0.z + aI.y * wi1.z + aI.z * wi2.z + aI.w * wi3.z;
            accI[n][3] += aI.x * wi0.w + aI.y * wi1.w + aI.z * wi2.w + aI.w * wi3.w;
            accO[n][0] += aO.x * wo0.x + aO.y * wo1.x + aO.z * wo2.x + aO.w * wo3.x;
            accO[n][1] += aO.x * wo0.y + aO.y * wo1.y + aO.z * wo2.y + aO.w * wo3.y;
            accO[n][2] += aO.x * wo0.z + aO.y * wo1.z + aO.z * wo2.z + aO.w * wo3.z;
            accO[n][3] += aO.x * wo0.w + aO.y * wo1.w + aO.z * wo2.w + aO.w * wo3.w;
        }
    }

    float4 bi4 = *(const float4*)&bi[j0];
    float4 br4 = *(const float4*)&br[j0];
    float bI[4] = {bi4.x, bi4.y, bi4.z, bi4.w};
    float bO[4] = {br4.x, br4.y, br4.z, br4.w};
#pragma unroll
    for (int n = 0; n < 4; ++n) {
        int v = v0 + n0 + n;
        if (v >= N) continue;
        float4 o;
        o.x = fmaxf((1.f - ALPHA) * (accI[n][0] + bI[0]) + ALPHA * (accO[n][0] + bO[0]), 0.f);
        o.y = fmaxf((1.f - ALPHA) * (accI[n][1] + bI[1]) + ALPHA * (accO[n][1] + bO[1]), 0.f);
        o.z = fmaxf((1.f - ALPHA) * (accI[n][2] + bI[2]) + ALPHA * (accO[n][2] + bO[2]), 0.f);
        o.w = fmaxf((1.f - ALPHA) * (accI[n][3] + bI[3]) + ALPHA * (accO[n][3] + bO[3]), 0.f);
        *(float4*)&h2[(size_t)v * 128 + j0] = o;
    }
}

// ---------------- pooling of 128-wide aggregated features (batch_seg sorted) -------------
#define POOL_NODES 32
__global__ void pool_kernel(const float* __restrict__ aggI, const float* __restrict__ aggO,
                            const int* __restrict__ seg,
                            float* __restrict__ poolI, float* __restrict__ poolO, int N)
{
    int j = threadIdx.x;  // 128 threads
    int v0 = blockIdx.x * POOL_NODES;
    if (v0 >= N) return;
    int v1 = min(N, v0 + POOL_NODES);
    float aI = 0.f, aO = 0.f;
    int cur = seg[v0];
    for (int v = v0; v < v1; ++v) {
        int g = seg[v];
        if (g != cur) {
            atomicAdd(&poolI[cur * 128 + j], aI);
            atomicAdd(&poolO[cur * 128 + j], aO);
            aI = 0.f; aO = 0.f; cur = g;
        }
        aI += aggI[(size_t)v * 128 + j];
        aO += aggO[(size_t)v * 128 + j];
    }
    atomicAdd(&poolI[cur * 128 + j], aI);
    atomicAdd(&poolO[cur * 128 + j], aO);
}

// ---------------- final: (G,128)x2 -> (G,120) with mean ----------------
__global__ void final_kernel(const float* __restrict__ poolI, const float* __restrict__ poolO,
                             const float* __restrict__ cnt,
                             const float* __restrict__ Wo, const float* __restrict__ bo,
                             const float* __restrict__ Wor, const float* __restrict__ bor,
                             float* __restrict__ out, int G)
{
    int g = blockIdx.x;
    int j = threadIdx.x;  // 120 threads
    if (g >= G || j >= 120) return;
    float acc = 0.f;
    for (int k = 0; k < 128; ++k) {
        acc += poolI[g * 128 + k] * ((1.f - ALPHA) * Wo[k * 120 + j])
             + poolO[g * 128 + k] * (ALPHA * Wor[k * 120 + j]);
    }
    float c = cnt[g];
    float bcomb = (1.f - ALPHA) * bo[j] + ALPHA * bor[j];
    out[g * 120 + j] = (c > 0.f) ? (acc / c + bcomb) : 0.f;
}

extern "C" void kernel_launch(void* const* d_in, const int* in_sizes, int n_in,
                              void* d_out, int out_size, void* d_ws, size_t ws_size,
                              hipStream_t stream)
{
    const float* x      = (const float*)d_in[0];
    const int*   ei     = (const int*)d_in[1];
    const int*   seg    = (const int*)d_in[2];
    const float* W_in   = (const float*)d_in[3];
    const float* b_in   = (const float*)d_in[4];
    const float* W_in_r = (const float*)d_in[5];
    const float* b_in_r = (const float*)d_in[6];
    const float* W_mid  = (const float*)d_in[7];
    const float* b_mid  = (const float*)d_in[8];
    const float* W_mid_r= (const float*)d_in[9];
    const float* b_mid_r= (const float*)d_in[10];
    const float* W_out  = (const float*)d_in[11];
    const float* b_out  = (const float*)d_in[12];
    const float* W_out_r= (const float*)d_in[13];
    const float* b_out_r= (const float*)d_in[14];

    const int N = in_sizes[0] / 4;
    const int E = in_sizes[1] / 2;
    const int G = out_size / 120;
    const int* src = ei;
    const int* dst = ei + E;
    const int NBLK  = ceil_div(N, SCAN_B);   // <= 1024 (N <= 262144)
    const int NBUCK = ceil_div(N, BSZ);      // <= 512

    // -------- workspace layout (4-byte units) --------
    char* wsb = (char*)d_ws;
    size_t off = 0;
    auto alloc = [&](size_t elems) { void* p = wsb + off * 4; off += elems; return p; };

    unsigned int* bhI   = (unsigned int*)alloc(MAXB);     // zeroed
    unsigned int* bhO   = (unsigned int*)alloc(MAXB);     // zeroed
    float*        cnt   = (float*)alloc(G);               // zeroed
    float*        poolI = (float*)alloc((size_t)G * 128); // zeroed
    float*        poolO = (float*)alloc((size_t)G * 128); // zeroed
    size_t zero_elems = off;
    unsigned int* baseI = (unsigned int*)alloc(MAXB);
    unsigned int* baseO = (unsigned int*)alloc(MAXB);
    unsigned int* curI  = (unsigned int*)alloc(MAXB);
    unsigned int* curO  = (unsigned int*)alloc(MAXB);
    unsigned int* degI  = (unsigned int*)alloc(N);
    unsigned int* degO  = (unsigned int*)alloc(N);
    float*        dinvI = (float*)alloc(N);
    float*        dinvO = (float*)alloc(N);
    unsigned int* rowI  = (unsigned int*)alloc(N);        // exclusive row starts
    unsigned int* rowO  = (unsigned int*)alloc(N);
    int*          adjI  = (int*)alloc(E);
    int*          adjO  = (int*)alloc(E);
    unsigned int* bsum  = (unsigned int*)alloc(1024);
    off = (off + 3) & ~(size_t)3;                         // 16B align
    float* acc4I = (float*)alloc((size_t)N * 4);
    float* acc4O = (float*)alloc((size_t)N * 4);
    float* bufA  = (float*)alloc((size_t)N * 128);        // h1 / h2
    float* bufB  = (float*)alloc((size_t)N * 128);        // agg in-direction
    float* bufC  = (float*)alloc((size_t)N * 128);        // agg out-direction
    (void)ws_size;

    // Bucketed edge buffers alias bufB/bufC (dead until gather128 writes them).
    int2* ebI = (int2*)bufB;
    int2* ebO = (int2*)bufC;

    hipMemsetAsync(d_ws, 0, zero_elems * 4, stream);

    const int T = 256;
    // ---- binned CSR build ----
    hist_kernel<<<ceil_div(E, T * 16), T, 0, stream>>>(src, dst, bhI, bhO, E, NBUCK);
    bucket_base_kernel<<<1, MAXB, 0, stream>>>(bhI, bhO, baseI, baseO, curI, curO, NBUCK);
    bucket_scatter_kernel<<<ceil_div(E, CHUNK), T, 0, stream>>>(src, dst, curI, curO, ebI, ebO, E);
    // after bucket_scatter, curI[b]/curO[b] == bucket end
    bucket_deg_kernel<<<NBUCK, T, 0, stream>>>(ebI, baseI, curI, degI, N);
    bucket_deg_kernel<<<NBUCK, T, 0, stream>>>(ebO, baseO, curO, degO, N);
    scan_blk_kernel<<<NBLK, SCAN_B, 0, stream>>>(degI, rowI, bsum, N);
    scan_top_kernel<<<1, 1024, 0, stream>>>(bsum, NBLK);
    scan_add_kernel<<<NBLK, SCAN_B, 0, stream>>>(rowI, bsum, degI, dinvI, N);
    scan_blk_kernel<<<NBLK, SCAN_B, 0, stream>>>(degO, rowO, bsum, N);
    scan_top_kernel<<<1, 1024, 0, stream>>>(bsum, NBLK);
    scan_add_kernel<<<NBLK, SCAN_B, 0, stream>>>(rowO, bsum, degO, dinvO, N);
    bucket_adj_kernel<<<NBUCK, T, 0, stream>>>(ebI, baseI, curI, rowI, adjI, N);
    bucket_adj_kernel<<<NBUCK, T, 0, stream>>>(ebO, baseO, curO, rowO, adjO, N);
    cnt_kernel<<<ceil_div(N, T), T, 0, stream>>>(seg, cnt, N);

    // ---- layer 1: width-4 gathers then dense 4->128 ----
    gather4_kernel<<<ceil_div(N, T), T, 0, stream>>>(rowI, degI, adjI, dinvI,
                                                     rowO, degO, adjO, dinvO,
                                                     (const float4*)x,
                                                     (float4*)acc4I, (float4*)acc4O, N);
    layer1_kernel<<<ceil_div(N, L1_NODES), 128, 0, stream>>>(acc4I, acc4O,
                                                             W_in, b_in, W_in_r, b_in_r, bufA, N);
    // ---- layer 2: both-direction gather then register-blocked GEMM ----
    gather128_kernel<<<dim3(ceil_div(N, 8), 2), 256, 0, stream>>>(
        rowI, degI, adjI, dinvI, rowO, degO, adjO, dinvO,
        (const float4*)bufA, (float4*)bufB, (float4*)bufC, N);
    layer2_kernel<<<ceil_div(N, 32), 256, 0, stream>>>(
        (const float4*)bufB, (const float4*)bufC,
        W_mid, b_mid, W_mid_r, b_mid_r, bufA, N);
    // ---- layer 3: both-direction gather, pool, final projection ----
    gather128_kernel<<<dim3(ceil_div(N, 8), 2), 256, 0, stream>>>(
        rowI, degI, adjI, dinvI, rowO, degO, adjO, dinvO,
        (const float4*)bufA, (float4*)bufB, (float4*)bufC, N);
    pool_kernel<<<ceil_div(N, POOL_NODES), 128, 0, stream>>>(bufB, bufC, seg, poolI, poolO, N);
    final_kernel<<<G, 128, 0, stream>>>(poolI, poolO, cnt,
                                        W_out, b_out, W_out_r, b_out_r, (float*)d_out, G);
}

// Round 7
// 823.291 us; speedup vs baseline: 14.7167x; 1.2982x over previous
//
#include <hip/hip_runtime.h>
#include <hip/hip_fp16.h>

#define ALPHA 0.5f
#define SCAN_B 256
#define BSH 9            // bucket shift: 512 nodes/bucket
#define BSZ 512          // nodes per bucket
#define MAXB 512         // max buckets -> supports N <= 262144
#define CHUNK 4096       // edges per block in bucket_scatter

static inline int ceil_div(int a, int b) { return (a + b - 1) / b; }

struct alignas(8) half4 { __half2 a, b; };   // 4 fp16 = 8 B

// ---------------- bucket histogram (both directions) ----------------
__global__ void hist_kernel(const int* __restrict__ src, const int* __restrict__ dst,
                            unsigned int* __restrict__ bhI, unsigned int* __restrict__ bhO,
                            int E, int nbuck)
{
    __shared__ unsigned int hI[MAXB], hO[MAXB];
    for (int b = threadIdx.x; b < MAXB; b += blockDim.x) { hI[b] = 0; hO[b] = 0; }
    __syncthreads();
    for (int e = blockIdx.x * blockDim.x + threadIdx.x; e < E; e += gridDim.x * blockDim.x) {
        atomicAdd(&hI[dst[e] >> BSH], 1u);
        atomicAdd(&hO[src[e] >> BSH], 1u);
    }
    __syncthreads();
    for (int b = threadIdx.x; b < nbuck; b += blockDim.x) {
        if (hI[b]) atomicAdd(&bhI[b], hI[b]);
        if (hO[b]) atomicAdd(&bhO[b], hO[b]);
    }
}

// ---------------- bucket bases: exclusive scan of both hists (1 block, MAXB threads) ------
__global__ void bucket_base_kernel(const unsigned int* __restrict__ bhI,
                                   const unsigned int* __restrict__ bhO,
                                   unsigned int* __restrict__ baseI, unsigned int* __restrict__ baseO,
                                   unsigned int* __restrict__ curI, unsigned int* __restrict__ curO,
                                   int nbuck)
{
    __shared__ unsigned int tI[MAXB], tO[MAXB];
    int t = threadIdx.x;
    unsigned int vI = (t < nbuck) ? bhI[t] : 0u;
    unsigned int vO = (t < nbuck) ? bhO[t] : 0u;
    tI[t] = vI; tO[t] = vO;
    __syncthreads();
    for (int o = 1; o < MAXB; o <<= 1) {
        unsigned int xI = (t >= o) ? tI[t - o] : 0u;
        unsigned int xO = (t >= o) ? tO[t - o] : 0u;
        __syncthreads();
        tI[t] += xI; tO[t] += xO;
        __syncthreads();
    }
    if (t < nbuck) {
        baseI[t] = tI[t] - vI; baseO[t] = tO[t] - vO;
        curI[t]  = tI[t] - vI; curO[t]  = tO[t] - vO;
    }
}

// ---------------- bucket scatter with block-local reservation ----------------
__global__ void bucket_scatter_kernel(const int* __restrict__ src, const int* __restrict__ dst,
                                      unsigned int* __restrict__ curI, unsigned int* __restrict__ curO,
                                      int2* __restrict__ ebI, int2* __restrict__ ebO, int E)
{
    __shared__ unsigned int cI[MAXB], cO[MAXB], bI[MAXB], bO[MAXB];
    int t = threadIdx.x;
    for (int b = t; b < MAXB; b += blockDim.x) { cI[b] = 0; cO[b] = 0; }
    __syncthreads();
    int e0 = blockIdx.x * CHUNK;
    int e1 = min(E, e0 + CHUNK);
    for (int e = e0 + t; e < e1; e += blockDim.x) {
        atomicAdd(&cI[dst[e] >> BSH], 1u);
        atomicAdd(&cO[src[e] >> BSH], 1u);
    }
    __syncthreads();
    for (int b = t; b < MAXB; b += blockDim.x) {
        unsigned int n = cI[b];
        if (n) bI[b] = atomicAdd(&curI[b], n);
        cI[b] = 0;
        n = cO[b];
        if (n) bO[b] = atomicAdd(&curO[b], n);
        cO[b] = 0;
    }
    __syncthreads();
    for (int e = e0 + t; e < e1; e += blockDim.x) {
        int s = src[e], d = dst[e];
        int lb = d >> BSH;
        unsigned int p = bI[lb] + atomicAdd(&cI[lb], 1u);
        ebI[p] = make_int2(d, s);
        lb = s >> BSH;
        p = bO[lb] + atomicAdd(&cO[lb], 1u);
        ebO[p] = make_int2(s, d);
    }
}

// ---------------- per-bucket degree (LDS counters, coalesced write) ----------------
__global__ void bucket_deg_kernel(const int2* __restrict__ eb,
                                  const unsigned int* __restrict__ base,
                                  const unsigned int* __restrict__ bend,
                                  unsigned int* __restrict__ deg, int N)
{
    __shared__ unsigned int d[BSZ];
    int b = blockIdx.x, t = threadIdx.x;
    for (int i = t; i < BSZ; i += blockDim.x) d[i] = 0;
    __syncthreads();
    unsigned int lo = base[b], hi = bend[b];
    int nbase = b << BSH;
    for (unsigned int i = lo + t; i < hi; i += blockDim.x)
        atomicAdd(&d[eb[i].x - nbase], 1u);
    __syncthreads();
    for (int i = t; i < BSZ; i += blockDim.x) {
        int v = nbase + i;
        if (v < N) deg[v] = d[i];
    }
}

// ---------------- per-bucket adjacency scatter (LDS cursors, window-local) ----------------
__global__ void bucket_adj_kernel(const int2* __restrict__ eb,
                                  const unsigned int* __restrict__ base,
                                  const unsigned int* __restrict__ bend,
                                  const unsigned int* __restrict__ rowstart,
                                  int* __restrict__ adj, int N)
{
    __shared__ unsigned int cur[BSZ];
    int b = blockIdx.x, t = threadIdx.x;
    int nbase = b << BSH;
    for (int i = t; i < BSZ; i += blockDim.x) {
        int v = nbase + i;
        cur[i] = (v < N) ? rowstart[v] : 0u;
    }
    __syncthreads();
    unsigned int lo = base[b], hi = bend[b];
    for (unsigned int i = lo + t; i < hi; i += blockDim.x) {
        int2 e = eb[i];
        unsigned int p = atomicAdd(&cur[e.x - nbase], 1u);
        adj[p] = e.y;
    }
}

// ---------------- exclusive scan: per-block pass ----------------
__global__ void scan_blk_kernel(const unsigned int* __restrict__ deg,
                                unsigned int* __restrict__ excl,
                                unsigned int* __restrict__ bsum, int N)
{
    __shared__ unsigned int tmp[SCAN_B];
    int t = threadIdx.x;
    int i = blockIdx.x * SCAN_B + t;
    unsigned int v = (i < N) ? deg[i] : 0u;
    tmp[t] = v;
    __syncthreads();
    for (int o = 1; o < SCAN_B; o <<= 1) {
        unsigned int x = (t >= o) ? tmp[t - o] : 0u;
        __syncthreads();
        tmp[t] += x;
        __syncthreads();
    }
    if (i < N) excl[i] = tmp[t] - v;
    if (t == SCAN_B - 1) bsum[blockIdx.x] = tmp[t];
}

// ---------------- exclusive scan: top-level (single block, nb <= 1024) ----------------
__global__ void scan_top_kernel(unsigned int* __restrict__ bsum, int nb)
{
    __shared__ unsigned int tmp[1024];
    int t = threadIdx.x;
    unsigned int v = (t < nb) ? bsum[t] : 0u;
    tmp[t] = v;
    __syncthreads();
    for (int o = 1; o < 1024; o <<= 1) {
        unsigned int x = (t >= o) ? tmp[t - o] : 0u;
        __syncthreads();
        tmp[t] += x;
        __syncthreads();
    }
    if (t < nb) bsum[t] = tmp[t] - v;
}

// ---------------- scan finalize: add block offset, compute dinv ----------------
__global__ void scan_add_kernel(unsigned int* __restrict__ excl,
                                const unsigned int* __restrict__ bsum,
                                const unsigned int* __restrict__ deg,
                                float* __restrict__ dinv, int N)
{
    int i = blockIdx.x * SCAN_B + threadIdx.x;
    if (i < N) {
        excl[i] += bsum[blockIdx.x];
        unsigned int d = deg[i];
        dinv[i] = d ? rsqrtf((float)d) : 0.f;
    }
}

// ---------------- per-graph node counts ----------------
__global__ void cnt_kernel(const int* __restrict__ seg, float* __restrict__ cnt, int N)
{
    int v = blockIdx.x * blockDim.x + threadIdx.x;
    if (v < N) atomicAdd(&cnt[seg[v]], 1.0f);
}

// ---------------- CSR gather, width 4 (layer 1 pre-projection) ----------------
__global__ void gather4_kernel(const unsigned int* __restrict__ rowI,
                               const unsigned int* __restrict__ degI,
                               const int* __restrict__ adjI,
                               const float* __restrict__ dinvI,
                               const unsigned int* __restrict__ rowO,
                               const unsigned int* __restrict__ degO,
                               const int* __restrict__ adjO,
                               const float* __restrict__ dinvO,
                               const float4* __restrict__ x4,
                               float4* __restrict__ accI, float4* __restrict__ accO, int N)
{
    int v = blockIdx.x * blockDim.x + threadIdx.x;
    if (v >= N) return;
    {
        unsigned int k = rowI[v], end = k + degI[v];
        float4 acc = {0.f, 0.f, 0.f, 0.f};
        for (; k < end; ++k) {
            int s = adjI[k];
            float w = dinvI[s];
            float4 xv = x4[s];
            acc.x += w * xv.x; acc.y += w * xv.y; acc.z += w * xv.z; acc.w += w * xv.w;
        }
        float dv = dinvI[v];
        accI[v] = make_float4(dv * acc.x, dv * acc.y, dv * acc.z, dv * acc.w);
    }
    {
        unsigned int k = rowO[v], end = k + degO[v];
        float4 acc = {0.f, 0.f, 0.f, 0.f};
        for (; k < end; ++k) {
            int s = adjO[k];
            float w = dinvO[s];
            float4 xv = x4[s];
            acc.x += w * xv.x; acc.y += w * xv.y; acc.z += w * xv.z; acc.w += w * xv.w;
        }
        float dv = dinvO[v];
        accO[v] = make_float4(dv * acc.x, dv * acc.y, dv * acc.z, dv * acc.w);
    }
}

// ---------------- layer 1 dense: (N,4)x2 -> (N,128) fp16, relu ----------------
#define L1_NODES 32
__global__ void layer1_kernel(const float* __restrict__ accI, const float* __restrict__ accO,
                              const float* __restrict__ Wi, const float* __restrict__ bi,
                              const float* __restrict__ Wr, const float* __restrict__ br,
                              __half* __restrict__ h1, int N)
{
    __shared__ float wI[4][128], wO[4][128], bb[128];
    int j = threadIdx.x;  // 128 threads
    for (int c = 0; c < 4; ++c) {
        wI[c][j] = (1.f - ALPHA) * Wi[c * 128 + j];
        wO[c][j] = ALPHA * Wr[c * 128 + j];
    }
    bb[j] = (1.f - ALPHA) * bi[j] + ALPHA * br[j];
    __syncthreads();
    int v0 = blockIdx.x * L1_NODES;
    int v1 = min(N, v0 + L1_NODES);
    for (int v = v0; v < v1; ++v) {
        float s = bb[j];
#pragma unroll
        for (int c = 0; c < 4; ++c)
            s += accI[v * 4 + c] * wI[c][j] + accO[v * 4 + c] * wO[c][j];
        h1[(size_t)v * 128 + j] = __float2half_rn(fmaxf(s, 0.f));
    }
}

// ---------------- CSR gather aggregation, width 128 fp16-in/f32-out, both dirs ----------
// 32 lanes per node (half4 = 8 B each -> 256 B/row); 256-thread block = 8 nodes.
__global__ void gather128_kernel(const unsigned int* __restrict__ rowstartI,
                                 const unsigned int* __restrict__ degI,
                                 const int* __restrict__ adjI,
                                 const float* __restrict__ dinvI,
                                 const unsigned int* __restrict__ rowstartO,
                                 const unsigned int* __restrict__ degO,
                                 const int* __restrict__ adjO,
                                 const float* __restrict__ dinvO,
                                 const half4* __restrict__ hp,
                                 float4* __restrict__ outI4, float4* __restrict__ outO4, int N)
{
    int v = blockIdx.x * 8 + (threadIdx.x >> 5);
    if (v >= N) return;
    int lane = threadIdx.x & 31;
    const unsigned int* __restrict__ rowstart = blockIdx.y ? rowstartO : rowstartI;
    const unsigned int* __restrict__ deg      = blockIdx.y ? degO : degI;
    const int* __restrict__ adj               = blockIdx.y ? adjO : adjI;
    const float* __restrict__ dinv            = blockIdx.y ? dinvO : dinvI;
    float4* __restrict__ out4                 = blockIdx.y ? outO4 : outI4;

    unsigned int k = rowstart[v];
    unsigned int end = k + deg[v];
    float4 acc = {0.f, 0.f, 0.f, 0.f};
    for (; k + 2 <= end; k += 2) {
        int s0 = adj[k], s1 = adj[k + 1];
        float w0 = dinv[s0], w1 = dinv[s1];
        half4 v0 = hp[(size_t)s0 * 32 + lane];
        half4 v1 = hp[(size_t)s1 * 32 + lane];
        float2 a0 = __half22float2(v0.a), b0 = __half22float2(v0.b);
        float2 a1 = __half22float2(v1.a), b1 = __half22float2(v1.b);
        acc.x += w0 * a0.x + w1 * a1.x;
        acc.y += w0 * a0.y + w1 * a1.y;
        acc.z += w0 * b0.x + w1 * b1.x;
        acc.w += w0 * b0.y + w1 * b1.y;
    }
    if (k < end) {
        int s = adj[k];
        float w = dinv[s];
        half4 hv = hp[(size_t)s * 32 + lane];
        float2 a = __half22float2(hv.a), b = __half22float2(hv.b);
        acc.x += w * a.x; acc.y += w * a.y; acc.z += w * b.x; acc.w += w * b.y;
    }
    float dv = dinv[v];
    float4 o = {dv * acc.x, dv * acc.y, dv * acc.z, dv * acc.w};
    out4[(size_t)v * 32 + lane] = o;
}

// ---------------- layer 2 dense, register-blocked: (N,128)x2 f32 -> (N,128) fp16, relu --
// 256 threads, 32 nodes x 128 outputs per block. Thread tile: 4 nodes x 4 outputs, k unroll 4.
__global__ __launch_bounds__(256) void layer2_kernel(
    const float4* __restrict__ aggI4, const float4* __restrict__ aggO4,
    const float* __restrict__ Wi, const float* __restrict__ bi,
    const float* __restrict__ Wr, const float* __restrict__ br,
    __half* __restrict__ h2, int N)
{
    __shared__ float sI[32][128];
    __shared__ float sO[32][128];
    int tid = threadIdx.x;
    int v0 = blockIdx.x * 32;
#pragma unroll
    for (int i = 0; i < 4; ++i) {
        int f = tid + i * 256;
        int n = f >> 5, kq = f & 31;
        int v = v0 + n;
        float4 a = (v < N) ? aggI4[(size_t)v * 32 + kq] : make_float4(0.f, 0.f, 0.f, 0.f);
        float4 b = (v < N) ? aggO4[(size_t)v * 32 + kq] : make_float4(0.f, 0.f, 0.f, 0.f);
        *(float4*)&sI[n][kq * 4] = a;
        *(float4*)&sO[n][kq * 4] = b;
    }
    __syncthreads();

    int jg = tid & 31;  int j0 = jg * 4;   // 4 outputs
    int ng = tid >> 5;  int n0 = ng * 4;   // 4 nodes
    float accI[4][4], accO[4][4];
#pragma unroll
    for (int n = 0; n < 4; ++n)
#pragma unroll
        for (int j = 0; j < 4; ++j) { accI[n][j] = 0.f; accO[n][j] = 0.f; }

    for (int kq = 0; kq < 32; ++kq) {
        int k = kq * 4;
        float4 wi0 = *(const float4*)&Wi[(k + 0) * 128 + j0];
        float4 wi1 = *(const float4*)&Wi[(k + 1) * 128 + j0];
        float4 wi2 = *(const float4*)&Wi[(k + 2) * 128 + j0];
        float4 wi3 = *(const float4*)&Wi[(k + 3) * 128 + j0];
        float4 wo0 = *(const float4*)&Wr[(k + 0) * 128 + j0];
        float4 wo1 = *(const float4*)&Wr[(k + 1) * 128 + j0];
        float4 wo2 = *(const float4*)&Wr[(k + 2) * 128 + j0];
        float4 wo3 = *(const float4*)&Wr[(k + 3) * 128 + j0];
#pragma unroll
        for (int n = 0; n < 4; ++n) {
            float4 aI = *(const float4*)&sI[n0 + n][k];
            float4 aO = *(const float4*)&sO[n0 + n][k];
            accI[n][0] += aI.x * wi0.x + aI.y * wi1.x + aI.z * wi2.x + aI.w * wi3.x;
            accI[n][1] += aI.x * wi0.y + aI.y * wi1.y + aI.z * wi2.y + aI.w * wi3.y;
            accI[n][2] += aI.x * wi0.z + aI.y * wi1.z + aI.z * wi2.z + aI.w * wi3.z;
            accI[n][3] += aI.x * wi0.w + aI.y * wi1.w + aI.z * wi2.w + aI.w * wi3.w;
            accO[n][0] += aO.x * wo0.x + aO.y * wo1.x + aO.z * wo2.x + aO.w * wo3.x;
            accO[n][1] += aO.x * wo0.y + aO.y * wo1.y + aO.z * wo2.y + aO.w * wo3.y;
            accO[n][2] += aO.x * wo0.z + aO.y * wo1.z + aO.z * wo2.z + aO.w * wo3.z;
            accO[n][3] += aO.x * wo0.w + aO.y * wo1.w + aO.z * wo2.w + aO.w * wo3.w;
        }
    }

    float4 bi4 = *(const float4*)&bi[j0];
    float4 br4 = *(const float4*)&br[j0];
#pragma unroll
    for (int n = 0; n < 4; ++n) {
        int v = v0 + n0 + n;
        if (v >= N) continue;
        float ox = fmaxf((1.f - ALPHA) * (accI[n][0] + bi4.x) + ALPHA * (accO[n][0] + br4.x), 0.f);
        float oy = fmaxf((1.f - ALPHA) * (accI[n][1] + bi4.y) + ALPHA * (accO[n][1] + br4.y), 0.f);
        float oz = fmaxf((1.f - ALPHA) * (accI[n][2] + bi4.z) + ALPHA * (accO[n][2] + br4.z), 0.f);
        float ow = fmaxf((1.f - ALPHA) * (accI[n][3] + bi4.w) + ALPHA * (accO[n][3] + br4.w), 0.f);
        half4 o;
        o.a = __floats2half2_rn(ox, oy);
        o.b = __floats2half2_rn(oz, ow);
        *(half4*)&h2[(size_t)v * 128 + j0] = o;
    }
}

// ---------------- pooling of 128-wide aggregated features (batch_seg sorted) -------------
#define POOL_NODES 32
__global__ void pool_kernel(const float* __restrict__ aggI, const float* __restrict__ aggO,
                            const int* __restrict__ seg,
                            float* __restrict__ poolI, float* __restrict__ poolO, int N)
{
    int j = threadIdx.x;  // 128 threads
    int v0 = blockIdx.x * POOL_NODES;
    if (v0 >= N) return;
    int v1 = min(N, v0 + POOL_NODES);
    float aI = 0.f, aO = 0.f;
    int cur = seg[v0];
    for (int v = v0; v < v1; ++v) {
        int g = seg[v];
        if (g != cur) {
            atomicAdd(&poolI[cur * 128 + j], aI);
            atomicAdd(&poolO[cur * 128 + j], aO);
            aI = 0.f; aO = 0.f; cur = g;
        }
        aI += aggI[(size_t)v * 128 + j];
        aO += aggO[(size_t)v * 128 + j];
    }
    atomicAdd(&poolI[cur * 128 + j], aI);
    atomicAdd(&poolO[cur * 128 + j], aO);
}

// ---------------- final: (G,128)x2 -> (G,120) with mean ----------------
__global__ void final_kernel(const float* __restrict__ poolI, const float* __restrict__ poolO,
                             const float* __restrict__ cnt,
                             const float* __restrict__ Wo, const float* __restrict__ bo,
                             const float* __restrict__ Wor, const float* __restrict__ bor,
                             float* __restrict__ out, int G)
{
    int g = blockIdx.x;
    int j = threadIdx.x;  // 120 threads
    if (g >= G || j >= 120) return;
    float acc = 0.f;
    for (int k = 0; k < 128; ++k) {
        acc += poolI[g * 128 + k] * ((1.f - ALPHA) * Wo[k * 120 + j])
             + poolO[g * 128 + k] * (ALPHA * Wor[k * 120 + j]);
    }
    float c = cnt[g];
    float bcomb = (1.f - ALPHA) * bo[j] + ALPHA * bor[j];
    out[g * 120 + j] = (c > 0.f) ? (acc / c + bcomb) : 0.f;
}

extern "C" void kernel_launch(void* const* d_in, const int* in_sizes, int n_in,
                              void* d_out, int out_size, void* d_ws, size_t ws_size,
                              hipStream_t stream)
{
    const float* x      = (const float*)d_in[0];
    const int*   ei     = (const int*)d_in[1];
    const int*   seg    = (const int*)d_in[2];
    const float* W_in   = (const float*)d_in[3];
    const float* b_in   = (const float*)d_in[4];
    const float* W_in_r = (const float*)d_in[5];
    const float* b_in_r = (const float*)d_in[6];
    const float* W_mid  = (const float*)d_in[7];
    const float* b_mid  = (const float*)d_in[8];
    const float* W_mid_r= (const float*)d_in[9];
    const float* b_mid_r= (const float*)d_in[10];
    const float* W_out  = (const float*)d_in[11];
    const float* b_out  = (const float*)d_in[12];
    const float* W_out_r= (const float*)d_in[13];
    const float* b_out_r= (const float*)d_in[14];

    const int N = in_sizes[0] / 4;
    const int E = in_sizes[1] / 2;
    const int G = out_size / 120;
    const int* src = ei;
    const int* dst = ei + E;
    const int NBLK  = ceil_div(N, SCAN_B);   // <= 1024 (N <= 262144)
    const int NBUCK = ceil_div(N, BSZ);      // <= 512

    // -------- workspace layout (4-byte units) --------
    char* wsb = (char*)d_ws;
    size_t off = 0;
    auto alloc = [&](size_t elems) { void* p = wsb + off * 4; off += elems; return p; };

    unsigned int* bhI   = (unsigned int*)alloc(MAXB);     // zeroed
    unsigned int* bhO   = (unsigned int*)alloc(MAXB);     // zeroed
    float*        cnt   = (float*)alloc(G);               // zeroed
    float*        poolI = (float*)alloc((size_t)G * 128); // zeroed
    float*        poolO = (float*)alloc((size_t)G * 128); // zeroed
    size_t zero_elems = off;
    unsigned int* baseI = (unsigned int*)alloc(MAXB);
    unsigned int* baseO = (unsigned int*)alloc(MAXB);
    unsigned int* curI  = (unsigned int*)alloc(MAXB);
    unsigned int* curO  = (unsigned int*)alloc(MAXB);
    unsigned int* degI  = (unsigned int*)alloc(N);
    unsigned int* degO  = (unsigned int*)alloc(N);
    float*        dinvI = (float*)alloc(N);
    float*        dinvO = (float*)alloc(N);
    unsigned int* rowI  = (unsigned int*)alloc(N);        // exclusive row starts
    unsigned int* rowO  = (unsigned int*)alloc(N);
    int*          adjI  = (int*)alloc(E);
    int*          adjO  = (int*)alloc(E);
    unsigned int* bsum  = (unsigned int*)alloc(1024);
    off = (off + 3) & ~(size_t)3;                         // 16B align
    float* acc4I = (float*)alloc((size_t)N * 4);
    float* acc4O = (float*)alloc((size_t)N * 4);
    __half* hbuf = (__half*)alloc((size_t)N * 64);        // h1 / h2 as fp16 (N*128 halves)
    float* bufB  = (float*)alloc((size_t)N * 128);        // agg in-direction (f32)
    float* bufC  = (float*)alloc((size_t)N * 128);        // agg out-direction (f32)
    (void)ws_size;

    // Bucketed edge buffers alias bufB/bufC (dead until gather128 writes them).
    int2* ebI = (int2*)bufB;
    int2* ebO = (int2*)bufC;

    hipMemsetAsync(d_ws, 0, zero_elems * 4, stream);

    const int T = 256;
    // ---- binned CSR build ----
    hist_kernel<<<ceil_div(E, T * 16), T, 0, stream>>>(src, dst, bhI, bhO, E, NBUCK);
    bucket_base_kernel<<<1, MAXB, 0, stream>>>(bhI, bhO, baseI, baseO, curI, curO, NBUCK);
    bucket_scatter_kernel<<<ceil_div(E, CHUNK), T, 0, stream>>>(src, dst, curI, curO, ebI, ebO, E);
    // after bucket_scatter, curI[b]/curO[b] == bucket end
    bucket_deg_kernel<<<NBUCK, T, 0, stream>>>(ebI, baseI, curI, degI, N);
    bucket_deg_kernel<<<NBUCK, T, 0, stream>>>(ebO, baseO, curO, degO, N);
    scan_blk_kernel<<<NBLK, SCAN_B, 0, stream>>>(degI, rowI, bsum, N);
    scan_top_kernel<<<1, 1024, 0, stream>>>(bsum, NBLK);
    scan_add_kernel<<<NBLK, SCAN_B, 0, stream>>>(rowI, bsum, degI, dinvI, N);
    scan_blk_kernel<<<NBLK, SCAN_B, 0, stream>>>(degO, rowO, bsum, N);
    scan_top_kernel<<<1, 1024, 0, stream>>>(bsum, NBLK);
    scan_add_kernel<<<NBLK, SCAN_B, 0, stream>>>(rowO, bsum, degO, dinvO, N);
    bucket_adj_kernel<<<NBUCK, T, 0, stream>>>(ebI, baseI, curI, rowI, adjI, N);
    bucket_adj_kernel<<<NBUCK, T, 0, stream>>>(ebO, baseO, curO, rowO, adjO, N);
    cnt_kernel<<<ceil_div(N, T), T, 0, stream>>>(seg, cnt, N);

    // ---- layer 1: width-4 gathers then dense 4->128 (fp16 out) ----
    gather4_kernel<<<ceil_div(N, T), T, 0, stream>>>(rowI, degI, adjI, dinvI,
                                                     rowO, degO, adjO, dinvO,
                                                     (const float4*)x,
                                                     (float4*)acc4I, (float4*)acc4O, N);
    layer1_kernel<<<ceil_div(N, L1_NODES), 128, 0, stream>>>(acc4I, acc4O,
                                                             W_in, b_in, W_in_r, b_in_r, hbuf, N);
    // ---- layer 2: both-direction fp16 gather then register-blocked GEMM (fp16 out) ----
    gather128_kernel<<<dim3(ceil_div(N, 8), 2), 256, 0, stream>>>(
        rowI, degI, adjI, dinvI, rowO, degO, adjO, dinvO,
        (const half4*)hbuf, (float4*)bufB, (float4*)bufC, N);
    layer2_kernel<<<ceil_div(N, 32), 256, 0, stream>>>(
        (const float4*)bufB, (const float4*)bufC,
        W_mid, b_mid, W_mid_r, b_mid_r, hbuf, N);
    // ---- layer 3: both-direction fp16 gather, pool, final projection ----
    gather128_kernel<<<dim3(ceil_div(N, 8), 2), 256, 0, stream>>>(
        rowI, degI, adjI, dinvI, rowO, degO, adjO, dinvO,
        (const half4*)hbuf, (float4*)bufB, (float4*)bufC, N);
    pool_kernel<<<ceil_div(N, POOL_NODES), 128, 0, stream>>>(bufB, bufC, seg, poolI, poolO, N);
    final_kernel<<<G, 128, 0, stream>>>(poolI, poolO, cnt,
                                        W_out, b_out, W_out_r, b_out_r, (float*)d_out, G);
}

// Round 8
// 642.894 us; speedup vs baseline: 18.8462x; 1.2806x over previous
//
#include <hip/hip_runtime.h>
#include <hip/hip_fp16.h>

#define ALPHA 0.5f
#define SCAN_B 256
#define BSH 9            // bucket shift: 512 nodes/bucket
#define BSZ 512          // nodes per bucket
#define MAXB 512         // max buckets -> supports N <= 262144
#define CHUNK 4096       // edges per block in bucket_scatter

static inline int ceil_div(int a, int b) { return (a + b - 1) / b; }

struct alignas(8) half4 { __half2 a, b; };   // 4 fp16 = 8 B

// ---------------- bucket histogram (both directions) ----------------
__global__ void hist_kernel(const int* __restrict__ src, const int* __restrict__ dst,
                            unsigned int* __restrict__ bhI, unsigned int* __restrict__ bhO,
                            int E, int nbuck)
{
    __shared__ unsigned int hI[MAXB], hO[MAXB];
    for (int b = threadIdx.x; b < MAXB; b += blockDim.x) { hI[b] = 0; hO[b] = 0; }
    __syncthreads();
    for (int e = blockIdx.x * blockDim.x + threadIdx.x; e < E; e += gridDim.x * blockDim.x) {
        atomicAdd(&hI[dst[e] >> BSH], 1u);
        atomicAdd(&hO[src[e] >> BSH], 1u);
    }
    __syncthreads();
    for (int b = threadIdx.x; b < nbuck; b += blockDim.x) {
        if (hI[b]) atomicAdd(&bhI[b], hI[b]);
        if (hO[b]) atomicAdd(&bhO[b], hO[b]);
    }
}

// ---------------- bucket bases: exclusive scan of both hists (1 block, MAXB threads) ------
__global__ void bucket_base_kernel(const unsigned int* __restrict__ bhI,
                                   const unsigned int* __restrict__ bhO,
                                   unsigned int* __restrict__ baseI, unsigned int* __restrict__ baseO,
                                   unsigned int* __restrict__ curI, unsigned int* __restrict__ curO,
                                   int nbuck)
{
    __shared__ unsigned int tI[MAXB], tO[MAXB];
    int t = threadIdx.x;
    unsigned int vI = (t < nbuck) ? bhI[t] : 0u;
    unsigned int vO = (t < nbuck) ? bhO[t] : 0u;
    tI[t] = vI; tO[t] = vO;
    __syncthreads();
    for (int o = 1; o < MAXB; o <<= 1) {
        unsigned int xI = (t >= o) ? tI[t - o] : 0u;
        unsigned int xO = (t >= o) ? tO[t - o] : 0u;
        __syncthreads();
        tI[t] += xI; tO[t] += xO;
        __syncthreads();
    }
    if (t < nbuck) {
        baseI[t] = tI[t] - vI; baseO[t] = tO[t] - vO;
        curI[t]  = tI[t] - vI; curO[t]  = tO[t] - vO;
    }
}

// ---------------- bucket scatter with block-local reservation ----------------
__global__ void bucket_scatter_kernel(const int* __restrict__ src, const int* __restrict__ dst,
                                      unsigned int* __restrict__ curI, unsigned int* __restrict__ curO,
                                      int2* __restrict__ ebI, int2* __restrict__ ebO, int E)
{
    __shared__ unsigned int cI[MAXB], cO[MAXB], bI[MAXB], bO[MAXB];
    int t = threadIdx.x;
    for (int b = t; b < MAXB; b += blockDim.x) { cI[b] = 0; cO[b] = 0; }
    __syncthreads();
    int e0 = blockIdx.x * CHUNK;
    int e1 = min(E, e0 + CHUNK);
    for (int e = e0 + t; e < e1; e += blockDim.x) {
        atomicAdd(&cI[dst[e] >> BSH], 1u);
        atomicAdd(&cO[src[e] >> BSH], 1u);
    }
    __syncthreads();
    for (int b = t; b < MAXB; b += blockDim.x) {
        unsigned int n = cI[b];
        if (n) bI[b] = atomicAdd(&curI[b], n);
        cI[b] = 0;
        n = cO[b];
        if (n) bO[b] = atomicAdd(&curO[b], n);
        cO[b] = 0;
    }
    __syncthreads();
    for (int e = e0 + t; e < e1; e += blockDim.x) {
        int s = src[e], d = dst[e];
        int lb = d >> BSH;
        unsigned int p = bI[lb] + atomicAdd(&cI[lb], 1u);
        ebI[p] = make_int2(d, s);
        lb = s >> BSH;
        p = bO[lb] + atomicAdd(&cO[lb], 1u);
        ebO[p] = make_int2(s, d);
    }
}

// ---------------- per-bucket degree (LDS counters, coalesced write) ----------------
__global__ void bucket_deg_kernel(const int2* __restrict__ eb,
                                  const unsigned int* __restrict__ base,
                                  const unsigned int* __restrict__ bend,
                                  unsigned int* __restrict__ deg, int N)
{
    __shared__ unsigned int d[BSZ];
    int b = blockIdx.x, t = threadIdx.x;
    for (int i = t; i < BSZ; i += blockDim.x) d[i] = 0;
    __syncthreads();
    unsigned int lo = base[b], hi = bend[b];
    int nbase = b << BSH;
    for (unsigned int i = lo + t; i < hi; i += blockDim.x)
        atomicAdd(&d[eb[i].x - nbase], 1u);
    __syncthreads();
    for (int i = t; i < BSZ; i += blockDim.x) {
        int v = nbase + i;
        if (v < N) deg[v] = d[i];
    }
}

// ---------------- per-bucket adjacency scatter (LDS cursors, window-local) ----------------
__global__ void bucket_adj_kernel(const int2* __restrict__ eb,
                                  const unsigned int* __restrict__ base,
                                  const unsigned int* __restrict__ bend,
                                  const unsigned int* __restrict__ rowstart,
                                  int* __restrict__ adj, int N)
{
    __shared__ unsigned int cur[BSZ];
    int b = blockIdx.x, t = threadIdx.x;
    int nbase = b << BSH;
    for (int i = t; i < BSZ; i += blockDim.x) {
        int v = nbase + i;
        cur[i] = (v < N) ? rowstart[v] : 0u;
    }
    __syncthreads();
    unsigned int lo = base[b], hi = bend[b];
    for (unsigned int i = lo + t; i < hi; i += blockDim.x) {
        int2 e = eb[i];
        unsigned int p = atomicAdd(&cur[e.x - nbase], 1u);
        adj[p] = e.y;
    }
}

// ---------------- exclusive scan: per-block pass ----------------
__global__ void scan_blk_kernel(const unsigned int* __restrict__ deg,
                                unsigned int* __restrict__ excl,
                                unsigned int* __restrict__ bsum, int N)
{
    __shared__ unsigned int tmp[SCAN_B];
    int t = threadIdx.x;
    int i = blockIdx.x * SCAN_B + t;
    unsigned int v = (i < N) ? deg[i] : 0u;
    tmp[t] = v;
    __syncthreads();
    for (int o = 1; o < SCAN_B; o <<= 1) {
        unsigned int x = (t >= o) ? tmp[t - o] : 0u;
        __syncthreads();
        tmp[t] += x;
        __syncthreads();
    }
    if (i < N) excl[i] = tmp[t] - v;
    if (t == SCAN_B - 1) bsum[blockIdx.x] = tmp[t];
}

// ---------------- exclusive scan: top-level (single block, nb <= 1024) ----------------
__global__ void scan_top_kernel(unsigned int* __restrict__ bsum, int nb)
{
    __shared__ unsigned int tmp[1024];
    int t = threadIdx.x;
    unsigned int v = (t < nb) ? bsum[t] : 0u;
    tmp[t] = v;
    __syncthreads();
    for (int o = 1; o < 1024; o <<= 1) {
        unsigned int x = (t >= o) ? tmp[t - o] : 0u;
        __syncthreads();
        tmp[t] += x;
        __syncthreads();
    }
    if (t < nb) bsum[t] = tmp[t] - v;
}

// ---------------- scan finalize: add block offset, compute dinv ----------------
__global__ void scan_add_kernel(unsigned int* __restrict__ excl,
                                const unsigned int* __restrict__ bsum,
                                const unsigned int* __restrict__ deg,
                                float* __restrict__ dinv, int N)
{
    int i = blockIdx.x * SCAN_B + threadIdx.x;
    if (i < N) {
        excl[i] += bsum[blockIdx.x];
        unsigned int d = deg[i];
        dinv[i] = d ? rsqrtf((float)d) : 0.f;
    }
}

// ---------------- per-graph node counts via binary search (seg is sorted) ----------------
__global__ void seg_cnt_kernel(const int* __restrict__ seg, float* __restrict__ cnt, int N, int G)
{
    int g = blockIdx.x * blockDim.x + threadIdx.x;
    if (g >= G) return;
    int lo = 0, hi = N;
    while (lo < hi) { int m = (lo + hi) >> 1; if (seg[m] < g) lo = m + 1; else hi = m; }
    int s0 = lo;
    hi = N;
    while (lo < hi) { int m = (lo + hi) >> 1; if (seg[m] < g + 1) lo = m + 1; else hi = m; }
    cnt[g] = (float)(lo - s0);
}

// ---------------- CSR gather, width 4 (layer 1 pre-projection) ----------------
__global__ void gather4_kernel(const unsigned int* __restrict__ rowI,
                               const unsigned int* __restrict__ degI,
                               const int* __restrict__ adjI,
                               const float* __restrict__ dinvI,
                               const unsigned int* __restrict__ rowO,
                               const unsigned int* __restrict__ degO,
                               const int* __restrict__ adjO,
                               const float* __restrict__ dinvO,
                               const float4* __restrict__ x4,
                               float4* __restrict__ accI, float4* __restrict__ accO, int N)
{
    int v = blockIdx.x * blockDim.x + threadIdx.x;
    if (v >= N) return;
    {
        unsigned int k = rowI[v], end = k + degI[v];
        float4 acc = {0.f, 0.f, 0.f, 0.f};
        for (; k < end; ++k) {
            int s = adjI[k];
            float w = dinvI[s];
            float4 xv = x4[s];
            acc.x += w * xv.x; acc.y += w * xv.y; acc.z += w * xv.z; acc.w += w * xv.w;
        }
        float dv = dinvI[v];
        accI[v] = make_float4(dv * acc.x, dv * acc.y, dv * acc.z, dv * acc.w);
    }
    {
        unsigned int k = rowO[v], end = k + degO[v];
        float4 acc = {0.f, 0.f, 0.f, 0.f};
        for (; k < end; ++k) {
            int s = adjO[k];
            float w = dinvO[s];
            float4 xv = x4[s];
            acc.x += w * xv.x; acc.y += w * xv.y; acc.z += w * xv.z; acc.w += w * xv.w;
        }
        float dv = dinvO[v];
        accO[v] = make_float4(dv * acc.x, dv * acc.y, dv * acc.z, dv * acc.w);
    }
}

// ---------------- layer 1 dense: (N,4)x2 -> (N,128) fp16, relu ----------------
#define L1_NODES 32
__global__ void layer1_kernel(const float* __restrict__ accI, const float* __restrict__ accO,
                              const float* __restrict__ Wi, const float* __restrict__ bi,
                              const float* __restrict__ Wr, const float* __restrict__ br,
                              __half* __restrict__ h1, int N)
{
    __shared__ float wI[4][128], wO[4][128], bb[128];
    int j = threadIdx.x;  // 128 threads
    for (int c = 0; c < 4; ++c) {
        wI[c][j] = (1.f - ALPHA) * Wi[c * 128 + j];
        wO[c][j] = ALPHA * Wr[c * 128 + j];
    }
    bb[j] = (1.f - ALPHA) * bi[j] + ALPHA * br[j];
    __syncthreads();
    int v0 = blockIdx.x * L1_NODES;
    int v1 = min(N, v0 + L1_NODES);
    for (int v = v0; v < v1; ++v) {
        float s = bb[j];
#pragma unroll
        for (int c = 0; c < 4; ++c)
            s += accI[v * 4 + c] * wI[c][j] + accO[v * 4 + c] * wO[c][j];
        h1[(size_t)v * 128 + j] = __float2half_rn(fmaxf(s, 0.f));
    }
}

// ---------------- CSR gather aggregation, width 128 fp16-in/f32-out, both dirs ----------
// 32 lanes per node (half4 = 8 B each -> 256 B/row); 256-thread block = 8 nodes.
__global__ void gather128_kernel(const unsigned int* __restrict__ rowstartI,
                                 const unsigned int* __restrict__ degI,
                                 const int* __restrict__ adjI,
                                 const float* __restrict__ dinvI,
                                 const unsigned int* __restrict__ rowstartO,
                                 const unsigned int* __restrict__ degO,
                                 const int* __restrict__ adjO,
                                 const float* __restrict__ dinvO,
                                 const half4* __restrict__ hp,
                                 float4* __restrict__ outI4, float4* __restrict__ outO4, int N)
{
    int v = blockIdx.x * 8 + (threadIdx.x >> 5);
    if (v >= N) return;
    int lane = threadIdx.x & 31;
    const unsigned int* __restrict__ rowstart = blockIdx.y ? rowstartO : rowstartI;
    const unsigned int* __restrict__ deg      = blockIdx.y ? degO : degI;
    const int* __restrict__ adj               = blockIdx.y ? adjO : adjI;
    const float* __restrict__ dinv            = blockIdx.y ? dinvO : dinvI;
    float4* __restrict__ out4                 = blockIdx.y ? outO4 : outI4;

    unsigned int k = rowstart[v];
    unsigned int end = k + deg[v];
    float4 acc = {0.f, 0.f, 0.f, 0.f};
    for (; k + 2 <= end; k += 2) {
        int s0 = adj[k], s1 = adj[k + 1];
        float w0 = dinv[s0], w1 = dinv[s1];
        half4 v0 = hp[(size_t)s0 * 32 + lane];
        half4 v1 = hp[(size_t)s1 * 32 + lane];
        float2 a0 = __half22float2(v0.a), b0 = __half22float2(v0.b);
        float2 a1 = __half22float2(v1.a), b1 = __half22float2(v1.b);
        acc.x += w0 * a0.x + w1 * a1.x;
        acc.y += w0 * a0.y + w1 * a1.y;
        acc.z += w0 * b0.x + w1 * b1.x;
        acc.w += w0 * b0.y + w1 * b1.y;
    }
    if (k < end) {
        int s = adj[k];
        float w = dinv[s];
        half4 hv = hp[(size_t)s * 32 + lane];
        float2 a = __half22float2(hv.a), b = __half22float2(hv.b);
        acc.x += w * a.x; acc.y += w * a.y; acc.z += w * b.x; acc.w += w * b.y;
    }
    float dv = dinv[v];
    float4 o = {dv * acc.x, dv * acc.y, dv * acc.z, dv * acc.w};
    out4[(size_t)v * 32 + lane] = o;
}

// ---------------- layer 2 dense, register-blocked: (N,128)x2 f32 -> (N,128) fp16, relu --
// 256 threads, 32 nodes x 128 outputs per block. Thread tile: 4 nodes x 4 outputs, k unroll 4.
__global__ __launch_bounds__(256) void layer2_kernel(
    const float4* __restrict__ aggI4, const float4* __restrict__ aggO4,
    const float* __restrict__ Wi, const float* __restrict__ bi,
    const float* __restrict__ Wr, const float* __restrict__ br,
    __half* __restrict__ h2, int N)
{
    __shared__ float sI[32][128];
    __shared__ float sO[32][128];
    int tid = threadIdx.x;
    int v0 = blockIdx.x * 32;
#pragma unroll
    for (int i = 0; i < 4; ++i) {
        int f = tid + i * 256;
        int n = f >> 5, kq = f & 31;
        int v = v0 + n;
        float4 a = (v < N) ? aggI4[(size_t)v * 32 + kq] : make_float4(0.f, 0.f, 0.f, 0.f);
        float4 b = (v < N) ? aggO4[(size_t)v * 32 + kq] : make_float4(0.f, 0.f, 0.f, 0.f);
        *(float4*)&sI[n][kq * 4] = a;
        *(float4*)&sO[n][kq * 4] = b;
    }
    __syncthreads();

    int jg = tid & 31;  int j0 = jg * 4;   // 4 outputs
    int ng = tid >> 5;  int n0 = ng * 4;   // 4 nodes
    float accI[4][4], accO[4][4];
#pragma unroll
    for (int n = 0; n < 4; ++n)
#pragma unroll
        for (int j = 0; j < 4; ++j) { accI[n][j] = 0.f; accO[n][j] = 0.f; }

    for (int kq = 0; kq < 32; ++kq) {
        int k = kq * 4;
        float4 wi0 = *(const float4*)&Wi[(k + 0) * 128 + j0];
        float4 wi1 = *(const float4*)&Wi[(k + 1) * 128 + j0];
        float4 wi2 = *(const float4*)&Wi[(k + 2) * 128 + j0];
        float4 wi3 = *(const float4*)&Wi[(k + 3) * 128 + j0];
        float4 wo0 = *(const float4*)&Wr[(k + 0) * 128 + j0];
        float4 wo1 = *(const float4*)&Wr[(k + 1) * 128 + j0];
        float4 wo2 = *(const float4*)&Wr[(k + 2) * 128 + j0];
        float4 wo3 = *(const float4*)&Wr[(k + 3) * 128 + j0];
#pragma unroll
        for (int n = 0; n < 4; ++n) {
            float4 aI = *(const float4*)&sI[n0 + n][k];
            float4 aO = *(const float4*)&sO[n0 + n][k];
            accI[n][0] += aI.x * wi0.x + aI.y * wi1.x + aI.z * wi2.x + aI.w * wi3.x;
            accI[n][1] += aI.x * wi0.y + aI.y * wi1.y + aI.z * wi2.y + aI.w * wi3.y;
            accI[n][2] += aI.x * wi0.z + aI.y * wi1.z + aI.z * wi2.z + aI.w * wi3.z;
            accI[n][3] += aI.x * wi0.w + aI.y * wi1.w + aI.z * wi2.w + aI.w * wi3.w;
            accO[n][0] += aO.x * wo0.x + aO.y * wo1.x + aO.z * wo2.x + aO.w * wo3.x;
            accO[n][1] += aO.x * wo0.y + aO.y * wo1.y + aO.z * wo2.y + aO.w * wo3.y;
            accO[n][2] += aO.x * wo0.z + aO.y * wo1.z + aO.z * wo2.z + aO.w * wo3.z;
            accO[n][3] += aO.x * wo0.w + aO.y * wo1.w + aO.z * wo2.w + aO.w * wo3.w;
        }
    }

    float4 bi4 = *(const float4*)&bi[j0];
    float4 br4 = *(const float4*)&br[j0];
#pragma unroll
    for (int n = 0; n < 4; ++n) {
        int v = v0 + n0 + n;
        if (v >= N) continue;
        float ox = fmaxf((1.f - ALPHA) * (accI[n][0] + bi4.x) + ALPHA * (accO[n][0] + br4.x), 0.f);
        float oy = fmaxf((1.f - ALPHA) * (accI[n][1] + bi4.y) + ALPHA * (accO[n][1] + br4.y), 0.f);
        float oz = fmaxf((1.f - ALPHA) * (accI[n][2] + bi4.z) + ALPHA * (accO[n][2] + br4.z), 0.f);
        float ow = fmaxf((1.f - ALPHA) * (accI[n][3] + bi4.w) + ALPHA * (accO[n][3] + br4.w), 0.f);
        half4 o;
        o.a = __floats2half2_rn(ox, oy);
        o.b = __floats2half2_rn(oz, ow);
        *(half4*)&h2[(size_t)v * 128 + j0] = o;
    }
}

// ---------------- pooling of 128-wide aggregated features (batch_seg sorted) -------------
#define POOL_NODES 32
__global__ void pool_kernel(const float* __restrict__ aggI, const float* __restrict__ aggO,
                            const int* __restrict__ seg,
                            float* __restrict__ poolI, float* __restrict__ poolO, int N)
{
    int j = threadIdx.x;  // 128 threads
    int v0 = blockIdx.x * POOL_NODES;
    if (v0 >= N) return;
    int v1 = min(N, v0 + POOL_NODES);
    float aI = 0.f, aO = 0.f;
    int cur = seg[v0];
    for (int v = v0; v < v1; ++v) {
        int g = seg[v];
        if (g != cur) {
            atomicAdd(&poolI[cur * 128 + j], aI);
            atomicAdd(&poolO[cur * 128 + j], aO);
            aI = 0.f; aO = 0.f; cur = g;
        }
        aI += aggI[(size_t)v * 128 + j];
        aO += aggO[(size_t)v * 128 + j];
    }
    atomicAdd(&poolI[cur * 128 + j], aI);
    atomicAdd(&poolO[cur * 128 + j], aO);
}

// ---------------- final: (G,128)x2 -> (G,120) with mean ----------------
__global__ void final_kernel(const float* __restrict__ poolI, const float* __restrict__ poolO,
                             const float* __restrict__ cnt,
                             const float* __restrict__ Wo, const float* __restrict__ bo,
                             const float* __restrict__ Wor, const float* __restrict__ bor,
                             float* __restrict__ out, int G)
{
    int g = blockIdx.x;
    int j = threadIdx.x;  // 120 threads
    if (g >= G || j >= 120) return;
    float acc = 0.f;
    for (int k = 0; k < 128; ++k) {
        acc += poolI[g * 128 + k] * ((1.f - ALPHA) * Wo[k * 120 + j])
             + poolO[g * 128 + k] * (ALPHA * Wor[k * 120 + j]);
    }
    float c = cnt[g];
    float bcomb = (1.f - ALPHA) * bo[j] + ALPHA * bor[j];
    out[g * 120 + j] = (c > 0.f) ? (acc / c + bcomb) : 0.f;
}

extern "C" void kernel_launch(void* const* d_in, const int* in_sizes, int n_in,
                              void* d_out, int out_size, void* d_ws, size_t ws_size,
                              hipStream_t stream)
{
    const float* x      = (const float*)d_in[0];
    const int*   ei     = (const int*)d_in[1];
    const int*   seg    = (const int*)d_in[2];
    const float* W_in   = (const float*)d_in[3];
    const float* b_in   = (const float*)d_in[4];
    const float* W_in_r = (const float*)d_in[5];
    const float* b_in_r = (const float*)d_in[6];
    const float* W_mid  = (const float*)d_in[7];
    const float* b_mid  = (const float*)d_in[8];
    const float* W_mid_r= (const float*)d_in[9];
    const float* b_mid_r= (const float*)d_in[10];
    const float* W_out  = (const float*)d_in[11];
    const float* b_out  = (const float*)d_in[12];
    const float* W_out_r= (const float*)d_in[13];
    const float* b_out_r= (const float*)d_in[14];

    const int N = in_sizes[0] / 4;
    const int E = in_sizes[1] / 2;
    const int G = out_size / 120;
    const int* src = ei;
    const int* dst = ei + E;
    const int NBLK  = ceil_div(N, SCAN_B);   // <= 1024 (N <= 262144)
    const int NBUCK = ceil_div(N, BSZ);      // <= 512

    // -------- workspace layout (4-byte units) --------
    char* wsb = (char*)d_ws;
    size_t off = 0;
    auto alloc = [&](size_t elems) { void* p = wsb + off * 4; off += elems; return p; };

    unsigned int* bhI   = (unsigned int*)alloc(MAXB);     // zeroed
    unsigned int* bhO   = (unsigned int*)alloc(MAXB);     // zeroed
    float*        poolI = (float*)alloc((size_t)G * 128); // zeroed
    float*        poolO = (float*)alloc((size_t)G * 128); // zeroed
    size_t zero_elems = off;
    float*        cnt   = (float*)alloc(G);               // fully written by seg_cnt
    unsigned int* baseI = (unsigned int*)alloc(MAXB);
    unsigned int* baseO = (unsigned int*)alloc(MAXB);
    unsigned int* curI  = (unsigned int*)alloc(MAXB);
    unsigned int* curO  = (unsigned int*)alloc(MAXB);
    unsigned int* degI  = (unsigned int*)alloc(N);
    unsigned int* degO  = (unsigned int*)alloc(N);
    float*        dinvI = (float*)alloc(N);
    float*        dinvO = (float*)alloc(N);
    unsigned int* rowI  = (unsigned int*)alloc(N);        // exclusive row starts
    unsigned int* rowO  = (unsigned int*)alloc(N);
    int*          adjI  = (int*)alloc(E);
    int*          adjO  = (int*)alloc(E);
    unsigned int* bsum  = (unsigned int*)alloc(1024);
    off = (off + 3) & ~(size_t)3;                         // 16B align
    float* acc4I = (float*)alloc((size_t)N * 4);
    float* acc4O = (float*)alloc((size_t)N * 4);
    __half* hbuf = (__half*)alloc((size_t)N * 64);        // h1 / h2 as fp16 (N*128 halves)
    float* bufB  = (float*)alloc((size_t)N * 128);        // agg in-direction (f32)
    float* bufC  = (float*)alloc((size_t)N * 128);        // agg out-direction (f32)
    (void)ws_size;

    // Bucketed edge buffers alias bufB/bufC (dead until gather128 writes them).
    int2* ebI = (int2*)bufB;
    int2* ebO = (int2*)bufC;

    hipMemsetAsync(d_ws, 0, zero_elems * 4, stream);

    const int T = 256;
    // ---- binned CSR build ----
    hist_kernel<<<ceil_div(E, T * 16), T, 0, stream>>>(src, dst, bhI, bhO, E, NBUCK);
    bucket_base_kernel<<<1, MAXB, 0, stream>>>(bhI, bhO, baseI, baseO, curI, curO, NBUCK);
    bucket_scatter_kernel<<<ceil_div(E, CHUNK), T, 0, stream>>>(src, dst, curI, curO, ebI, ebO, E);
    // after bucket_scatter, curI[b]/curO[b] == bucket end
    bucket_deg_kernel<<<NBUCK, T, 0, stream>>>(ebI, baseI, curI, degI, N);
    bucket_deg_kernel<<<NBUCK, T, 0, stream>>>(ebO, baseO, curO, degO, N);
    scan_blk_kernel<<<NBLK, SCAN_B, 0, stream>>>(degI, rowI, bsum, N);
    scan_top_kernel<<<1, 1024, 0, stream>>>(bsum, NBLK);
    scan_add_kernel<<<NBLK, SCAN_B, 0, stream>>>(rowI, bsum, degI, dinvI, N);
    scan_blk_kernel<<<NBLK, SCAN_B, 0, stream>>>(degO, rowO, bsum, N);
    scan_top_kernel<<<1, 1024, 0, stream>>>(bsum, NBLK);
    scan_add_kernel<<<NBLK, SCAN_B, 0, stream>>>(rowO, bsum, degO, dinvO, N);
    bucket_adj_kernel<<<NBUCK, T, 0, stream>>>(ebI, baseI, curI, rowI, adjI, N);
    bucket_adj_kernel<<<NBUCK, T, 0, stream>>>(ebO, baseO, curO, rowO, adjO, N);
    seg_cnt_kernel<<<ceil_div(G, T), T, 0, stream>>>(seg, cnt, N, G);

    // ---- layer 1: width-4 gathers then dense 4->128 (fp16 out) ----
    gather4_kernel<<<ceil_div(N, T), T, 0, stream>>>(rowI, degI, adjI, dinvI,
                                                     rowO, degO, adjO, dinvO,
                                                     (const float4*)x,
                                                     (float4*)acc4I, (float4*)acc4O, N);
    layer1_kernel<<<ceil_div(N, L1_NODES), 128, 0, stream>>>(acc4I, acc4O,
                                                             W_in, b_in, W_in_r, b_in_r, hbuf, N);
    // ---- layer 2: both-direction fp16 gather then register-blocked GEMM (fp16 out) ----
    gather128_kernel<<<dim3(ceil_div(N, 8), 2), 256, 0, stream>>>(
        rowI, degI, adjI, dinvI, rowO, degO, adjO, dinvO,
        (const half4*)hbuf, (float4*)bufB, (float4*)bufC, N);
    layer2_kernel<<<ceil_div(N, 32), 256, 0, stream>>>(
        (const float4*)bufB, (const float4*)bufC,
        W_mid, b_mid, W_mid_r, b_mid_r, hbuf, N);
    // ---- layer 3: both-direction fp16 gather, pool, final projection ----
    gather128_kernel<<<dim3(ceil_div(N, 8), 2), 256, 0, stream>>>(
        rowI, degI, adjI, dinvI, rowO, degO, adjO, dinvO,
        (const half4*)hbuf, (float4*)bufB, (float4*)bufC, N);
    pool_kernel<<<ceil_div(N, POOL_NODES), 128, 0, stream>>>(bufB, bufC, seg, poolI, poolO, N);
    final_kernel<<<G, 128, 0, stream>>>(poolI, poolO, cnt,
                                        W_out, b_out, W_out_r, b_out_r, (float*)d_out, G);
}

// Round 9
// 570.841 us; speedup vs baseline: 21.2250x; 1.1262x over previous
//
#include <hip/hip_runtime.h>
#include <hip/hip_fp16.h>

#define ALPHA 0.5f
#define SCAN_B 256
#define BSH 9            // bucket shift: 512 nodes/bucket
#define BSZ 512          // nodes per bucket
#define MAXB 512         // max buckets -> supports N <= 262144
#define CHUNK 4096       // edges per block in bucket_scatter

static inline int ceil_div(int a, int b) { return (a + b - 1) / b; }

struct alignas(8) half4 { __half2 a, b; };   // 4 fp16 = 8 B

typedef _Float16 half8 __attribute__((ext_vector_type(8)));
typedef float f32x4 __attribute__((ext_vector_type(4)));

// ---------------- bucket histogram (both directions) ----------------
__global__ void hist_kernel(const int* __restrict__ src, const int* __restrict__ dst,
                            unsigned int* __restrict__ bhI, unsigned int* __restrict__ bhO,
                            int E, int nbuck)
{
    __shared__ unsigned int hI[MAXB], hO[MAXB];
    for (int b = threadIdx.x; b < MAXB; b += blockDim.x) { hI[b] = 0; hO[b] = 0; }
    __syncthreads();
    for (int e = blockIdx.x * blockDim.x + threadIdx.x; e < E; e += gridDim.x * blockDim.x) {
        atomicAdd(&hI[dst[e] >> BSH], 1u);
        atomicAdd(&hO[src[e] >> BSH], 1u);
    }
    __syncthreads();
    for (int b = threadIdx.x; b < nbuck; b += blockDim.x) {
        if (hI[b]) atomicAdd(&bhI[b], hI[b]);
        if (hO[b]) atomicAdd(&bhO[b], hO[b]);
    }
}

// ---------------- bucket bases: exclusive scan of both hists (1 block, MAXB threads) ------
__global__ void bucket_base_kernel(const unsigned int* __restrict__ bhI,
                                   const unsigned int* __restrict__ bhO,
                                   unsigned int* __restrict__ baseI, unsigned int* __restrict__ baseO,
                                   unsigned int* __restrict__ curI, unsigned int* __restrict__ curO,
                                   int nbuck)
{
    __shared__ unsigned int tI[MAXB], tO[MAXB];
    int t = threadIdx.x;
    unsigned int vI = (t < nbuck) ? bhI[t] : 0u;
    unsigned int vO = (t < nbuck) ? bhO[t] : 0u;
    tI[t] = vI; tO[t] = vO;
    __syncthreads();
    for (int o = 1; o < MAXB; o <<= 1) {
        unsigned int xI = (t >= o) ? tI[t - o] : 0u;
        unsigned int xO = (t >= o) ? tO[t - o] : 0u;
        __syncthreads();
        tI[t] += xI; tO[t] += xO;
        __syncthreads();
    }
    if (t < nbuck) {
        baseI[t] = tI[t] - vI; baseO[t] = tO[t] - vO;
        curI[t]  = tI[t] - vI; curO[t]  = tO[t] - vO;
    }
}

// ---------------- bucket scatter with block-local reservation ----------------
__global__ void bucket_scatter_kernel(const int* __restrict__ src, const int* __restrict__ dst,
                                      unsigned int* __restrict__ curI, unsigned int* __restrict__ curO,
                                      int2* __restrict__ ebI, int2* __restrict__ ebO, int E)
{
    __shared__ unsigned int cI[MAXB], cO[MAXB], bI[MAXB], bO[MAXB];
    int t = threadIdx.x;
    for (int b = t; b < MAXB; b += blockDim.x) { cI[b] = 0; cO[b] = 0; }
    __syncthreads();
    int e0 = blockIdx.x * CHUNK;
    int e1 = min(E, e0 + CHUNK);
    for (int e = e0 + t; e < e1; e += blockDim.x) {
        atomicAdd(&cI[dst[e] >> BSH], 1u);
        atomicAdd(&cO[src[e] >> BSH], 1u);
    }
    __syncthreads();
    for (int b = t; b < MAXB; b += blockDim.x) {
        unsigned int n = cI[b];
        if (n) bI[b] = atomicAdd(&curI[b], n);
        cI[b] = 0;
        n = cO[b];
        if (n) bO[b] = atomicAdd(&curO[b], n);
        cO[b] = 0;
    }
    __syncthreads();
    for (int e = e0 + t; e < e1; e += blockDim.x) {
        int s = src[e], d = dst[e];
        int lb = d >> BSH;
        unsigned int p = bI[lb] + atomicAdd(&cI[lb], 1u);
        ebI[p] = make_int2(d, s);
        lb = s >> BSH;
        p = bO[lb] + atomicAdd(&cO[lb], 1u);
        ebO[p] = make_int2(s, d);
    }
}

// ---------------- per-bucket degree (LDS counters, coalesced write) ----------------
__global__ void bucket_deg_kernel(const int2* __restrict__ eb,
                                  const unsigned int* __restrict__ base,
                                  const unsigned int* __restrict__ bend,
                                  unsigned int* __restrict__ deg, int N)
{
    __shared__ unsigned int d[BSZ];
    int b = blockIdx.x, t = threadIdx.x;
    for (int i = t; i < BSZ; i += blockDim.x) d[i] = 0;
    __syncthreads();
    unsigned int lo = base[b], hi = bend[b];
    int nbase = b << BSH;
    for (unsigned int i = lo + t; i < hi; i += blockDim.x)
        atomicAdd(&d[eb[i].x - nbase], 1u);
    __syncthreads();
    for (int i = t; i < BSZ; i += blockDim.x) {
        int v = nbase + i;
        if (v < N) deg[v] = d[i];
    }
}

// ---------------- per-bucket adjacency scatter (LDS cursors, window-local) ----------------
__global__ void bucket_adj_kernel(const int2* __restrict__ eb,
                                  const unsigned int* __restrict__ base,
                                  const unsigned int* __restrict__ bend,
                                  const unsigned int* __restrict__ rowstart,
                                  int* __restrict__ adj, int N)
{
    __shared__ unsigned int cur[BSZ];
    int b = blockIdx.x, t = threadIdx.x;
    int nbase = b << BSH;
    for (int i = t; i < BSZ; i += blockDim.x) {
        int v = nbase + i;
        cur[i] = (v < N) ? rowstart[v] : 0u;
    }
    __syncthreads();
    unsigned int lo = base[b], hi = bend[b];
    for (unsigned int i = lo + t; i < hi; i += blockDim.x) {
        int2 e = eb[i];
        unsigned int p = atomicAdd(&cur[e.x - nbase], 1u);
        adj[p] = e.y;
    }
}

// ---------------- exclusive scan: per-block pass ----------------
__global__ void scan_blk_kernel(const unsigned int* __restrict__ deg,
                                unsigned int* __restrict__ excl,
                                unsigned int* __restrict__ bsum, int N)
{
    __shared__ unsigned int tmp[SCAN_B];
    int t = threadIdx.x;
    int i = blockIdx.x * SCAN_B + t;
    unsigned int v = (i < N) ? deg[i] : 0u;
    tmp[t] = v;
    __syncthreads();
    for (int o = 1; o < SCAN_B; o <<= 1) {
        unsigned int x = (t >= o) ? tmp[t - o] : 0u;
        __syncthreads();
        tmp[t] += x;
        __syncthreads();
    }
    if (i < N) excl[i] = tmp[t] - v;
    if (t == SCAN_B - 1) bsum[blockIdx.x] = tmp[t];
}

// ---------------- exclusive scan: top-level (single block, nb <= 1024) ----------------
__global__ void scan_top_kernel(unsigned int* __restrict__ bsum, int nb)
{
    __shared__ unsigned int tmp[1024];
    int t = threadIdx.x;
    unsigned int v = (t < nb) ? bsum[t] : 0u;
    tmp[t] = v;
    __syncthreads();
    for (int o = 1; o < 1024; o <<= 1) {
        unsigned int x = (t >= o) ? tmp[t - o] : 0u;
        __syncthreads();
        tmp[t] += x;
        __syncthreads();
    }
    if (t < nb) bsum[t] = tmp[t] - v;
}

// ---------------- scan finalize: add block offset, compute dinv ----------------
__global__ void scan_add_kernel(unsigned int* __restrict__ excl,
                                const unsigned int* __restrict__ bsum,
                                const unsigned int* __restrict__ deg,
                                float* __restrict__ dinv, int N)
{
    int i = blockIdx.x * SCAN_B + threadIdx.x;
    if (i < N) {
        excl[i] += bsum[blockIdx.x];
        unsigned int d = deg[i];
        dinv[i] = d ? rsqrtf((float)d) : 0.f;
    }
}

// ---------------- per-graph node counts via binary search (seg is sorted) ----------------
__global__ void seg_cnt_kernel(const int* __restrict__ seg, float* __restrict__ cnt, int N, int G)
{
    int g = blockIdx.x * blockDim.x + threadIdx.x;
    if (g >= G) return;
    int lo = 0, hi = N;
    while (lo < hi) { int m = (lo + hi) >> 1; if (seg[m] < g) lo = m + 1; else hi = m; }
    int s0 = lo;
    hi = N;
    while (lo < hi) { int m = (lo + hi) >> 1; if (seg[m] < g + 1) lo = m + 1; else hi = m; }
    cnt[g] = (float)(lo - s0);
}

// ---------------- layer2 weight prep: Wt[j][k] fp16 (pre-scaled, transposed), bcomb ------
__global__ void prep_w_kernel(const float* __restrict__ Wi, const float* __restrict__ Wr,
                              const float* __restrict__ bi, const float* __restrict__ br,
                              __half* __restrict__ Wt, float* __restrict__ bcomb)
{
    int idx = blockIdx.x * 256 + threadIdx.x;   // 128*256 elems
    if (idx < 128 * 256) {
        int j = idx >> 8, k = idx & 255;
        float w = (k < 128) ? (1.f - ALPHA) * Wi[k * 128 + j]
                            : ALPHA * Wr[(k - 128) * 128 + j];
        Wt[idx] = __float2half_rn(w);           // Wt[j*256 + k]
    }
    if (idx < 128) bcomb[idx] = (1.f - ALPHA) * bi[idx] + ALPHA * br[idx];
}

// ---------------- CSR gather, width 4 (layer 1 pre-projection) ----------------
__global__ void gather4_kernel(const unsigned int* __restrict__ rowI,
                               const unsigned int* __restrict__ degI,
                               const int* __restrict__ adjI,
                               const float* __restrict__ dinvI,
                               const unsigned int* __restrict__ rowO,
                               const unsigned int* __restrict__ degO,
                               const int* __restrict__ adjO,
                               const float* __restrict__ dinvO,
                               const float4* __restrict__ x4,
                               float4* __restrict__ accI, float4* __restrict__ accO, int N)
{
    int v = blockIdx.x * blockDim.x + threadIdx.x;
    if (v >= N) return;
    {
        unsigned int k = rowI[v], end = k + degI[v];
        float4 acc = {0.f, 0.f, 0.f, 0.f};
        for (; k < end; ++k) {
            int s = adjI[k];
            float w = dinvI[s];
            float4 xv = x4[s];
            acc.x += w * xv.x; acc.y += w * xv.y; acc.z += w * xv.z; acc.w += w * xv.w;
        }
        float dv = dinvI[v];
        accI[v] = make_float4(dv * acc.x, dv * acc.y, dv * acc.z, dv * acc.w);
    }
    {
        unsigned int k = rowO[v], end = k + degO[v];
        float4 acc = {0.f, 0.f, 0.f, 0.f};
        for (; k < end; ++k) {
            int s = adjO[k];
            float w = dinvO[s];
            float4 xv = x4[s];
            acc.x += w * xv.x; acc.y += w * xv.y; acc.z += w * xv.z; acc.w += w * xv.w;
        }
        float dv = dinvO[v];
        accO[v] = make_float4(dv * acc.x, dv * acc.y, dv * acc.z, dv * acc.w);
    }
}

// ---------------- layer 1 dense: (N,4)x2 -> (N,128) fp16, relu ----------------
#define L1_NODES 32
__global__ void layer1_kernel(const float* __restrict__ accI, const float* __restrict__ accO,
                              const float* __restrict__ Wi, const float* __restrict__ bi,
                              const float* __restrict__ Wr, const float* __restrict__ br,
                              __half* __restrict__ h1, int N)
{
    __shared__ float wI[4][128], wO[4][128], bb[128];
    int j = threadIdx.x;  // 128 threads
    for (int c = 0; c < 4; ++c) {
        wI[c][j] = (1.f - ALPHA) * Wi[c * 128 + j];
        wO[c][j] = ALPHA * Wr[c * 128 + j];
    }
    bb[j] = (1.f - ALPHA) * bi[j] + ALPHA * br[j];
    __syncthreads();
    int v0 = blockIdx.x * L1_NODES;
    int v1 = min(N, v0 + L1_NODES);
    for (int v = v0; v < v1; ++v) {
        float s = bb[j];
#pragma unroll
        for (int c = 0; c < 4; ++c)
            s += accI[v * 4 + c] * wI[c][j] + accO[v * 4 + c] * wO[c][j];
        h1[(size_t)v * 128 + j] = __float2half_rn(fmaxf(s, 0.f));
    }
}

// ---------------- CSR gather aggregation, width 128 fp16-in/fp16-out, both dirs ----------
// 32 lanes per node (half4 = 8 B each -> 256 B/row); f32 accumulate, fp16 store.
__global__ void gather128_kernel(const unsigned int* __restrict__ rowstartI,
                                 const unsigned int* __restrict__ degI,
                                 const int* __restrict__ adjI,
                                 const float* __restrict__ dinvI,
                                 const unsigned int* __restrict__ rowstartO,
                                 const unsigned int* __restrict__ degO,
                                 const int* __restrict__ adjO,
                                 const float* __restrict__ dinvO,
                                 const half4* __restrict__ hp,
                                 half4* __restrict__ outI, half4* __restrict__ outO, int N)
{
    int v = blockIdx.x * 8 + (threadIdx.x >> 5);
    if (v >= N) return;
    int lane = threadIdx.x & 31;
    const unsigned int* __restrict__ rowstart = blockIdx.y ? rowstartO : rowstartI;
    const unsigned int* __restrict__ deg      = blockIdx.y ? degO : degI;
    const int* __restrict__ adj               = blockIdx.y ? adjO : adjI;
    const float* __restrict__ dinv            = blockIdx.y ? dinvO : dinvI;
    half4* __restrict__ out                   = blockIdx.y ? outO : outI;

    unsigned int k = rowstart[v];
    unsigned int end = k + deg[v];
    float4 acc = {0.f, 0.f, 0.f, 0.f};
    for (; k + 2 <= end; k += 2) {
        int s0 = adj[k], s1 = adj[k + 1];
        float w0 = dinv[s0], w1 = dinv[s1];
        half4 v0 = hp[(size_t)s0 * 32 + lane];
        half4 v1 = hp[(size_t)s1 * 32 + lane];
        float2 a0 = __half22float2(v0.a), b0 = __half22float2(v0.b);
        float2 a1 = __half22float2(v1.a), b1 = __half22float2(v1.b);
        acc.x += w0 * a0.x + w1 * a1.x;
        acc.y += w0 * a0.y + w1 * a1.y;
        acc.z += w0 * b0.x + w1 * b1.x;
        acc.w += w0 * b0.y + w1 * b1.y;
    }
    if (k < end) {
        int s = adj[k];
        float w = dinv[s];
        half4 hv = hp[(size_t)s * 32 + lane];
        float2 a = __half22float2(hv.a), b = __half22float2(hv.b);
        acc.x += w * a.x; acc.y += w * a.y; acc.z += w * b.x; acc.w += w * b.y;
    }
    float dv = dinv[v];
    half4 o;
    o.a = __floats2half2_rn(dv * acc.x, dv * acc.y);
    o.b = __floats2half2_rn(dv * acc.z, dv * acc.w);
    out[(size_t)v * 32 + lane] = o;
}

// ---------------- layer 2 via MFMA: [aggI|aggO] (N,256)fp16 @ Wt^T -> (N,128) fp16 -------
// 256 threads = 4 waves; wave = 16 nodes x 128 cols (8 col-tiles), K=256 in 8 steps of 32.
// mfma_f32_16x16x32_f16: A row=lane&15, k=(lane>>4)*8+i; B col=lane&15, same k;
// C/D col=lane&15, row=(lane>>4)*4+reg  [verified mapping].
__global__ __launch_bounds__(256) void layer2_mfma_kernel(
    const __half* __restrict__ aggI, const __half* __restrict__ aggO,   // [N][128] each
    const __half* __restrict__ Wt,    // [128][256] pre-scaled, transposed
    const float* __restrict__ bcomb,  // [128]
    __half* __restrict__ h2, int N)
{
    int wave = threadIdx.x >> 6;
    int lane = threadIdx.x & 63;
    int v0 = blockIdx.x * 64 + wave * 16;
    int row = lane & 15;
    int kg  = lane >> 4;                 // 0..3
    int vsafe = min(v0 + row, N - 1);

    f32x4 acc[8];
#pragma unroll
    for (int t = 0; t < 8; ++t) acc[t] = (f32x4){0.f, 0.f, 0.f, 0.f};

#pragma unroll
    for (int ks = 0; ks < 8; ++ks) {
        const __half* asrc = (ks < 4) ? aggI : aggO;
        int kofs = (ks & 3) * 32 + kg * 8;
        half8 afrag = *(const half8*)&asrc[(size_t)vsafe * 128 + kofs];
        int kw = ks * 32 + kg * 8;
#pragma unroll
        for (int t = 0; t < 8; ++t) {
            int j = t * 16 + row;
            half8 bfrag = *(const half8*)&Wt[(size_t)j * 256 + kw];
            acc[t] = __builtin_amdgcn_mfma_f32_16x16x32_f16(afrag, bfrag, acc[t], 0, 0, 0);
        }
    }

#pragma unroll
    for (int t = 0; t < 8; ++t) {
        int j = t * 16 + row;
        float bj = bcomb[j];
#pragma unroll
        for (int r = 0; r < 4; ++r) {
            int vr = v0 + kg * 4 + r;
            if (vr < N)
                h2[(size_t)vr * 128 + j] = __float2half_rn(fmaxf(acc[t][r] + bj, 0.f));
        }
    }
}

// ---------------- pooling of fp16 aggregated features (batch_seg sorted) -----------------
#define POOL_NODES 32
__global__ void pool_kernel(const half4* __restrict__ aggI, const half4* __restrict__ aggO,
                            const int* __restrict__ seg,
                            float* __restrict__ poolI, float* __restrict__ poolO, int N)
{
    int j = threadIdx.x;  // 32 half4-lanes x 4 = 128 channels; threads 0..31 handle half4 each
    // 128 threads: thread j handles channel j (scalar half reads)
    int v0 = blockIdx.x * POOL_NODES;
    if (v0 >= N) return;
    int v1 = min(N, v0 + POOL_NODES);
    const __half* aI = (const __half*)aggI;
    const __half* aO = (const __half*)aggO;
    float sI = 0.f, sO = 0.f;
    int cur = seg[v0];
    for (int v = v0; v < v1; ++v) {
        int g = seg[v];
        if (g != cur) {
            atomicAdd(&poolI[cur * 128 + j], sI);
            atomicAdd(&poolO[cur * 128 + j], sO);
            sI = 0.f; sO = 0.f; cur = g;
        }
        sI += __half2float(aI[(size_t)v * 128 + j]);
        sO += __half2float(aO[(size_t)v * 128 + j]);
    }
    atomicAdd(&poolI[cur * 128 + j], sI);
    atomicAdd(&poolO[cur * 128 + j], sO);
}

// ---------------- final: (G,128)x2 -> (G,120) with mean ----------------
__global__ void final_kernel(const float* __restrict__ poolI, const float* __restrict__ poolO,
                             const float* __restrict__ cnt,
                             const float* __restrict__ Wo, const float* __restrict__ bo,
                             const float* __restrict__ Wor, const float* __restrict__ bor,
                             float* __restrict__ out, int G)
{
    int g = blockIdx.x;
    int j = threadIdx.x;  // 120 threads
    if (g >= G || j >= 120) return;
    float acc = 0.f;
    for (int k = 0; k < 128; ++k) {
        acc += poolI[g * 128 + k] * ((1.f - ALPHA) * Wo[k * 120 + j])
             + poolO[g * 128 + k] * (ALPHA * Wor[k * 120 + j]);
    }
    float c = cnt[g];
    float bcomb = (1.f - ALPHA) * bo[j] + ALPHA * bor[j];
    out[g * 120 + j] = (c > 0.f) ? (acc / c + bcomb) : 0.f;
}

extern "C" void kernel_launch(void* const* d_in, const int* in_sizes, int n_in,
                              void* d_out, int out_size, void* d_ws, size_t ws_size,
                              hipStream_t stream)
{
    const float* x      = (const float*)d_in[0];
    const int*   ei     = (const int*)d_in[1];
    const int*   seg    = (const int*)d_in[2];
    const float* W_in   = (const float*)d_in[3];
    const float* b_in   = (const float*)d_in[4];
    const float* W_in_r = (const float*)d_in[5];
    const float* b_in_r = (const float*)d_in[6];
    const float* W_mid  = (const float*)d_in[7];
    const float* b_mid  = (const float*)d_in[8];
    const float* W_mid_r= (const float*)d_in[9];
    const float* b_mid_r= (const float*)d_in[10];
    const float* W_out  = (const float*)d_in[11];
    const float* b_out  = (const float*)d_in[12];
    const float* W_out_r= (const float*)d_in[13];
    const float* b_out_r= (const float*)d_in[14];

    const int N = in_sizes[0] / 4;
    const int E = in_sizes[1] / 2;
    const int G = out_size / 120;
    const int* src = ei;
    const int* dst = ei + E;
    const int NBLK  = ceil_div(N, SCAN_B);   // <= 1024 (N <= 262144)
    const int NBUCK = ceil_div(N, BSZ);      // <= 512

    // -------- workspace layout (4-byte units) --------
    char* wsb = (char*)d_ws;
    size_t off = 0;
    auto alloc = [&](size_t elems) { void* p = wsb + off * 4; off += elems; return p; };

    unsigned int* bhI   = (unsigned int*)alloc(MAXB);     // zeroed
    unsigned int* bhO   = (unsigned int*)alloc(MAXB);     // zeroed
    float*        poolI = (float*)alloc((size_t)G * 128); // zeroed
    float*        poolO = (float*)alloc((size_t)G * 128); // zeroed
    size_t zero_elems = off;
    float*        cnt   = (float*)alloc(G);               // fully written by seg_cnt
    unsigned int* baseI = (unsigned int*)alloc(MAXB);
    unsigned int* baseO = (unsigned int*)alloc(MAXB);
    unsigned int* curI  = (unsigned int*)alloc(MAXB);
    unsigned int* curO  = (unsigned int*)alloc(MAXB);
    unsigned int* degI  = (unsigned int*)alloc(N);
    unsigned int* degO  = (unsigned int*)alloc(N);
    float*        dinvI = (float*)alloc(N);
    float*        dinvO = (float*)alloc(N);
    unsigned int* rowI  = (unsigned int*)alloc(N);        // exclusive row starts
    unsigned int* rowO  = (unsigned int*)alloc(N);
    int*          adjI  = (int*)alloc(E);
    int*          adjO  = (int*)alloc(E);
    unsigned int* bsum  = (unsigned int*)alloc(1024);
    __half*       Wt    = (__half*)alloc(128 * 256 / 2);  // 32768 halves
    float*        bcomb = (float*)alloc(128);
    off = (off + 3) & ~(size_t)3;                         // 16B align
    float* acc4I = (float*)alloc((size_t)N * 4);
    float* acc4O = (float*)alloc((size_t)N * 4);
    __half* hbuf = (__half*)alloc((size_t)N * 64);        // h1 / h2 fp16 (N*128 halves)
    __half* aggI = (__half*)alloc((size_t)N * 64);        // fp16 agg in-direction
    __half* aggO = (__half*)alloc((size_t)N * 64);        // fp16 agg out-direction
    (void)ws_size;

    // Bucketed edge buffers alias agg buffers (dead until gather128 writes them).
    // ebI needs E*8 B = 12.8 MB; aggI is N*256 B = 25.6 MB. OK.
    int2* ebI = (int2*)aggI;
    int2* ebO = (int2*)aggO;

    hipMemsetAsync(d_ws, 0, zero_elems * 4, stream);

    const int T = 256;
    // ---- binned CSR build ----
    hist_kernel<<<ceil_div(E, T * 16), T, 0, stream>>>(src, dst, bhI, bhO, E, NBUCK);
    bucket_base_kernel<<<1, MAXB, 0, stream>>>(bhI, bhO, baseI, baseO, curI, curO, NBUCK);
    bucket_scatter_kernel<<<ceil_div(E, CHUNK), T, 0, stream>>>(src, dst, curI, curO, ebI, ebO, E);
    // after bucket_scatter, curI[b]/curO[b] == bucket end
    bucket_deg_kernel<<<NBUCK, T, 0, stream>>>(ebI, baseI, curI, degI, N);
    bucket_deg_kernel<<<NBUCK, T, 0, stream>>>(ebO, baseO, curO, degO, N);
    scan_blk_kernel<<<NBLK, SCAN_B, 0, stream>>>(degI, rowI, bsum, N);
    scan_top_kernel<<<1, 1024, 0, stream>>>(bsum, NBLK);
    scan_add_kernel<<<NBLK, SCAN_B, 0, stream>>>(rowI, bsum, degI, dinvI, N);
    scan_blk_kernel<<<NBLK, SCAN_B, 0, stream>>>(degO, rowO, bsum, N);
    scan_top_kernel<<<1, 1024, 0, stream>>>(bsum, NBLK);
    scan_add_kernel<<<NBLK, SCAN_B, 0, stream>>>(rowO, bsum, degO, dinvO, N);
    bucket_adj_kernel<<<NBUCK, T, 0, stream>>>(ebI, baseI, curI, rowI, adjI, N);
    bucket_adj_kernel<<<NBUCK, T, 0, stream>>>(ebO, baseO, curO, rowO, adjO, N);
    seg_cnt_kernel<<<ceil_div(G, T), T, 0, stream>>>(seg, cnt, N, G);
    prep_w_kernel<<<128, 256, 0, stream>>>(W_mid, W_mid_r, b_mid, b_mid_r, Wt, bcomb);

    // ---- layer 1: width-4 gathers then dense 4->128 (fp16 out) ----
    gather4_kernel<<<ceil_div(N, T), T, 0, stream>>>(rowI, degI, adjI, dinvI,
                                                     rowO, degO, adjO, dinvO,
                                                     (const float4*)x,
                                                     (float4*)acc4I, (float4*)acc4O, N);
    layer1_kernel<<<ceil_div(N, L1_NODES), 128, 0, stream>>>(acc4I, acc4O,
                                                             W_in, b_in, W_in_r, b_in_r, hbuf, N);
    // ---- layer 2: fp16 gather (both dirs) then MFMA GEMM (fp16 out) ----
    gather128_kernel<<<dim3(ceil_div(N, 8), 2), 256, 0, stream>>>(
        rowI, degI, adjI, dinvI, rowO, degO, adjO, dinvO,
        (const half4*)hbuf, (half4*)aggI, (half4*)aggO, N);
    layer2_mfma_kernel<<<ceil_div(N, 64), 256, 0, stream>>>(
        aggI, aggO, Wt, bcomb, hbuf, N);
    // ---- layer 3: fp16 gather, pool, final projection ----
    gather128_kernel<<<dim3(ceil_div(N, 8), 2), 256, 0, stream>>>(
        rowI, degI, adjI, dinvI, rowO, degO, adjO, dinvO,
        (const half4*)hbuf, (half4*)aggI, (half4*)aggO, N);
    pool_kernel<<<ceil_div(N, POOL_NODES), 128, 0, stream>>>(
        (const half4*)aggI, (const half4*)aggO, seg, poolI, poolO, N);
    final_kernel<<<G, 128, 0, stream>>>(poolI, poolO, cnt,
                                        W_out, b_out, W_out_r, b_out_r, (float*)d_out, G);
}

// Round 10
// 509.497 us; speedup vs baseline: 23.7806x; 1.1204x over previous
//
#include <hip/hip_runtime.h>
#include <hip/hip_fp16.h>

#define ALPHA 0.5f
#define SCAN_B 256
#define BSH 9            // bucket shift: 512 nodes/bucket
#define BSZ 512          // nodes per bucket
#define MAXB 512         // max buckets -> supports N <= 262144
#define CHUNK 4096       // edges per block in bucket_scatter

static inline int ceil_div(int a, int b) { return (a + b - 1) / b; }

struct alignas(8) half4 { __half2 a, b; };   // 4 fp16 = 8 B

typedef _Float16 half8 __attribute__((ext_vector_type(8)));
typedef float f32x4 __attribute__((ext_vector_type(4)));

// ---------------- bucket histogram (both directions) ----------------
__global__ void hist_kernel(const int* __restrict__ src, const int* __restrict__ dst,
                            unsigned int* __restrict__ bhI, unsigned int* __restrict__ bhO,
                            int E, int nbuck)
{
    __shared__ unsigned int hI[MAXB], hO[MAXB];
    for (int b = threadIdx.x; b < MAXB; b += blockDim.x) { hI[b] = 0; hO[b] = 0; }
    __syncthreads();
    for (int e = blockIdx.x * blockDim.x + threadIdx.x; e < E; e += gridDim.x * blockDim.x) {
        atomicAdd(&hI[dst[e] >> BSH], 1u);
        atomicAdd(&hO[src[e] >> BSH], 1u);
    }
    __syncthreads();
    for (int b = threadIdx.x; b < nbuck; b += blockDim.x) {
        if (hI[b]) atomicAdd(&bhI[b], hI[b]);
        if (hO[b]) atomicAdd(&bhO[b], hO[b]);
    }
}

// ---------------- bucket bases: exclusive scan of both hists (1 block, MAXB threads) ------
__global__ void bucket_base_kernel(const unsigned int* __restrict__ bhI,
                                   const unsigned int* __restrict__ bhO,
                                   unsigned int* __restrict__ baseI, unsigned int* __restrict__ baseO,
                                   unsigned int* __restrict__ curI, unsigned int* __restrict__ curO,
                                   int nbuck)
{
    __shared__ unsigned int tI[MAXB], tO[MAXB];
    int t = threadIdx.x;
    unsigned int vI = (t < nbuck) ? bhI[t] : 0u;
    unsigned int vO = (t < nbuck) ? bhO[t] : 0u;
    tI[t] = vI; tO[t] = vO;
    __syncthreads();
    for (int o = 1; o < MAXB; o <<= 1) {
        unsigned int xI = (t >= o) ? tI[t - o] : 0u;
        unsigned int xO = (t >= o) ? tO[t - o] : 0u;
        __syncthreads();
        tI[t] += xI; tO[t] += xO;
        __syncthreads();
    }
    if (t < nbuck) {
        baseI[t] = tI[t] - vI; baseO[t] = tO[t] - vO;
        curI[t]  = tI[t] - vI; curO[t]  = tO[t] - vO;
    }
}

// ---------------- bucket scatter with block-local reservation ----------------
__global__ void bucket_scatter_kernel(const int* __restrict__ src, const int* __restrict__ dst,
                                      unsigned int* __restrict__ curI, unsigned int* __restrict__ curO,
                                      int2* __restrict__ ebI, int2* __restrict__ ebO, int E)
{
    __shared__ unsigned int cI[MAXB], cO[MAXB], bI[MAXB], bO[MAXB];
    int t = threadIdx.x;
    for (int b = t; b < MAXB; b += blockDim.x) { cI[b] = 0; cO[b] = 0; }
    __syncthreads();
    int e0 = blockIdx.x * CHUNK;
    int e1 = min(E, e0 + CHUNK);
    for (int e = e0 + t; e < e1; e += blockDim.x) {
        atomicAdd(&cI[dst[e] >> BSH], 1u);
        atomicAdd(&cO[src[e] >> BSH], 1u);
    }
    __syncthreads();
    for (int b = t; b < MAXB; b += blockDim.x) {
        unsigned int n = cI[b];
        if (n) bI[b] = atomicAdd(&curI[b], n);
        cI[b] = 0;
        n = cO[b];
        if (n) bO[b] = atomicAdd(&curO[b], n);
        cO[b] = 0;
    }
    __syncthreads();
    for (int e = e0 + t; e < e1; e += blockDim.x) {
        int s = src[e], d = dst[e];
        int lb = d >> BSH;
        unsigned int p = bI[lb] + atomicAdd(&cI[lb], 1u);
        ebI[p] = make_int2(d, s);
        lb = s >> BSH;
        p = bO[lb] + atomicAdd(&cO[lb], 1u);
        ebO[p] = make_int2(s, d);
    }
}

// ---------------- per-bucket degree, both dirs via blockIdx.y ----------------
__global__ void bucket_deg2_kernel(const int2* __restrict__ ebI, const int2* __restrict__ ebO,
                                   const unsigned int* __restrict__ baseI, const unsigned int* __restrict__ baseO,
                                   const unsigned int* __restrict__ bendI, const unsigned int* __restrict__ bendO,
                                   unsigned int* __restrict__ degI, unsigned int* __restrict__ degO, int N)
{
    const int2* __restrict__ eb          = blockIdx.y ? ebO : ebI;
    const unsigned int* __restrict__ base = blockIdx.y ? baseO : baseI;
    const unsigned int* __restrict__ bend = blockIdx.y ? bendO : bendI;
    unsigned int* __restrict__ deg        = blockIdx.y ? degO : degI;
    __shared__ unsigned int d[BSZ];
    int b = blockIdx.x, t = threadIdx.x;
    for (int i = t; i < BSZ; i += blockDim.x) d[i] = 0;
    __syncthreads();
    unsigned int lo = base[b], hi = bend[b];
    int nbase = b << BSH;
    for (unsigned int i = lo + t; i < hi; i += blockDim.x)
        atomicAdd(&d[eb[i].x - nbase], 1u);
    __syncthreads();
    for (int i = t; i < BSZ; i += blockDim.x) {
        int v = nbase + i;
        if (v < N) deg[v] = d[i];
    }
}

// ---------------- per-bucket adjacency scatter, both dirs via blockIdx.y -----------------
__global__ void bucket_adj2_kernel(const int2* __restrict__ ebI, const int2* __restrict__ ebO,
                                   const unsigned int* __restrict__ baseI, const unsigned int* __restrict__ baseO,
                                   const unsigned int* __restrict__ bendI, const unsigned int* __restrict__ bendO,
                                   const unsigned int* __restrict__ rowI, const unsigned int* __restrict__ rowO,
                                   int* __restrict__ adjI, int* __restrict__ adjO, int N)
{
    const int2* __restrict__ eb           = blockIdx.y ? ebO : ebI;
    const unsigned int* __restrict__ base  = blockIdx.y ? baseO : baseI;
    const unsigned int* __restrict__ bend  = blockIdx.y ? bendO : bendI;
    const unsigned int* __restrict__ rowst = blockIdx.y ? rowO : rowI;
    int* __restrict__ adj                  = blockIdx.y ? adjO : adjI;
    __shared__ unsigned int cur[BSZ];
    int b = blockIdx.x, t = threadIdx.x;
    int nbase = b << BSH;
    for (int i = t; i < BSZ; i += blockDim.x) {
        int v = nbase + i;
        cur[i] = (v < N) ? rowst[v] : 0u;
    }
    __syncthreads();
    unsigned int lo = base[b], hi = bend[b];
    for (unsigned int i = lo + t; i < hi; i += blockDim.x) {
        int2 e = eb[i];
        unsigned int p = atomicAdd(&cur[e.x - nbase], 1u);
        adj[p] = e.y;
    }
}

// ---------------- exclusive scan: per-block pass, both dirs ----------------
__global__ void scan_blk2_kernel(const unsigned int* __restrict__ degI, const unsigned int* __restrict__ degO,
                                 unsigned int* __restrict__ exclI, unsigned int* __restrict__ exclO,
                                 unsigned int* __restrict__ bsumI, unsigned int* __restrict__ bsumO, int N)
{
    const unsigned int* __restrict__ deg = blockIdx.y ? degO : degI;
    unsigned int* __restrict__ excl      = blockIdx.y ? exclO : exclI;
    unsigned int* __restrict__ bsum      = blockIdx.y ? bsumO : bsumI;
    __shared__ unsigned int tmp[SCAN_B];
    int t = threadIdx.x;
    int i = blockIdx.x * SCAN_B + t;
    unsigned int v = (i < N) ? deg[i] : 0u;
    tmp[t] = v;
    __syncthreads();
    for (int o = 1; o < SCAN_B; o <<= 1) {
        unsigned int x = (t >= o) ? tmp[t - o] : 0u;
        __syncthreads();
        tmp[t] += x;
        __syncthreads();
    }
    if (i < N) excl[i] = tmp[t] - v;
    if (t == SCAN_B - 1) bsum[blockIdx.x] = tmp[t];
}

// ---------------- exclusive scan: top-level, both dirs (grid.x = 2) ----------------
__global__ void scan_top2_kernel(unsigned int* __restrict__ bsumI, unsigned int* __restrict__ bsumO, int nb)
{
    unsigned int* __restrict__ bsum = blockIdx.x ? bsumO : bsumI;
    __shared__ unsigned int tmp[1024];
    int t = threadIdx.x;
    unsigned int v = (t < nb) ? bsum[t] : 0u;
    tmp[t] = v;
    __syncthreads();
    for (int o = 1; o < 1024; o <<= 1) {
        unsigned int x = (t >= o) ? tmp[t - o] : 0u;
        __syncthreads();
        tmp[t] += x;
        __syncthreads();
    }
    if (t < nb) bsum[t] = tmp[t] - v;
}

// ---------------- scan finalize + dinv, both dirs ----------------
__global__ void scan_add2_kernel(unsigned int* __restrict__ exclI, unsigned int* __restrict__ exclO,
                                 const unsigned int* __restrict__ bsumI, const unsigned int* __restrict__ bsumO,
                                 const unsigned int* __restrict__ degI, const unsigned int* __restrict__ degO,
                                 float* __restrict__ dinvI, float* __restrict__ dinvO, int N)
{
    unsigned int* __restrict__ excl       = blockIdx.y ? exclO : exclI;
    const unsigned int* __restrict__ bsum = blockIdx.y ? bsumO : bsumI;
    const unsigned int* __restrict__ deg  = blockIdx.y ? degO : degI;
    float* __restrict__ dinv              = blockIdx.y ? dinvO : dinvI;
    int i = blockIdx.x * SCAN_B + threadIdx.x;
    if (i < N) {
        excl[i] += bsum[blockIdx.x];
        unsigned int d = deg[i];
        dinv[i] = d ? rsqrtf((float)d) : 0.f;
    }
}

// ---------------- per-graph node counts via binary search (seg is sorted) ----------------
__global__ void seg_cnt_kernel(const int* __restrict__ seg, float* __restrict__ cnt, int N, int G)
{
    int g = blockIdx.x * blockDim.x + threadIdx.x;
    if (g >= G) return;
    int lo = 0, hi = N;
    while (lo < hi) { int m = (lo + hi) >> 1; if (seg[m] < g) lo = m + 1; else hi = m; }
    int s0 = lo;
    hi = N;
    while (lo < hi) { int m = (lo + hi) >> 1; if (seg[m] < g + 1) lo = m + 1; else hi = m; }
    cnt[g] = (float)(lo - s0);
}

// ---------------- layer2 weight prep: Wt[j][k] fp16 (pre-scaled, transposed), bcomb ------
__global__ void prep_w_kernel(const float* __restrict__ Wi, const float* __restrict__ Wr,
                              const float* __restrict__ bi, const float* __restrict__ br,
                              __half* __restrict__ Wt, float* __restrict__ bcomb)
{
    int idx = blockIdx.x * 256 + threadIdx.x;   // 128*256 elems
    if (idx < 128 * 256) {
        int j = idx >> 8, k = idx & 255;
        float w = (k < 128) ? (1.f - ALPHA) * Wi[k * 128 + j]
                            : ALPHA * Wr[(k - 128) * 128 + j];
        Wt[idx] = __float2half_rn(w);           // Wt[j*256 + k]
    }
    if (idx < 128) bcomb[idx] = (1.f - ALPHA) * bi[idx] + ALPHA * br[idx];
}

// ---------------- CSR gather, width 4 (layer 1 pre-projection) ----------------
__global__ void gather4_kernel(const unsigned int* __restrict__ rowI,
                               const unsigned int* __restrict__ degI,
                               const int* __restrict__ adjI,
                               const float* __restrict__ dinvI,
                               const unsigned int* __restrict__ rowO,
                               const unsigned int* __restrict__ degO,
                               const int* __restrict__ adjO,
                               const float* __restrict__ dinvO,
                               const float4* __restrict__ x4,
                               float4* __restrict__ accI, float4* __restrict__ accO, int N)
{
    int v = blockIdx.x * blockDim.x + threadIdx.x;
    if (v >= N) return;
    {
        unsigned int k = rowI[v], end = k + degI[v];
        float4 acc = {0.f, 0.f, 0.f, 0.f};
        for (; k < end; ++k) {
            int s = adjI[k];
            float w = dinvI[s];
            float4 xv = x4[s];
            acc.x += w * xv.x; acc.y += w * xv.y; acc.z += w * xv.z; acc.w += w * xv.w;
        }
        float dv = dinvI[v];
        accI[v] = make_float4(dv * acc.x, dv * acc.y, dv * acc.z, dv * acc.w);
    }
    {
        unsigned int k = rowO[v], end = k + degO[v];
        float4 acc = {0.f, 0.f, 0.f, 0.f};
        for (; k < end; ++k) {
            int s = adjO[k];
            float w = dinvO[s];
            float4 xv = x4[s];
            acc.x += w * xv.x; acc.y += w * xv.y; acc.z += w * xv.z; acc.w += w * xv.w;
        }
        float dv = dinvO[v];
        accO[v] = make_float4(dv * acc.x, dv * acc.y, dv * acc.z, dv * acc.w);
    }
}

// ---------------- layer 1 dense: (N,4)x2 -> (N,128) fp16, relu ----------------
#define L1_NODES 32
__global__ void layer1_kernel(const float* __restrict__ accI, const float* __restrict__ accO,
                              const float* __restrict__ Wi, const float* __restrict__ bi,
                              const float* __restrict__ Wr, const float* __restrict__ br,
                              __half* __restrict__ h1, int N)
{
    __shared__ float wI[4][128], wO[4][128], bb[128];
    int j = threadIdx.x;  // 128 threads
    for (int c = 0; c < 4; ++c) {
        wI[c][j] = (1.f - ALPHA) * Wi[c * 128 + j];
        wO[c][j] = ALPHA * Wr[c * 128 + j];
    }
    bb[j] = (1.f - ALPHA) * bi[j] + ALPHA * br[j];
    __syncthreads();
    int v0 = blockIdx.x * L1_NODES;
    int v1 = min(N, v0 + L1_NODES);
    for (int v = v0; v < v1; ++v) {
        float s = bb[j];
#pragma unroll
        for (int c = 0; c < 4; ++c)
            s += accI[v * 4 + c] * wI[c][j] + accO[v * 4 + c] * wO[c][j];
        h1[(size_t)v * 128 + j] = __float2half_rn(fmaxf(s, 0.f));
    }
}

// ---------------- CSR gather aggregation, width 128 fp16: 16 lanes x half8 per node ------
// wave64 covers 4 nodes -> 2x rows in flight vs 32-lane layout; 16 B loads per lane.
__global__ void gather128_kernel(const unsigned int* __restrict__ rowstartI,
                                 const unsigned int* __restrict__ degI,
                                 const int* __restrict__ adjI,
                                 const float* __restrict__ dinvI,
                                 const unsigned int* __restrict__ rowstartO,
                                 const unsigned int* __restrict__ degO,
                                 const int* __restrict__ adjO,
                                 const float* __restrict__ dinvO,
                                 const half8* __restrict__ hp,
                                 half8* __restrict__ outI, half8* __restrict__ outO, int N)
{
    int v = blockIdx.x * 16 + (threadIdx.x >> 4);
    if (v >= N) return;
    int lane = threadIdx.x & 15;
    const unsigned int* __restrict__ rowstart = blockIdx.y ? rowstartO : rowstartI;
    const unsigned int* __restrict__ deg      = blockIdx.y ? degO : degI;
    const int* __restrict__ adj               = blockIdx.y ? adjO : adjI;
    const float* __restrict__ dinv            = blockIdx.y ? dinvO : dinvI;
    half8* __restrict__ out                   = blockIdx.y ? outO : outI;

    unsigned int k = rowstart[v];
    unsigned int end = k + deg[v];
    float acc[8];
#pragma unroll
    for (int i = 0; i < 8; ++i) acc[i] = 0.f;

    for (; k + 2 <= end; k += 2) {
        int s0 = adj[k], s1 = adj[k + 1];
        float w0 = dinv[s0], w1 = dinv[s1];
        half8 h0 = hp[(size_t)s0 * 16 + lane];
        half8 h1 = hp[(size_t)s1 * 16 + lane];
#pragma unroll
        for (int i = 0; i < 8; ++i)
            acc[i] += w0 * (float)h0[i] + w1 * (float)h1[i];
    }
    if (k < end) {
        int s = adj[k];
        float w = dinv[s];
        half8 hv = hp[(size_t)s * 16 + lane];
#pragma unroll
        for (int i = 0; i < 8; ++i)
            acc[i] += w * (float)hv[i];
    }
    float dv = dinv[v];
    half8 o;
#pragma unroll
    for (int i = 0; i < 8; ++i) o[i] = (_Float16)(dv * acc[i]);
    out[(size_t)v * 16 + lane] = o;
}

// ---------------- layer 2 via MFMA: [aggI|aggO] (N,256)fp16 @ Wt^T -> (N,128) fp16 -------
// 256 threads = 4 waves; wave = 16 nodes x 128 cols (8 col-tiles), K=256 in 8 steps of 32.
__global__ __launch_bounds__(256) void layer2_mfma_kernel(
    const __half* __restrict__ aggI, const __half* __restrict__ aggO,   // [N][128] each
    const __half* __restrict__ Wt,    // [128][256] pre-scaled, transposed
    const float* __restrict__ bcomb,  // [128]
    __half* __restrict__ h2, int N)
{
    int wave = threadIdx.x >> 6;
    int lane = threadIdx.x & 63;
    int v0 = blockIdx.x * 64 + wave * 16;
    int row = lane & 15;
    int kg  = lane >> 4;                 // 0..3
    int vsafe = min(v0 + row, N - 1);

    f32x4 acc[8];
#pragma unroll
    for (int t = 0; t < 8; ++t) acc[t] = (f32x4){0.f, 0.f, 0.f, 0.f};

#pragma unroll
    for (int ks = 0; ks < 8; ++ks) {
        const __half* asrc = (ks < 4) ? aggI : aggO;
        int kofs = (ks & 3) * 32 + kg * 8;
        half8 afrag = *(const half8*)&asrc[(size_t)vsafe * 128 + kofs];
        int kw = ks * 32 + kg * 8;
#pragma unroll
        for (int t = 0; t < 8; ++t) {
            int j = t * 16 + row;
            half8 bfrag = *(const half8*)&Wt[(size_t)j * 256 + kw];
            acc[t] = __builtin_amdgcn_mfma_f32_16x16x32_f16(afrag, bfrag, acc[t], 0, 0, 0);
        }
    }

#pragma unroll
    for (int t = 0; t < 8; ++t) {
        int j = t * 16 + row;
        float bj = bcomb[j];
#pragma unroll
        for (int r = 0; r < 4; ++r) {
            int vr = v0 + kg * 4 + r;
            if (vr < N)
                h2[(size_t)vr * 128 + j] = __float2half_rn(fmaxf(acc[t][r] + bj, 0.f));
        }
    }
}

// ---------------- pooling of fp16 aggregated features (batch_seg sorted) -----------------
#define POOL_NODES 32
__global__ void pool_kernel(const __half* __restrict__ aI, const __half* __restrict__ aO,
                            const int* __restrict__ seg,
                            float* __restrict__ poolI, float* __restrict__ poolO, int N)
{
    int j = threadIdx.x;  // 128 threads, one channel each
    int v0 = blockIdx.x * POOL_NODES;
    if (v0 >= N) return;
    int v1 = min(N, v0 + POOL_NODES);
    float sI = 0.f, sO = 0.f;
    int cur = seg[v0];
    for (int v = v0; v < v1; ++v) {
        int g = seg[v];
        if (g != cur) {
            atomicAdd(&poolI[cur * 128 + j], sI);
            atomicAdd(&poolO[cur * 128 + j], sO);
            sI = 0.f; sO = 0.f; cur = g;
        }
        sI += __half2float(aI[(size_t)v * 128 + j]);
        sO += __half2float(aO[(size_t)v * 128 + j]);
    }
    atomicAdd(&poolI[cur * 128 + j], sI);
    atomicAdd(&poolO[cur * 128 + j], sO);
}

// ---------------- final: (G,128)x2 -> (G,120) with mean ----------------
__global__ void final_kernel(const float* __restrict__ poolI, const float* __restrict__ poolO,
                             const float* __restrict__ cnt,
                             const float* __restrict__ Wo, const float* __restrict__ bo,
                             const float* __restrict__ Wor, const float* __restrict__ bor,
                             float* __restrict__ out, int G)
{
    int g = blockIdx.x;
    int j = threadIdx.x;  // 120 threads
    if (g >= G || j >= 120) return;
    float acc = 0.f;
    for (int k = 0; k < 128; ++k) {
        acc += poolI[g * 128 + k] * ((1.f - ALPHA) * Wo[k * 120 + j])
             + poolO[g * 128 + k] * (ALPHA * Wor[k * 120 + j]);
    }
    float c = cnt[g];
    float bcomb = (1.f - ALPHA) * bo[j] + ALPHA * bor[j];
    out[g * 120 + j] = (c > 0.f) ? (acc / c + bcomb) : 0.f;
}

extern "C" void kernel_launch(void* const* d_in, const int* in_sizes, int n_in,
                              void* d_out, int out_size, void* d_ws, size_t ws_size,
                              hipStream_t stream)
{
    const float* x      = (const float*)d_in[0];
    const int*   ei     = (const int*)d_in[1];
    const int*   seg    = (const int*)d_in[2];
    const float* W_in   = (const float*)d_in[3];
    const float* b_in   = (const float*)d_in[4];
    const float* W_in_r = (const float*)d_in[5];
    const float* b_in_r = (const float*)d_in[6];
    const float* W_mid  = (const float*)d_in[7];
    const float* b_mid  = (const float*)d_in[8];
    const float* W_mid_r= (const float*)d_in[9];
    const float* b_mid_r= (const float*)d_in[10];
    const float* W_out  = (const float*)d_in[11];
    const float* b_out  = (const float*)d_in[12];
    const float* W_out_r= (const float*)d_in[13];
    const float* b_out_r= (const float*)d_in[14];

    const int N = in_sizes[0] / 4;
    const int E = in_sizes[1] / 2;
    const int G = out_size / 120;
    const int* src = ei;
    const int* dst = ei + E;
    const int NBLK  = ceil_div(N, SCAN_B);   // <= 1024 (N <= 262144)
    const int NBUCK = ceil_div(N, BSZ);      // <= 512

    // -------- workspace layout (4-byte units) --------
    char* wsb = (char*)d_ws;
    size_t off = 0;
    auto alloc = [&](size_t elems) { void* p = wsb + off * 4; off += elems; return p; };

    unsigned int* bhI   = (unsigned int*)alloc(MAXB);     // zeroed
    unsigned int* bhO   = (unsigned int*)alloc(MAXB);     // zeroed
    float*        poolI = (float*)alloc((size_t)G * 128); // zeroed
    float*        poolO = (float*)alloc((size_t)G * 128); // zeroed
    size_t zero_elems = off;
    float*        cnt   = (float*)alloc(G);               // fully written by seg_cnt
    unsigned int* baseI = (unsigned int*)alloc(MAXB);
    unsigned int* baseO = (unsigned int*)alloc(MAXB);
    unsigned int* curI  = (unsigned int*)alloc(MAXB);
    unsigned int* curO  = (unsigned int*)alloc(MAXB);
    unsigned int* degI  = (unsigned int*)alloc(N);
    unsigned int* degO  = (unsigned int*)alloc(N);
    float*        dinvI = (float*)alloc(N);
    float*        dinvO = (float*)alloc(N);
    unsigned int* rowI  = (unsigned int*)alloc(N);        // exclusive row starts
    unsigned int* rowO  = (unsigned int*)alloc(N);
    int*          adjI  = (int*)alloc(E);
    int*          adjO  = (int*)alloc(E);
    unsigned int* bsumI = (unsigned int*)alloc(1024);
    unsigned int* bsumO = (unsigned int*)alloc(1024);
    __half*       Wt    = (__half*)alloc(128 * 256 / 2);  // 32768 halves
    float*        bcomb = (float*)alloc(128);
    off = (off + 3) & ~(size_t)3;                         // 16B align
    float* acc4I = (float*)alloc((size_t)N * 4);
    float* acc4O = (float*)alloc((size_t)N * 4);
    __half* hbuf = (__half*)alloc((size_t)N * 64);        // h1 / h2 fp16 (N*128 halves)
    __half* aggI = (__half*)alloc((size_t)N * 64);        // fp16 agg in-direction
    __half* aggO = (__half*)alloc((size_t)N * 64);        // fp16 agg out-direction
    (void)ws_size;

    // Bucketed edge buffers alias agg buffers (dead until gather128 writes them).
    int2* ebI = (int2*)aggI;
    int2* ebO = (int2*)aggO;

    hipMemsetAsync(d_ws, 0, zero_elems * 4, stream);

    const int T = 256;
    // ---- binned CSR build ----
    hist_kernel<<<ceil_div(E, T * 16), T, 0, stream>>>(src, dst, bhI, bhO, E, NBUCK);
    bucket_base_kernel<<<1, MAXB, 0, stream>>>(bhI, bhO, baseI, baseO, curI, curO, NBUCK);
    bucket_scatter_kernel<<<ceil_div(E, CHUNK), T, 0, stream>>>(src, dst, curI, curO, ebI, ebO, E);
    // after bucket_scatter, curI[b]/curO[b] == bucket end
    bucket_deg2_kernel<<<dim3(NBUCK, 2), T, 0, stream>>>(ebI, ebO, baseI, baseO, curI, curO,
                                                         degI, degO, N);
    scan_blk2_kernel<<<dim3(NBLK, 2), SCAN_B, 0, stream>>>(degI, degO, rowI, rowO, bsumI, bsumO, N);
    scan_top2_kernel<<<2, 1024, 0, stream>>>(bsumI, bsumO, NBLK);
    scan_add2_kernel<<<dim3(NBLK, 2), SCAN_B, 0, stream>>>(rowI, rowO, bsumI, bsumO,
                                                           degI, degO, dinvI, dinvO, N);
    bucket_adj2_kernel<<<dim3(NBUCK, 2), T, 0, stream>>>(ebI, ebO, baseI, baseO, curI, curO,
                                                         rowI, rowO, adjI, adjO, N);
    seg_cnt_kernel<<<ceil_div(G, T), T, 0, stream>>>(seg, cnt, N, G);
    prep_w_kernel<<<128, 256, 0, stream>>>(W_mid, W_mid_r, b_mid, b_mid_r, Wt, bcomb);

    // ---- layer 1: width-4 gathers then dense 4->128 (fp16 out) ----
    gather4_kernel<<<ceil_div(N, T), T, 0, stream>>>(rowI, degI, adjI, dinvI,
                                                     rowO, degO, adjO, dinvO,
                                                     (const float4*)x,
                                                     (float4*)acc4I, (float4*)acc4O, N);
    layer1_kernel<<<ceil_div(N, L1_NODES), 128, 0, stream>>>(acc4I, acc4O,
                                                             W_in, b_in, W_in_r, b_in_r, hbuf, N);
    // ---- layer 2: fp16 gather (both dirs) then MFMA GEMM (fp16 out) ----
    gather128_kernel<<<dim3(ceil_div(N, 16), 2), 256, 0, stream>>>(
        rowI, degI, adjI, dinvI, rowO, degO, adjO, dinvO,
        (const half8*)hbuf, (half8*)aggI, (half8*)aggO, N);
    layer2_mfma_kernel<<<ceil_div(N, 64), 256, 0, stream>>>(
        aggI, aggO, Wt, bcomb, hbuf, N);
    // ---- layer 3: fp16 gather, pool, final projection ----
    gather128_kernel<<<dim3(ceil_div(N, 16), 2), 256, 0, stream>>>(
        rowI, degI, adjI, dinvI, rowO, degO, adjO, dinvO,
        (const half8*)hbuf, (half8*)aggI, (half8*)aggO, N);
    pool_kernel<<<ceil_div(N, POOL_NODES), 128, 0, stream>>>(
        aggI, aggO, seg, poolI, poolO, N);
    final_kernel<<<G, 128, 0, stream>>>(poolI, poolO, cnt,
                                        W_out, b_out, W_out_r, b_out_r, (float*)d_out, G);
}

// Round 11
// 480.388 us; speedup vs baseline: 25.2216x; 1.0606x over previous
//
#include <hip/hip_runtime.h>
#include <hip/hip_fp16.h>

#define ALPHA 0.5f
#define BSH 9            // bucket shift: 512 nodes/bucket
#define BSZ 512          // nodes per bucket
#define MAXB 512         // max buckets -> supports N <= 262144
#define CHUNK 4096       // edges per block in bucket_scatter

static inline int ceil_div(int a, int b) { return (a + b - 1) / b; }

typedef _Float16 half8 __attribute__((ext_vector_type(8)));
typedef float f32x4 __attribute__((ext_vector_type(4)));

// ---------------- bucket histogram (both directions) ----------------
__global__ void hist_kernel(const int* __restrict__ src, const int* __restrict__ dst,
                            unsigned int* __restrict__ bhI, unsigned int* __restrict__ bhO,
                            int E, int nbuck)
{
    __shared__ unsigned int hI[MAXB], hO[MAXB];
    for (int b = threadIdx.x; b < MAXB; b += blockDim.x) { hI[b] = 0; hO[b] = 0; }
    __syncthreads();
    for (int e = blockIdx.x * blockDim.x + threadIdx.x; e < E; e += gridDim.x * blockDim.x) {
        atomicAdd(&hI[dst[e] >> BSH], 1u);
        atomicAdd(&hO[src[e] >> BSH], 1u);
    }
    __syncthreads();
    for (int b = threadIdx.x; b < nbuck; b += blockDim.x) {
        if (hI[b]) atomicAdd(&bhI[b], hI[b]);
        if (hO[b]) atomicAdd(&bhO[b], hO[b]);
    }
}

// ---------------- bucket bases: exclusive scan of both hists (1 block, MAXB threads) ------
__global__ void bucket_base_kernel(const unsigned int* __restrict__ bhI,
                                   const unsigned int* __restrict__ bhO,
                                   unsigned int* __restrict__ baseI, unsigned int* __restrict__ baseO,
                                   unsigned int* __restrict__ curI, unsigned int* __restrict__ curO,
                                   int nbuck)
{
    __shared__ unsigned int tI[MAXB], tO[MAXB];
    int t = threadIdx.x;
    unsigned int vI = (t < nbuck) ? bhI[t] : 0u;
    unsigned int vO = (t < nbuck) ? bhO[t] : 0u;
    tI[t] = vI; tO[t] = vO;
    __syncthreads();
    for (int o = 1; o < MAXB; o <<= 1) {
        unsigned int xI = (t >= o) ? tI[t - o] : 0u;
        unsigned int xO = (t >= o) ? tO[t - o] : 0u;
        __syncthreads();
        tI[t] += xI; tO[t] += xO;
        __syncthreads();
    }
    if (t < nbuck) {
        baseI[t] = tI[t] - vI; baseO[t] = tO[t] - vO;
        curI[t]  = tI[t] - vI; curO[t]  = tO[t] - vO;
    }
}

// ---------------- bucket scatter with block-local reservation ----------------
__global__ void bucket_scatter_kernel(const int* __restrict__ src, const int* __restrict__ dst,
                                      unsigned int* __restrict__ curI, unsigned int* __restrict__ curO,
                                      int2* __restrict__ ebI, int2* __restrict__ ebO, int E)
{
    __shared__ unsigned int cI[MAXB], cO[MAXB], bI[MAXB], bO[MAXB];
    int t = threadIdx.x;
    for (int b = t; b < MAXB; b += blockDim.x) { cI[b] = 0; cO[b] = 0; }
    __syncthreads();
    int e0 = blockIdx.x * CHUNK;
    int e1 = min(E, e0 + CHUNK);
    for (int e = e0 + t; e < e1; e += blockDim.x) {
        atomicAdd(&cI[dst[e] >> BSH], 1u);
        atomicAdd(&cO[src[e] >> BSH], 1u);
    }
    __syncthreads();
    for (int b = t; b < MAXB; b += blockDim.x) {
        unsigned int n = cI[b];
        if (n) bI[b] = atomicAdd(&curI[b], n);
        cI[b] = 0;
        n = cO[b];
        if (n) bO[b] = atomicAdd(&curO[b], n);
        cO[b] = 0;
    }
    __syncthreads();
    for (int e = e0 + t; e < e1; e += blockDim.x) {
        int s = src[e], d = dst[e];
        int lb = d >> BSH;
        unsigned int p = bI[lb] + atomicAdd(&cI[lb], 1u);
        ebI[p] = make_int2(d, s);
        lb = s >> BSH;
        p = bO[lb] + atomicAdd(&cO[lb], 1u);
        ebO[p] = make_int2(s, d);
    }
}

// ---------------- fused per-bucket CSR finalize: deg + scan + rowstart/dinv + adj --------
// One block per (bucket, direction). baseI[b] gives the bucket's global edge offset, so
// rowstart = base + local exclusive scan. Replaces 5 separate kernels.
__global__ __launch_bounds__(256) void bucket_csr_kernel(
    const int2* __restrict__ ebI, const int2* __restrict__ ebO,
    const unsigned int* __restrict__ baseI, const unsigned int* __restrict__ baseO,
    const unsigned int* __restrict__ bendI, const unsigned int* __restrict__ bendO,
    unsigned int* __restrict__ rowI, unsigned int* __restrict__ rowO,
    unsigned int* __restrict__ degI, unsigned int* __restrict__ degO,
    float* __restrict__ dinvI, float* __restrict__ dinvO,
    int* __restrict__ adjI, int* __restrict__ adjO, int N)
{
    const int2* __restrict__ eb           = blockIdx.y ? ebO : ebI;
    const unsigned int* __restrict__ base = blockIdx.y ? baseO : baseI;
    const unsigned int* __restrict__ bend = blockIdx.y ? bendO : bendI;
    unsigned int* __restrict__ row        = blockIdx.y ? rowO : rowI;
    unsigned int* __restrict__ deg        = blockIdx.y ? degO : degI;
    float* __restrict__ dinv              = blockIdx.y ? dinvO : dinvI;
    int* __restrict__ adj                 = blockIdx.y ? adjO : adjI;

    __shared__ unsigned int d[BSZ];    // degree, then cursor
    __shared__ unsigned int ex[BSZ];   // exclusive scan
    __shared__ unsigned int ps[256];   // pair sums
    int b = blockIdx.x, t = threadIdx.x;
    int nbase = b << BSH;

    for (int i = t; i < BSZ; i += 256) d[i] = 0;
    __syncthreads();
    unsigned int lo = base[b], hi = bend[b];
    for (unsigned int i = lo + t; i < hi; i += 256)
        atomicAdd(&d[eb[i].x - nbase], 1u);
    __syncthreads();

    // exclusive scan of d[0..511]: pairwise then Hillis-Steele over 256 pair sums
    ps[t] = d[2 * t] + d[2 * t + 1];
    __syncthreads();
    for (int o = 1; o < 256; o <<= 1) {
        unsigned int x = (t >= o) ? ps[t - o] : 0u;
        __syncthreads();
        ps[t] += x;
        __syncthreads();
    }
    unsigned int p0 = (t > 0) ? ps[t - 1] : 0u;
    ex[2 * t]     = p0;
    ex[2 * t + 1] = p0 + d[2 * t];
    __syncthreads();

    // write rowstart / deg / dinv
    for (int i = t; i < BSZ; i += 256) {
        int v = nbase + i;
        if (v < N) {
            unsigned int dd = d[i];
            row[v]  = lo + ex[i];
            deg[v]  = dd;
            dinv[v] = dd ? rsqrtf((float)dd) : 0.f;
        }
    }
    __syncthreads();
    // cursors, then adjacency scatter within the bucket's window
    for (int i = t; i < BSZ; i += 256) d[i] = lo + ex[i];
    __syncthreads();
    for (unsigned int i = lo + t; i < hi; i += 256) {
        int2 e = eb[i];
        unsigned int p = atomicAdd(&d[e.x - nbase], 1u);
        adj[p] = e.y;
    }
}

// ---------------- per-graph node counts via binary search (seg is sorted) ----------------
__global__ void seg_cnt_kernel(const int* __restrict__ seg, float* __restrict__ cnt, int N, int G)
{
    int g = blockIdx.x * blockDim.x + threadIdx.x;
    if (g >= G) return;
    int lo = 0, hi = N;
    while (lo < hi) { int m = (lo + hi) >> 1; if (seg[m] < g) lo = m + 1; else hi = m; }
    int s0 = lo;
    hi = N;
    while (lo < hi) { int m = (lo + hi) >> 1; if (seg[m] < g + 1) lo = m + 1; else hi = m; }
    cnt[g] = (float)(lo - s0);
}

// ---------------- layer2 weight prep: Wt[j][k] fp16 (pre-scaled, transposed), bcomb ------
__global__ void prep_w_kernel(const float* __restrict__ Wi, const float* __restrict__ Wr,
                              const float* __restrict__ bi, const float* __restrict__ br,
                              __half* __restrict__ Wt, float* __restrict__ bcomb)
{
    int idx = blockIdx.x * 256 + threadIdx.x;   // 128*256 elems
    if (idx < 128 * 256) {
        int j = idx >> 8, k = idx & 255;
        float w = (k < 128) ? (1.f - ALPHA) * Wi[k * 128 + j]
                            : ALPHA * Wr[(k - 128) * 128 + j];
        Wt[idx] = __float2half_rn(w);           // Wt[j*256 + k]
    }
    if (idx < 128) bcomb[idx] = (1.f - ALPHA) * bi[idx] + ALPHA * br[idx];
}

// ---------------- fused layer 1: CSR width-4 gathers + dense 4->128 fp16, relu ----------
// One thread per node: both CSR loops in registers, then project via LDS weights.
__global__ __launch_bounds__(256) void layer1_fused_kernel(
    const unsigned int* __restrict__ rowI, const unsigned int* __restrict__ degI,
    const int* __restrict__ adjI, const float* __restrict__ dinvI,
    const unsigned int* __restrict__ rowO, const unsigned int* __restrict__ degO,
    const int* __restrict__ adjO, const float* __restrict__ dinvO,
    const float4* __restrict__ x4,
    const float* __restrict__ Wi, const float* __restrict__ bi,
    const float* __restrict__ Wr, const float* __restrict__ br,
    __half* __restrict__ h1, int N)
{
    __shared__ float wI[4][128], wO[4][128], bb[128];
    int t = threadIdx.x;
    if (t < 128) {
#pragma unroll
        for (int c = 0; c < 4; ++c) {
            wI[c][t] = (1.f - ALPHA) * Wi[c * 128 + t];
            wO[c][t] = ALPHA * Wr[c * 128 + t];
        }
        bb[t] = (1.f - ALPHA) * bi[t] + ALPHA * br[t];
    }
    __syncthreads();
    int v = blockIdx.x * 256 + t;
    if (v >= N) return;

    float4 aI = {0.f, 0.f, 0.f, 0.f};
    {
        unsigned int k = rowI[v], end = k + degI[v];
        for (; k < end; ++k) {
            int s = adjI[k];
            float w = dinvI[s];
            float4 xv = x4[s];
            aI.x += w * xv.x; aI.y += w * xv.y; aI.z += w * xv.z; aI.w += w * xv.w;
        }
        float dv = dinvI[v];
        aI.x *= dv; aI.y *= dv; aI.z *= dv; aI.w *= dv;
    }
    float4 aO = {0.f, 0.f, 0.f, 0.f};
    {
        unsigned int k = rowO[v], end = k + degO[v];
        for (; k < end; ++k) {
            int s = adjO[k];
            float w = dinvO[s];
            float4 xv = x4[s];
            aO.x += w * xv.x; aO.y += w * xv.y; aO.z += w * xv.z; aO.w += w * xv.w;
        }
        float dv = dinvO[v];
        aO.x *= dv; aO.y *= dv; aO.z *= dv; aO.w *= dv;
    }

    half8* outp = (half8*)&h1[(size_t)v * 128];
#pragma unroll
    for (int jq = 0; jq < 16; ++jq) {
        half8 o;
#pragma unroll
        for (int u = 0; u < 8; ++u) {
            int j = jq * 8 + u;
            float s = bb[j]
                    + aI.x * wI[0][j] + aI.y * wI[1][j] + aI.z * wI[2][j] + aI.w * wI[3][j]
                    + aO.x * wO[0][j] + aO.y * wO[1][j] + aO.z * wO[2][j] + aO.w * wO[3][j];
            o[u] = (_Float16)fmaxf(s, 0.f);
        }
        outp[jq] = o;
    }
}

// ---------------- CSR gather aggregation, width 128 fp16: 16 lanes x half8, unroll 4 -----
__global__ void gather128_kernel(const unsigned int* __restrict__ rowstartI,
                                 const unsigned int* __restrict__ degI,
                                 const int* __restrict__ adjI,
                                 const float* __restrict__ dinvI,
                                 const unsigned int* __restrict__ rowstartO,
                                 const unsigned int* __restrict__ degO,
                                 const int* __restrict__ adjO,
                                 const float* __restrict__ dinvO,
                                 const half8* __restrict__ hp,
                                 half8* __restrict__ outI, half8* __restrict__ outO, int N)
{
    int v = blockIdx.x * 16 + (threadIdx.x >> 4);
    if (v >= N) return;
    int lane = threadIdx.x & 15;
    const unsigned int* __restrict__ rowstart = blockIdx.y ? rowstartO : rowstartI;
    const unsigned int* __restrict__ deg      = blockIdx.y ? degO : degI;
    const int* __restrict__ adj               = blockIdx.y ? adjO : adjI;
    const float* __restrict__ dinv            = blockIdx.y ? dinvO : dinvI;
    half8* __restrict__ out                   = blockIdx.y ? outO : outI;

    unsigned int k = rowstart[v];
    unsigned int end = k + deg[v];
    float acc[8];
#pragma unroll
    for (int i = 0; i < 8; ++i) acc[i] = 0.f;

    for (; k + 4 <= end; k += 4) {
        int s0 = adj[k], s1 = adj[k + 1], s2 = adj[k + 2], s3 = adj[k + 3];
        float w0 = dinv[s0], w1 = dinv[s1], w2 = dinv[s2], w3 = dinv[s3];
        half8 h0 = hp[(size_t)s0 * 16 + lane];
        half8 h1 = hp[(size_t)s1 * 16 + lane];
        half8 h2 = hp[(size_t)s2 * 16 + lane];
        half8 h3 = hp[(size_t)s3 * 16 + lane];
#pragma unroll
        for (int i = 0; i < 8; ++i)
            acc[i] += w0 * (float)h0[i] + w1 * (float)h1[i]
                    + w2 * (float)h2[i] + w3 * (float)h3[i];
    }
    for (; k < end; ++k) {
        int s = adj[k];
        float w = dinv[s];
        half8 hv = hp[(size_t)s * 16 + lane];
#pragma unroll
        for (int i = 0; i < 8; ++i)
            acc[i] += w * (float)hv[i];
    }
    float dv = dinv[v];
    half8 o;
#pragma unroll
    for (int i = 0; i < 8; ++i) o[i] = (_Float16)(dv * acc[i]);
    out[(size_t)v * 16 + lane] = o;
}

// ---------------- layer 2 via MFMA: [aggI|aggO] (N,256)fp16 @ Wt^T -> (N,128) fp16 -------
__global__ __launch_bounds__(256) void layer2_mfma_kernel(
    const __half* __restrict__ aggI, const __half* __restrict__ aggO,   // [N][128] each
    const __half* __restrict__ Wt,    // [128][256] pre-scaled, transposed
    const float* __restrict__ bcomb,  // [128]
    __half* __restrict__ h2, int N)
{
    int wave = threadIdx.x >> 6;
    int lane = threadIdx.x & 63;
    int v0 = blockIdx.x * 64 + wave * 16;
    int row = lane & 15;
    int kg  = lane >> 4;                 // 0..3
    int vsafe = min(v0 + row, N - 1);

    f32x4 acc[8];
#pragma unroll
    for (int t = 0; t < 8; ++t) acc[t] = (f32x4){0.f, 0.f, 0.f, 0.f};

#pragma unroll
    for (int ks = 0; ks < 8; ++ks) {
        const __half* asrc = (ks < 4) ? aggI : aggO;
        int kofs = (ks & 3) * 32 + kg * 8;
        half8 afrag = *(const half8*)&asrc[(size_t)vsafe * 128 + kofs];
        int kw = ks * 32 + kg * 8;
#pragma unroll
        for (int t = 0; t < 8; ++t) {
            int j = t * 16 + row;
            half8 bfrag = *(const half8*)&Wt[(size_t)j * 256 + kw];
            acc[t] = __builtin_amdgcn_mfma_f32_16x16x32_f16(afrag, bfrag, acc[t], 0, 0, 0);
        }
    }

#pragma unroll
    for (int t = 0; t < 8; ++t) {
        int j = t * 16 + row;
        float bj = bcomb[j];
#pragma unroll
        for (int r = 0; r < 4; ++r) {
            int vr = v0 + kg * 4 + r;
            if (vr < N)
                h2[(size_t)vr * 128 + j] = __float2half_rn(fmaxf(acc[t][r] + bj, 0.f));
        }
    }
}

// ---------------- pooling of fp16 aggregated features (batch_seg sorted) -----------------
#define POOL_NODES 32
__global__ void pool_kernel(const __half* __restrict__ aI, const __half* __restrict__ aO,
                            const int* __restrict__ seg,
                            float* __restrict__ poolI, float* __restrict__ poolO, int N)
{
    int j = threadIdx.x;  // 128 threads, one channel each
    int v0 = blockIdx.x * POOL_NODES;
    if (v0 >= N) return;
    int v1 = min(N, v0 + POOL_NODES);
    float sI = 0.f, sO = 0.f;
    int cur = seg[v0];
    for (int v = v0; v < v1; ++v) {
        int g = seg[v];
        if (g != cur) {
            atomicAdd(&poolI[cur * 128 + j], sI);
            atomicAdd(&poolO[cur * 128 + j], sO);
            sI = 0.f; sO = 0.f; cur = g;
        }
        sI += __half2float(aI[(size_t)v * 128 + j]);
        sO += __half2float(aO[(size_t)v * 128 + j]);
    }
    atomicAdd(&poolI[cur * 128 + j], sI);
    atomicAdd(&poolO[cur * 128 + j], sO);
}

// ---------------- final: (G,128)x2 -> (G,120) with mean ----------------
__global__ void final_kernel(const float* __restrict__ poolI, const float* __restrict__ poolO,
                             const float* __restrict__ cnt,
                             const float* __restrict__ Wo, const float* __restrict__ bo,
                             const float* __restrict__ Wor, const float* __restrict__ bor,
                             float* __restrict__ out, int G)
{
    int g = blockIdx.x;
    int j = threadIdx.x;  // 120 threads
    if (g >= G || j >= 120) return;
    float acc = 0.f;
    for (int k = 0; k < 128; ++k) {
        acc += poolI[g * 128 + k] * ((1.f - ALPHA) * Wo[k * 120 + j])
             + poolO[g * 128 + k] * (ALPHA * Wor[k * 120 + j]);
    }
    float c = cnt[g];
    float bcomb = (1.f - ALPHA) * bo[j] + ALPHA * bor[j];
    out[g * 120 + j] = (c > 0.f) ? (acc / c + bcomb) : 0.f;
}

extern "C" void kernel_launch(void* const* d_in, const int* in_sizes, int n_in,
                              void* d_out, int out_size, void* d_ws, size_t ws_size,
                              hipStream_t stream)
{
    const float* x      = (const float*)d_in[0];
    const int*   ei     = (const int*)d_in[1];
    const int*   seg    = (const int*)d_in[2];
    const float* W_in   = (const float*)d_in[3];
    const float* b_in   = (const float*)d_in[4];
    const float* W_in_r = (const float*)d_in[5];
    const float* b_in_r = (const float*)d_in[6];
    const float* W_mid  = (const float*)d_in[7];
    const float* b_mid  = (const float*)d_in[8];
    const float* W_mid_r= (const float*)d_in[9];
    const float* b_mid_r= (const float*)d_in[10];
    const float* W_out  = (const float*)d_in[11];
    const float* b_out  = (const float*)d_in[12];
    const float* W_out_r= (const float*)d_in[13];
    const float* b_out_r= (const float*)d_in[14];

    const int N = in_sizes[0] / 4;
    const int E = in_sizes[1] / 2;
    const int G = out_size / 120;
    const int* src = ei;
    const int* dst = ei + E;
    const int NBUCK = ceil_div(N, BSZ);      // <= 512

    // -------- workspace layout (4-byte units) --------
    char* wsb = (char*)d_ws;
    size_t off = 0;
    auto alloc = [&](size_t elems) { void* p = wsb + off * 4; off += elems; return p; };

    unsigned int* bhI   = (unsigned int*)alloc(MAXB);     // zeroed
    unsigned int* bhO   = (unsigned int*)alloc(MAXB);     // zeroed
    float*        poolI = (float*)alloc((size_t)G * 128); // zeroed
    float*        poolO = (float*)alloc((size_t)G * 128); // zeroed
    size_t zero_elems = off;
    float*        cnt   = (float*)alloc(G);               // fully written by seg_cnt
    unsigned int* baseI = (unsigned int*)alloc(MAXB);
    unsigned int* baseO = (unsigned int*)alloc(MAXB);
    unsigned int* curI  = (unsigned int*)alloc(MAXB);
    unsigned int* curO  = (unsigned int*)alloc(MAXB);
    unsigned int* degI  = (unsigned int*)alloc(N);
    unsigned int* degO  = (unsigned int*)alloc(N);
    float*        dinvI = (float*)alloc(N);
    float*        dinvO = (float*)alloc(N);
    unsigned int* rowI  = (unsigned int*)alloc(N);        // exclusive row starts
    unsigned int* rowO  = (unsigned int*)alloc(N);
    int*          adjI  = (int*)alloc(E);
    int*          adjO  = (int*)alloc(E);
    __half*       Wt    = (__half*)alloc(128 * 256 / 2);  // 32768 halves
    float*        bcomb = (float*)alloc(128);
    off = (off + 3) & ~(size_t)3;                         // 16B align
    __half* hbuf = (__half*)alloc((size_t)N * 64);        // h1 / h2 fp16 (N*128 halves)
    __half* aggI = (__half*)alloc((size_t)N * 64);        // fp16 agg in-direction
    __half* aggO = (__half*)alloc((size_t)N * 64);        // fp16 agg out-direction
    (void)ws_size;

    // Bucketed edge buffers alias agg buffers (dead until gather128 writes them).
    int2* ebI = (int2*)aggI;
    int2* ebO = (int2*)aggO;

    hipMemsetAsync(d_ws, 0, zero_elems * 4, stream);

    const int T = 256;
    // ---- binned CSR build ----
    hist_kernel<<<ceil_div(E, T * 16), T, 0, stream>>>(src, dst, bhI, bhO, E, NBUCK);
    bucket_base_kernel<<<1, MAXB, 0, stream>>>(bhI, bhO, baseI, baseO, curI, curO, NBUCK);
    bucket_scatter_kernel<<<ceil_div(E, CHUNK), T, 0, stream>>>(src, dst, curI, curO, ebI, ebO, E);
    // after bucket_scatter, curI[b]/curO[b] == bucket end
    bucket_csr_kernel<<<dim3(NBUCK, 2), T, 0, stream>>>(ebI, ebO, baseI, baseO, curI, curO,
                                                        rowI, rowO, degI, degO,
                                                        dinvI, dinvO, adjI, adjO, N);
    seg_cnt_kernel<<<ceil_div(G, T), T, 0, stream>>>(seg, cnt, N, G);
    prep_w_kernel<<<128, 256, 0, stream>>>(W_mid, W_mid_r, b_mid, b_mid_r, Wt, bcomb);

    // ---- layer 1: fused CSR-4 gathers + dense 4->128 (fp16 out) ----
    layer1_fused_kernel<<<ceil_div(N, T), T, 0, stream>>>(
        rowI, degI, adjI, dinvI, rowO, degO, adjO, dinvO,
        (const float4*)x, W_in, b_in, W_in_r, b_in_r, hbuf, N);
    // ---- layer 2: fp16 gather (both dirs) then MFMA GEMM (fp16 out) ----
    gather128_kernel<<<dim3(ceil_div(N, 16), 2), 256, 0, stream>>>(
        rowI, degI, adjI, dinvI, rowO, degO, adjO, dinvO,
        (const half8*)hbuf, (half8*)aggI, (half8*)aggO, N);
    layer2_mfma_kernel<<<ceil_div(N, 64), 256, 0, stream>>>(
        aggI, aggO, Wt, bcomb, hbuf, N);
    // ---- layer 3: fp16 gather, pool, final projection ----
    gather128_kernel<<<dim3(ceil_div(N, 16), 2), 256, 0, stream>>>(
        rowI, degI, adjI, dinvI, rowO, degO, adjO, dinvO,
        (const half8*)hbuf, (half8*)aggI, (half8*)aggO, N);
    pool_kernel<<<ceil_div(N, POOL_NODES), 128, 0, stream>>>(
        aggI, aggO, seg, poolI, poolO, N);
    final_kernel<<<G, 128, 0, stream>>>(poolI, poolO, cnt,
                                        W_out, b_out, W_out_r, b_out_r, (float*)d_out, G);
}